// Round 1
// baseline (910.564 us; speedup 1.0000x reference)
//
#include <hip/hip_runtime.h>
#include <hip/hip_bf16.h>

// Problem constants
#define BATCH 2
#define SEQ 512
#define DIM 768
#define HEADS 12
#define NEXP 8
#define FFDIM 3072
#define HDIM 64
#define NTOK (BATCH*SEQ)          // 1024
#define NENT (2*NTOK)             // 2048 (token, slot) entries

// ---------------- LayerNorm: one block per token, 256 threads ----------------
__global__ __launch_bounds__(256) void ln_kernel(const float* __restrict__ x,
                                                 const float* __restrict__ g,
                                                 const float* __restrict__ b,
                                                 float* __restrict__ out) {
    int t = blockIdx.x;
    const float* xr = x + (long)t * DIM;
    float* orow = out + (long)t * DIM;
    int tid = threadIdx.x;
    float v0 = xr[tid], v1 = xr[tid + 256], v2 = xr[tid + 512];
    float s = v0 + v1 + v2;
    __shared__ float red[4];
    #pragma unroll
    for (int o = 32; o; o >>= 1) s += __shfl_xor(s, o);
    if ((tid & 63) == 0) red[tid >> 6] = s;
    __syncthreads();
    s = red[0] + red[1] + red[2] + red[3];
    float mu = s * (1.f / DIM);
    float d0 = v0 - mu, d1 = v1 - mu, d2 = v2 - mu;
    float q = d0*d0 + d1*d1 + d2*d2;
    __shared__ float red2[4];
    #pragma unroll
    for (int o = 32; o; o >>= 1) q += __shfl_xor(q, o);
    if ((tid & 63) == 0) red2[tid >> 6] = q;
    __syncthreads();
    q = red2[0] + red2[1] + red2[2] + red2[3];
    float rstd = rsqrtf(q * (1.f / DIM) + 1e-5f);
    orow[tid]       = d0 * rstd * g[tid]       + b[tid];
    orow[tid + 256] = d1 * rstd * g[tid + 256] + b[tid + 256];
    orow[tid + 512] = d2 * rstd * g[tid + 512] + b[tid + 512];
}

// ---------------- Generic tiled GEMM ----------------
// C[m,n] = alpha * sum_k A[m,k] * (TRANSB ? B[n,k] : B[k,n])  (+bias[n]) (+resid) (ACT)
// Batched via blockIdx.z: off = (z/zdiv)*hi + (z%zdiv)*lo per operand.
// GROUPED: per-expert row ranges from grp_off[z..z+1]; B/bias stride by z.
#define BM 64
#define BN 64
#define BKK 16

template<bool TRANSB, bool GROUPED, int ACT>
__global__ __launch_bounds__(256) void gemm_kernel(
    const float* __restrict__ A, const float* __restrict__ B,
    const float* __restrict__ bias, const float* __restrict__ resid,
    float* __restrict__ C,
    int M, int N, int K, int lda, int ldb, int ldc,
    int zdiv,
    long a_hi, long a_lo, long b_hi, long b_lo, long c_hi, long c_lo,
    long bias_stride,
    const int* __restrict__ grp_off, float alpha)
{
    int z = blockIdx.z;
    int zh = z / zdiv, zl = z % zdiv;
    long aoff, coff, boff;
    int m_count = M;
    if (GROUPED) {
        int m0 = grp_off[z], m1 = grp_off[z + 1];
        m_count = m1 - m0;
        if ((int)blockIdx.y * BM >= m_count) return;
        aoff = (long)m0 * lda;
        coff = (long)m0 * ldc;
        boff = (long)z * b_hi;
    } else {
        aoff = zh * a_hi + zl * a_lo;
        coff = zh * c_hi + zl * c_lo;
        boff = zh * b_hi + zl * b_lo;
    }
    const float* Ab = A + aoff;
    const float* Bb = B + boff;
    const float* biasb = bias ? bias + (long)z * bias_stride : nullptr;
    float* Cb = C + coff;

    __shared__ float As[BKK][BM + 1];
    __shared__ float Bs[BKK][BN + 1];

    int tid = threadIdx.x;
    int bm = blockIdx.y * BM;
    int bn = blockIdx.x * BN;
    int tx = tid % 16, ty = tid / 16;

    float acc[4][4] = {};

    for (int k0 = 0; k0 < K; k0 += BKK) {
        // A tile: As[k][m] = A[bm+m][k0+k]
        {
            int kk = tid % BKK;
            int mm0 = tid / BKK;
            #pragma unroll
            for (int r = 0; r < 4; ++r) {
                int mm = mm0 + r * 16;
                int gm = bm + mm;
                float v = 0.f;
                if (!GROUPED || gm < m_count)
                    v = Ab[(long)gm * lda + k0 + kk];
                As[kk][mm] = v;
            }
        }
        if (TRANSB) {
            int kk = tid % BKK;
            int nn0 = tid / BKK;
            #pragma unroll
            for (int r = 0; r < 4; ++r) {
                int nn = nn0 + r * 16;
                Bs[kk][nn] = Bb[(long)(bn + nn) * ldb + k0 + kk];
            }
        } else {
            int nn = tid % BN;
            int kk0 = tid / BN;
            #pragma unroll
            for (int r = 0; r < 4; ++r) {
                int kk = kk0 + r * 4;
                Bs[kk][nn] = Bb[(long)(k0 + kk) * ldb + bn + nn];
            }
        }
        __syncthreads();
        #pragma unroll
        for (int k = 0; k < BKK; ++k) {
            float a[4], bb[4];
            #pragma unroll
            for (int i = 0; i < 4; ++i) a[i] = As[k][ty * 4 + i];
            #pragma unroll
            for (int j = 0; j < 4; ++j) bb[j] = Bs[k][tx * 4 + j];
            #pragma unroll
            for (int i = 0; i < 4; ++i)
                #pragma unroll
                for (int j = 0; j < 4; ++j)
                    acc[i][j] += a[i] * bb[j];
        }
        __syncthreads();
    }

    #pragma unroll
    for (int i = 0; i < 4; ++i) {
        int row = bm + ty * 4 + i;
        if (GROUPED && row >= m_count) continue;
        #pragma unroll
        for (int j = 0; j < 4; ++j) {
            int col = bn + tx * 4 + j;
            float v = acc[i][j] * alpha;
            if (biasb) v += biasb[col];
            if (resid) v += resid[(long)row * ldc + col];
            if (ACT == 1) v = 0.5f * v * (1.f + erff(v * 0.70710678118654752f));
            Cb[(long)row * ldc + col] = v;
        }
    }
}

// ---------------- row softmax over 512 ----------------
__global__ __launch_bounds__(256) void softmax512(float* __restrict__ s) {
    long row = blockIdx.x;
    float* p = s + row * 512;
    int tid = threadIdx.x;
    float a = p[tid], b = p[tid + 256];
    float m = fmaxf(a, b);
    __shared__ float red[4], red2[4];
    #pragma unroll
    for (int o = 32; o; o >>= 1) m = fmaxf(m, __shfl_xor(m, o));
    if ((tid & 63) == 0) red[tid >> 6] = m;
    __syncthreads();
    m = fmaxf(fmaxf(red[0], red[1]), fmaxf(red[2], red[3]));
    float e0 = expf(a - m), e1 = expf(b - m);
    float ssum = e0 + e1;
    #pragma unroll
    for (int o = 32; o; o >>= 1) ssum += __shfl_xor(ssum, o);
    if ((tid & 63) == 0) red2[tid >> 6] = ssum;
    __syncthreads();
    ssum = red2[0] + red2[1] + red2[2] + red2[3];
    float inv = 1.f / ssum;
    p[tid] = e0 * inv;
    p[tid + 256] = e1 * inv;
}

// ---------------- router: logits, softmax, top2, renorm ----------------
__global__ __launch_bounds__(64) void router_kernel(const float* __restrict__ t2,
                                                    const float* __restrict__ rw,
                                                    const float* __restrict__ rb,
                                                    int* __restrict__ e_sel,
                                                    float* __restrict__ w_sel) {
    int t = blockIdx.x;
    int lane = threadIdx.x;
    const float* tr = t2 + (long)t * DIM;
    float tv[12];
    #pragma unroll
    for (int i = 0; i < 12; ++i) tv[i] = tr[lane + 64 * i];
    float logits[NEXP];
    #pragma unroll
    for (int e = 0; e < NEXP; ++e) {
        const float* wr = rw + (long)e * DIM;
        float s = 0.f;
        #pragma unroll
        for (int i = 0; i < 12; ++i) s += tv[i] * wr[lane + 64 * i];
        #pragma unroll
        for (int o = 32; o; o >>= 1) s += __shfl_xor(s, o);
        logits[e] = s + rb[e];
    }
    if (lane == 0) {
        int e0 = -1, e1 = -1;
        float l0 = -1e30f, l1 = -1e30f;
        #pragma unroll
        for (int e = 0; e < NEXP; ++e) {
            float l = logits[e];
            if (l > l0) { l1 = l0; e1 = e0; l0 = l; e0 = e; }
            else if (l > l1) { l1 = l; e1 = e; }
        }
        float p1 = expf(l1 - l0);       // p(top2)/p(top1)
        float inv = 1.f / (1.f + p1);
        e_sel[t * 2] = e0;  e_sel[t * 2 + 1] = e1;
        w_sel[t * 2] = inv; w_sel[t * 2 + 1] = p1 * inv;
    }
}

// ---------------- build per-expert entry lists (single block) ----------------
__global__ __launch_bounds__(1024) void build_lists(const int* __restrict__ e_sel,
                                                    int* __restrict__ entry_tok,
                                                    int* __restrict__ pos,
                                                    int* __restrict__ grp_off) {
    __shared__ int cnt[NEXP];
    __shared__ int off[NEXP + 1];
    __shared__ int cur[NEXP];
    int tid = threadIdx.x;
    if (tid < NEXP) cnt[tid] = 0;
    __syncthreads();
    for (int i = tid; i < NENT; i += 1024) atomicAdd(&cnt[e_sel[i]], 1);
    __syncthreads();
    if (tid == 0) {
        off[0] = 0;
        for (int e = 0; e < NEXP; ++e) off[e + 1] = off[e] + cnt[e];
        for (int e = 0; e < NEXP; ++e) cur[e] = off[e];
    }
    __syncthreads();
    for (int i = tid; i < NENT; i += 1024) {
        int e = e_sel[i];
        int p = atomicAdd(&cur[e], 1);
        entry_tok[p] = i >> 1;
        pos[i] = p;
    }
    if (tid < NEXP + 1) grp_off[tid] = off[tid];
}

// ---------------- gather rows for grouped GEMM ----------------
__global__ __launch_bounds__(256) void gather_kernel(const float* __restrict__ t2,
                                                     const int* __restrict__ entry_tok,
                                                     float* __restrict__ t2g) {
    long i = (long)blockIdx.x * 256 + threadIdx.x;
    if (i >= (long)NENT * DIM) return;
    int p = (int)(i / DIM), d = (int)(i % DIM);
    t2g[i] = t2[(long)entry_tok[p] * DIM + d];
}

// ---------------- final combine: out = x1 + w0*y(pos0) + w1*y(pos1) ----------------
__global__ __launch_bounds__(256) void combine_kernel(const float* __restrict__ x1,
                                                      const float* __restrict__ ybuf,
                                                      const int* __restrict__ pos,
                                                      const float* __restrict__ wsel,
                                                      float* __restrict__ out) {
    long i = (long)blockIdx.x * 256 + threadIdx.x;
    if (i >= (long)NTOK * DIM) return;
    int t = (int)(i / DIM), d = (int)(i % DIM);
    float v = x1[i];
    v += wsel[t * 2]     * ybuf[(long)pos[t * 2]     * DIM + d];
    v += wsel[t * 2 + 1] * ybuf[(long)pos[t * 2 + 1] * DIM + d];
    out[i] = v;
}

extern "C" void kernel_launch(void* const* d_in, const int* in_sizes, int n_in,
                              void* d_out, int out_size, void* d_ws, size_t ws_size,
                              hipStream_t stream) {
    const float* x        = (const float*)d_in[0];
    const float* ln1_g    = (const float*)d_in[1];
    const float* ln1_b    = (const float*)d_in[2];
    const float* ln2_g    = (const float*)d_in[3];
    const float* ln2_b    = (const float*)d_in[4];
    const float* in_w     = (const float*)d_in[5];
    const float* in_b     = (const float*)d_in[6];
    const float* out_w    = (const float*)d_in[7];
    const float* out_b    = (const float*)d_in[8];
    const float* router_w = (const float*)d_in[9];
    const float* router_b = (const float*)d_in[10];
    const float* w1       = (const float*)d_in[11];
    const float* b1       = (const float*)d_in[12];
    const float* w2       = (const float*)d_in[13];
    const float* b2       = (const float*)d_in[14];
    float* out = (float*)d_out;
    float* ws = (float*)d_ws;

    const long TD = (long)NTOK * DIM;          // 786432
    float* h    = ws;                          // TD
    float* qkv  = ws + TD;                     // 3*TD
    float* big  = ws + 4 * TD;                 // 8*TD : scores, later hid
    float* oat  = ws + 12 * TD;                // TD
    float* x1   = ws + 13 * TD;                // TD
    float* t2   = ws + 14 * TD;                // TD
    float* t2g  = ws + 15 * TD;                // 2*TD
    float* ybuf = ws + 17 * TD;                // 2*TD
    float* misc = ws + 19 * TD;
    int*   e_sel     = (int*)misc;             // 2048
    float* w_sel     = misc + 2048;            // 2048
    int*   entry_tok = (int*)(misc + 4096);    // 2048
    int*   pos       = (int*)(misc + 6144);    // 2048
    int*   grp_off   = (int*)(misc + 8192);    // 9

    // 1. LN1
    ln_kernel<<<NTOK, 256, 0, stream>>>(x, ln1_g, ln1_b, h);

    // 2. qkv = h @ in_w^T + in_b    [1024, 2304]
    gemm_kernel<true, false, 0><<<dim3(36, 16, 1), 256, 0, stream>>>(
        h, in_w, in_b, nullptr, qkv,
        NTOK, 3 * DIM, DIM, DIM, DIM, 3 * DIM,
        1, 0, 0, 0, 0, 0, 0, 0, nullptr, 1.f);

    // 3. scores[z] = q @ k^T / 8   z = b*12 + head,  [512,512] each
    {
        long sd = (long)SEQ * 3 * DIM;              // per-batch stride in qkv
        gemm_kernel<true, false, 0><<<dim3(8, 8, 24), 256, 0, stream>>>(
            qkv, qkv + DIM, nullptr, nullptr, big,
            SEQ, SEQ, HDIM, 3 * DIM, 3 * DIM, SEQ,
            HEADS, sd, HDIM, sd, HDIM,
            (long)HEADS * SEQ * SEQ, (long)SEQ * SEQ,
            0, nullptr, 0.125f);
    }

    // 4. softmax rows
    softmax512<<<24 * SEQ, 256, 0, stream>>>(big);

    // 5. o = attn @ v   -> oat [1024, 768] (head-merged)
    {
        long sd = (long)SEQ * 3 * DIM;
        gemm_kernel<false, false, 0><<<dim3(1, 8, 24), 256, 0, stream>>>(
            big, qkv + 2 * DIM, nullptr, nullptr, oat,
            SEQ, HDIM, SEQ, SEQ, 3 * DIM, DIM,
            HEADS, (long)HEADS * SEQ * SEQ, (long)SEQ * SEQ,
            sd, HDIM,
            (long)SEQ * DIM, HDIM,
            0, nullptr, 1.f);
    }

    // 6. x1 = x + oat @ out_w^T + out_b
    gemm_kernel<true, false, 0><<<dim3(12, 16, 1), 256, 0, stream>>>(
        oat, out_w, out_b, x, x1,
        NTOK, DIM, DIM, DIM, DIM, DIM,
        1, 0, 0, 0, 0, 0, 0, 0, nullptr, 1.f);

    // 7. LN2
    ln_kernel<<<NTOK, 256, 0, stream>>>(x1, ln2_g, ln2_b, t2);

    // 8. router
    router_kernel<<<NTOK, 64, 0, stream>>>(t2, router_w, router_b, e_sel, w_sel);

    // 9. build lists
    build_lists<<<1, 1024, 0, stream>>>(e_sel, entry_tok, pos, grp_off);

    // 10. gather
    gather_kernel<<<(NENT * DIM + 255) / 256, 256, 0, stream>>>(t2, entry_tok, t2g);

    // 11. FFN1 grouped: hid = gelu(t2g @ w1[e] + b1[e])   N=3072 K=768
    gemm_kernel<false, true, 1><<<dim3(48, 16, 8), 256, 0, stream>>>(
        t2g, w1, b1, nullptr, big,
        0, FFDIM, DIM, DIM, FFDIM, FFDIM,
        1, 0, 0, (long)DIM * FFDIM, 0, 0, 0,
        FFDIM, grp_off, 1.f);

    // 12. FFN2 grouped: ybuf = hid @ w2[e] + b2[e]   N=768 K=3072
    gemm_kernel<false, true, 0><<<dim3(12, 16, 8), 256, 0, stream>>>(
        big, w2, b2, nullptr, ybuf,
        0, DIM, FFDIM, FFDIM, DIM, DIM,
        1, 0, 0, (long)FFDIM * DIM, 0, 0, 0,
        DIM, grp_off, 1.f);

    // 13. combine
    combine_kernel<<<(NTOK * DIM + 255) / 256, 256, 0, stream>>>(
        x1, ybuf, pos, w_sel, out);
}

// Round 2
// 319.189 us; speedup vs baseline: 2.8527x; 2.8527x over previous
//
#include <hip/hip_runtime.h>
#include <hip/hip_bf16.h>

// Problem constants
#define BATCH 2
#define SEQ 512
#define DIM 768
#define HEADS 12
#define NEXP 8
#define FFDIM 3072
#define HDIM 64
#define NTOK (BATCH*SEQ)          // 1024
#define NENT (2*NTOK)             // 2048 (token, slot) entries

typedef __hip_bfloat16 bf16;
typedef __attribute__((ext_vector_type(8))) short s8v;
typedef __attribute__((ext_vector_type(4))) float f4v;

// ---- async global->LDS (16B per lane, wave-uniform LDS base + lane*16) ----
typedef __attribute__((address_space(1))) const unsigned char gas_u8;
typedef __attribute__((address_space(3))) unsigned char las_u8;
__device__ __forceinline__ void gload16(const void* g, void* l) {
    __builtin_amdgcn_global_load_lds((gas_u8*)g, (las_u8*)l, 16, 0, 0);
}

// ---------------- LayerNorm: one block per token, 256 threads ----------------
__global__ __launch_bounds__(256) void ln_kernel(const float* __restrict__ x,
                                                 const float* __restrict__ g,
                                                 const float* __restrict__ b,
                                                 float* __restrict__ outf,
                                                 bf16* __restrict__ outb) {
    int t = blockIdx.x;
    const float* xr = x + (long)t * DIM;
    int tid = threadIdx.x;
    float v0 = xr[tid], v1 = xr[tid + 256], v2 = xr[tid + 512];
    float s = v0 + v1 + v2;
    __shared__ float red[4];
    #pragma unroll
    for (int o = 32; o; o >>= 1) s += __shfl_xor(s, o);
    if ((tid & 63) == 0) red[tid >> 6] = s;
    __syncthreads();
    s = red[0] + red[1] + red[2] + red[3];
    float mu = s * (1.f / DIM);
    float d0 = v0 - mu, d1 = v1 - mu, d2 = v2 - mu;
    float q = d0*d0 + d1*d1 + d2*d2;
    __shared__ float red2[4];
    #pragma unroll
    for (int o = 32; o; o >>= 1) q += __shfl_xor(q, o);
    if ((tid & 63) == 0) red2[tid >> 6] = q;
    __syncthreads();
    q = red2[0] + red2[1] + red2[2] + red2[3];
    float rstd = rsqrtf(q * (1.f / DIM) + 1e-5f);
    float o0 = d0 * rstd * g[tid]       + b[tid];
    float o1 = d1 * rstd * g[tid + 256] + b[tid + 256];
    float o2 = d2 * rstd * g[tid + 512] + b[tid + 512];
    if (outf) {
        float* of = outf + (long)t * DIM;
        of[tid] = o0; of[tid + 256] = o1; of[tid + 512] = o2;
    }
    if (outb) {
        bf16* ob = outb + (long)t * DIM;
        ob[tid] = __float2bfloat16(o0);
        ob[tid + 256] = __float2bfloat16(o1);
        ob[tid + 512] = __float2bfloat16(o2);
    }
}

// ---------------- MFMA GEMM (m97 structure: 128x128 tile, BK=32, 4 waves) ----
// C[m,n] = alpha * sum_k A[m,k] * B[n,k]   (B stored [N][K] row-major, bf16)
// (+bias[col]) (GELU) (+resid) ; OUTBF16 selects store type.
// Batched via z (zdiv split) or GROUPED via grp_off row ranges.
template<bool GROUPED, bool GELU, bool OUTBF16>
__global__ __launch_bounds__(256) void mfma_gemm(
    const bf16* __restrict__ A, const bf16* __restrict__ B,
    const float* __restrict__ bias, const float* __restrict__ resid,
    void* __restrict__ Cv,
    int M, int N, int K, int lda, int ldb, int ldc,
    int zdiv,
    long a_hi, long a_lo, long b_hi, long b_lo, long c_hi, long c_lo,
    long bias_stride, const int* __restrict__ grp_off, float alpha)
{
    int z = blockIdx.z;
    int zh = z / zdiv, zl = z % zdiv;
    long aoff, boff, coff;
    int m_count = M;
    if (GROUPED) {
        int m0 = grp_off[z], m1 = grp_off[z + 1];
        m_count = m1 - m0;
        if ((int)blockIdx.y * 128 >= m_count) return;
        aoff = (long)m0 * lda;
        coff = (long)m0 * ldc;
        boff = (long)z * b_hi;
    } else {
        aoff = zh * a_hi + zl * a_lo;
        boff = zh * b_hi + zl * b_lo;
        coff = zh * c_hi + zl * c_lo;
    }
    const short* Ag = (const short*)(A + aoff);
    const short* Bg = (const short*)(B + boff);
    const float* biasp = bias ? bias + (long)z * bias_stride : nullptr;
    float* Cf = (float*)Cv + coff;
    bf16*  Cb = (bf16*)Cv + coff;

    __shared__ short As[128 * 32];   // [m][k] rows of 64B
    __shared__ short Bs[128 * 32];   // [n][k]

    int tid = threadIdx.x;
    int wv = tid >> 6, ln = tid & 63;
    int wr = wv >> 1, wc = wv & 1;          // 2x2 wave grid, each wave 64x64
    int fr = ln & 15, fq = ln >> 4;
    int bm = blockIdx.y * 128, bn = blockIdx.x * 128;

    f4v acc[4][4] = {};

    for (int k0 = 0; k0 < K; k0 += 32) {
        // stage A,B: chunk c = is*256 + wv*64 + lane; m=c>>2, kq=c&3
        #pragma unroll
        for (int is = 0; is < 2; ++is) {
            int c = is * 256 + wv * 64 + ln;
            int m = c >> 2, kq = c & 3;
            gload16(Ag + (long)(bm + m) * lda + k0 + kq * 8,
                    &As[(is * 256 + wv * 64) * 8]);
            gload16(Bg + (long)(bn + m) * ldb + k0 + kq * 8,
                    &Bs[(is * 256 + wv * 64) * 8]);
        }
        __syncthreads();
        s8v av[4], bv[4];
        #pragma unroll
        for (int i = 0; i < 4; ++i)
            av[i] = *(const s8v*)&As[(wr * 64 + i * 16 + fr) * 32 + fq * 8];
        #pragma unroll
        for (int j = 0; j < 4; ++j)
            bv[j] = *(const s8v*)&Bs[(wc * 64 + j * 16 + fr) * 32 + fq * 8];
        #pragma unroll
        for (int i = 0; i < 4; ++i)
            #pragma unroll
            for (int j = 0; j < 4; ++j)
                acc[i][j] = __builtin_amdgcn_mfma_f32_16x16x32_bf16(av[i], bv[j], acc[i][j], 0, 0, 0);
        __syncthreads();
    }

    // epilogue: C/D layout col=lane&15, row=(lane>>4)*4+reg
    #pragma unroll
    for (int i = 0; i < 4; ++i) {
        #pragma unroll
        for (int r = 0; r < 4; ++r) {
            int row = bm + wr * 64 + i * 16 + fq * 4 + r;
            if (GROUPED && row >= m_count) continue;
            #pragma unroll
            for (int j = 0; j < 4; ++j) {
                int col = bn + wc * 64 + j * 16 + fr;
                if (col < N) {
                    float v = acc[i][j][r] * alpha;
                    if (biasp) v += biasp[col];
                    if (GELU) v = 0.5f * v * (1.f + erff(v * 0.70710678118654752f));
                    if (resid) v += resid[(long)row * ldc + col];
                    if (OUTBF16) Cb[(long)row * ldc + col] = __float2bfloat16(v);
                    else         Cf[(long)row * ldc + col] = v;
                }
            }
        }
    }
}

// ---------------- row softmax over 512 (f32 in, bf16 out) ----------------
__global__ __launch_bounds__(256) void softmax512(const float* __restrict__ s,
                                                  bf16* __restrict__ attn) {
    long row = blockIdx.x;
    const float* p = s + row * 512;
    int tid = threadIdx.x;
    float a = p[tid], b = p[tid + 256];
    float m = fmaxf(a, b);
    __shared__ float red[4], red2[4];
    #pragma unroll
    for (int o = 32; o; o >>= 1) m = fmaxf(m, __shfl_xor(m, o));
    if ((tid & 63) == 0) red[tid >> 6] = m;
    __syncthreads();
    m = fmaxf(fmaxf(red[0], red[1]), fmaxf(red[2], red[3]));
    float e0 = expf(a - m), e1 = expf(b - m);
    float ssum = e0 + e1;
    #pragma unroll
    for (int o = 32; o; o >>= 1) ssum += __shfl_xor(ssum, o);
    if ((tid & 63) == 0) red2[tid >> 6] = ssum;
    __syncthreads();
    ssum = red2[0] + red2[1] + red2[2] + red2[3];
    float inv = 1.f / ssum;
    bf16* ar = attn + row * 512;
    ar[tid]       = __float2bfloat16(e0 * inv);
    ar[tid + 256] = __float2bfloat16(e1 * inv);
}

// ---------------- V transpose: qkv bf16 [tok][2304] -> vt [z][64][512] ------
__global__ __launch_bounds__(256) void vt_kernel(const bf16* __restrict__ qkvb,
                                                 bf16* __restrict__ vt) {
    int st = blockIdx.x;            // s tile (8)
    int z = blockIdx.y;             // 24
    int b = z / HEADS, h = z % HEADS;
    __shared__ short tile[64][65];
    int t = threadIdx.x;
    int d = t & 63, s0 = t >> 6;
    const short* q = (const short*)qkvb;
    #pragma unroll
    for (int i = 0; i < 16; ++i) {
        int s = st * 64 + s0 + i * 4;
        tile[s0 + i * 4][d] = q[(long)(b * SEQ + s) * 2304 + 2 * DIM + h * HDIM + d];
    }
    __syncthreads();
    short* o = (short*)vt;
    #pragma unroll
    for (int i = 0; i < 16; ++i) {
        int d2 = (t >> 6) + i * 4;
        o[(long)(z * 64 + d2) * 512 + st * 64 + (t & 63)] = tile[t & 63][d2];
    }
}

// ---------------- weight transpose-convert: f32 [z][R][C] -> bf16 [z][C][R] --
__global__ __launch_bounds__(256) void wtrans_kernel(const float* __restrict__ in,
                                                     bf16* __restrict__ out,
                                                     int R, int C) {
    int z = blockIdx.z;
    long ibase = (long)z * R * C;
    int rt = blockIdx.y * 64, ct = blockIdx.x * 64;
    __shared__ float tile[64][65];
    int t = threadIdx.x;
    int c = t & 63, r0 = t >> 6;
    #pragma unroll
    for (int i = 0; i < 16; ++i)
        tile[r0 + i * 4][c] = in[ibase + (long)(rt + r0 + i * 4) * C + ct + c];
    __syncthreads();
    #pragma unroll
    for (int i = 0; i < 16; ++i) {
        int cc = r0 + i * 4;
        out[ibase + (long)(ct + cc) * R + rt + c] = __float2bfloat16(tile[c][cc]);
    }
}

// ---------------- straight f32 -> bf16 convert ----------------
__global__ __launch_bounds__(256) void cvt_kernel(const float* __restrict__ in,
                                                  bf16* __restrict__ out, long n) {
    long i = ((long)blockIdx.x * 256 + threadIdx.x) * 4;
    if (i >= n) return;
    float4 v = *(const float4*)(in + i);
    out[i]     = __float2bfloat16(v.x);
    out[i + 1] = __float2bfloat16(v.y);
    out[i + 2] = __float2bfloat16(v.z);
    out[i + 3] = __float2bfloat16(v.w);
}

// ---------------- router: logits, softmax, top2, renorm ----------------
__global__ __launch_bounds__(64) void router_kernel(const float* __restrict__ t2,
                                                    const float* __restrict__ rw,
                                                    const float* __restrict__ rb,
                                                    int* __restrict__ e_sel,
                                                    float* __restrict__ w_sel) {
    int t = blockIdx.x;
    int lane = threadIdx.x;
    const float* tr = t2 + (long)t * DIM;
    float tv[12];
    #pragma unroll
    for (int i = 0; i < 12; ++i) tv[i] = tr[lane + 64 * i];
    float logits[NEXP];
    #pragma unroll
    for (int e = 0; e < NEXP; ++e) {
        const float* wr = rw + (long)e * DIM;
        float s = 0.f;
        #pragma unroll
        for (int i = 0; i < 12; ++i) s += tv[i] * wr[lane + 64 * i];
        #pragma unroll
        for (int o = 32; o; o >>= 1) s += __shfl_xor(s, o);
        logits[e] = s + rb[e];
    }
    if (lane == 0) {
        int e0 = -1, e1 = -1;
        float l0 = -1e30f, l1 = -1e30f;
        #pragma unroll
        for (int e = 0; e < NEXP; ++e) {
            float l = logits[e];
            if (l > l0) { l1 = l0; e1 = e0; l0 = l; e0 = e; }
            else if (l > l1) { l1 = l; e1 = e; }
        }
        float p1 = expf(l1 - l0);
        float inv = 1.f / (1.f + p1);
        e_sel[t * 2] = e0;  e_sel[t * 2 + 1] = e1;
        w_sel[t * 2] = inv; w_sel[t * 2 + 1] = p1 * inv;
    }
}

// ---------------- build per-expert entry lists (single block) ----------------
__global__ __launch_bounds__(1024) void build_lists(const int* __restrict__ e_sel,
                                                    int* __restrict__ entry_tok,
                                                    int* __restrict__ pos,
                                                    int* __restrict__ grp_off) {
    __shared__ int cnt[NEXP];
    __shared__ int off[NEXP + 1];
    __shared__ int cur[NEXP];
    int tid = threadIdx.x;
    if (tid < NEXP) cnt[tid] = 0;
    __syncthreads();
    for (int i = tid; i < NENT; i += 1024) atomicAdd(&cnt[e_sel[i]], 1);
    __syncthreads();
    if (tid == 0) {
        off[0] = 0;
        for (int e = 0; e < NEXP; ++e) off[e + 1] = off[e] + cnt[e];
        for (int e = 0; e < NEXP; ++e) cur[e] = off[e];
    }
    __syncthreads();
    for (int i = tid; i < NENT; i += 1024) {
        int e = e_sel[i];
        int p = atomicAdd(&cur[e], 1);
        entry_tok[p] = i >> 1;
        pos[i] = p;
    }
    if (tid < NEXP + 1) grp_off[tid] = off[tid];
}

// ---------------- gather rows (bf16, 8B units) ----------------
__global__ __launch_bounds__(256) void gather_kernel(const bf16* __restrict__ t2b,
                                                     const int* __restrict__ entry_tok,
                                                     bf16* __restrict__ t2g) {
    long i = (long)blockIdx.x * 256 + threadIdx.x;   // unit = 4 bf16 (8B); DIM/4=192
    if (i >= (long)NENT * 192) return;
    int p = (int)(i / 192), q = (int)(i % 192);
    ((uint2*)t2g)[(long)p * 192 + q] = ((const uint2*)t2b)[(long)entry_tok[p] * 192 + q];
}

// ---------------- final combine: out = x1 + w0*y(pos0) + w1*y(pos1) ----------
__global__ __launch_bounds__(256) void combine_kernel(const float* __restrict__ x1,
                                                      const float* __restrict__ ybuf,
                                                      const int* __restrict__ pos,
                                                      const float* __restrict__ wsel,
                                                      float* __restrict__ out) {
    long i = (long)blockIdx.x * 256 + threadIdx.x;
    if (i >= (long)NTOK * DIM) return;
    int t = (int)(i / DIM), d = (int)(i % DIM);
    float v = x1[i];
    v += wsel[t * 2]     * ybuf[(long)pos[t * 2]     * DIM + d];
    v += wsel[t * 2 + 1] * ybuf[(long)pos[t * 2 + 1] * DIM + d];
    out[i] = v;
}

extern "C" void kernel_launch(void* const* d_in, const int* in_sizes, int n_in,
                              void* d_out, int out_size, void* d_ws, size_t ws_size,
                              hipStream_t stream) {
    const float* x        = (const float*)d_in[0];
    const float* ln1_g    = (const float*)d_in[1];
    const float* ln1_b    = (const float*)d_in[2];
    const float* ln2_g    = (const float*)d_in[3];
    const float* ln2_b    = (const float*)d_in[4];
    const float* in_w     = (const float*)d_in[5];
    const float* in_b     = (const float*)d_in[6];
    const float* out_w    = (const float*)d_in[7];
    const float* out_b    = (const float*)d_in[8];
    const float* router_w = (const float*)d_in[9];
    const float* router_b = (const float*)d_in[10];
    const float* w1       = (const float*)d_in[11];
    const float* b1       = (const float*)d_in[12];
    const float* w2       = (const float*)d_in[13];
    const float* b2       = (const float*)d_in[14];
    float* out = (float*)d_out;

    const long TD = (long)NTOK * DIM;          // 786432
    char* p = (char*)d_ws;
    size_t off = 0;
    auto alloc = [&](size_t bytes) -> void* {
        void* r = p + off; off += (bytes + 255) & ~(size_t)255; return r;
    };
    bf16*  h_b    = (bf16*)alloc(TD * 2);
    bf16*  in_wb  = (bf16*)alloc(2304L * 768 * 2);
    bf16*  qkv_b  = (bf16*)alloc(1024L * 2304 * 2);
    bf16*  out_wb = (bf16*)alloc(768L * 768 * 2);
    bf16*  vt_b   = (bf16*)alloc((24L * 64 + 64) * 512 * 2);   // +64-row pad for B-tile overread
    bf16*  oat_b  = (bf16*)alloc(TD * 2);
    float* x1     = (float*)alloc(TD * 4);
    float* t2     = (float*)alloc(TD * 4);
    bf16*  t2b    = (bf16*)alloc(TD * 2);
    bf16*  t2g    = (bf16*)alloc((2048L + 128) * 768 * 2);     // +128-row pad (grouped A overread)
    bf16*  w1t    = (bf16*)alloc(8L * 3072 * 768 * 2);         // aliased: scores f32 + attn bf16
    bf16*  w2t    = (bf16*)alloc(8L * 768 * 3072 * 2);
    bf16*  hid    = (bf16*)alloc((2048L + 128) * 3072 * 2);    // +128-row pad
    float* ybuf   = (float*)alloc(2048L * 768 * 4);
    int*   e_sel     = (int*)alloc(NENT * 4);
    float* w_sel     = (float*)alloc(NENT * 4);
    int*   entry_tok = (int*)alloc(NENT * 4);
    int*   pos       = (int*)alloc(NENT * 4);
    int*   grp_off   = (int*)alloc(64);
    // scores/attn live inside the (not-yet-written) w1t region; w1 transpose
    // runs only after PV has consumed attn.
    float* scores = (float*)w1t;                               // 24*512*512 f32 = 25.17MB
    bf16*  attn   = (bf16*)((char*)w1t + 24L * 512 * 512 * 4); // 12.58MB

    // 1. LN1 -> h bf16
    ln_kernel<<<NTOK, 256, 0, stream>>>(x, ln1_g, ln1_b, nullptr, h_b);
    // 2-3. weight converts (straight)
    cvt_kernel<<<1728, 256, 0, stream>>>(in_w, in_wb, 2304L * 768);
    cvt_kernel<<<576, 256, 0, stream>>>(out_w, out_wb, 768L * 768);
    // 4. qkv = h @ in_w^T + in_b -> bf16 [1024,2304]
    mfma_gemm<false, false, true><<<dim3(18, 8, 1), 256, 0, stream>>>(
        h_b, in_wb, in_b, nullptr, qkv_b,
        NTOK, 3 * DIM, DIM, DIM, DIM, 3 * DIM,
        1, 0, 0, 0, 0, 0, 0, 0, nullptr, 1.f);
    // 5. scores = Q @ K^T / 8 -> f32 [24][512][512]
    mfma_gemm<false, false, false><<<dim3(4, 4, 24), 256, 0, stream>>>(
        qkv_b, qkv_b + DIM, nullptr, nullptr, scores,
        SEQ, SEQ, HDIM, 3 * DIM, 3 * DIM, SEQ,
        HEADS, (long)SEQ * 3 * DIM, HDIM, (long)SEQ * 3 * DIM, HDIM,
        (long)HEADS * SEQ * SEQ, (long)SEQ * SEQ,
        0, nullptr, 0.125f);
    // 6. softmax -> attn bf16
    softmax512<<<24 * SEQ, 256, 0, stream>>>(scores, attn);
    // 7. V transpose -> vt [24][64][512]
    vt_kernel<<<dim3(8, 24), 256, 0, stream>>>(qkv_b, vt_b);
    // 8. o = attn @ V -> oat bf16 [1024,768] head-merged
    mfma_gemm<false, false, true><<<dim3(1, 4, 24), 256, 0, stream>>>(
        attn, vt_b, nullptr, nullptr, oat_b,
        SEQ, HDIM, SEQ, SEQ, SEQ, DIM,
        HEADS, (long)HEADS * SEQ * SEQ, (long)SEQ * SEQ,
        (long)HEADS * HDIM * SEQ, (long)HDIM * SEQ,
        (long)SEQ * DIM, HDIM,
        0, nullptr, 1.f);
    // 9. x1 = x + oat @ out_w^T + out_b  (f32)
    mfma_gemm<false, false, false><<<dim3(6, 8, 1), 256, 0, stream>>>(
        oat_b, out_wb, out_b, x, x1,
        NTOK, DIM, DIM, DIM, DIM, DIM,
        1, 0, 0, 0, 0, 0, 0, 0, nullptr, 1.f);
    // 10. LN2 -> t2 f32 + t2b bf16
    ln_kernel<<<NTOK, 256, 0, stream>>>(x1, ln2_g, ln2_b, t2, t2b);
    // 11. router (f32)
    router_kernel<<<NTOK, 64, 0, stream>>>(t2, router_w, router_b, e_sel, w_sel);
    // 12. build lists
    build_lists<<<1, 1024, 0, stream>>>(e_sel, entry_tok, pos, grp_off);
    // 13. gather bf16
    gather_kernel<<<1536, 256, 0, stream>>>(t2b, entry_tok, t2g);
    // 14. w1 transpose-convert (after PV: overwrites scores/attn region)
    wtrans_kernel<<<dim3(48, 12, 8), 256, 0, stream>>>(w1, w1t, DIM, FFDIM);
    // 15. FFN1 grouped: hid = gelu(t2g @ w1t^T + b1) -> bf16
    mfma_gemm<true, true, true><<<dim3(24, 16, 8), 256, 0, stream>>>(
        t2g, w1t, b1, nullptr, hid,
        0, FFDIM, DIM, DIM, DIM, FFDIM,
        1, 0, 0, (long)FFDIM * DIM, 0, 0, 0,
        FFDIM, grp_off, 1.f);
    // 16. w2 transpose-convert
    wtrans_kernel<<<dim3(12, 48, 8), 256, 0, stream>>>(w2, w2t, FFDIM, DIM);
    // 17. FFN2 grouped: ybuf = hid @ w2t^T + b2 -> f32
    mfma_gemm<true, false, false><<<dim3(6, 16, 8), 256, 0, stream>>>(
        hid, w2t, b2, nullptr, ybuf,
        0, DIM, FFDIM, FFDIM, FFDIM, DIM,
        1, 0, 0, (long)DIM * FFDIM, 0, 0, 0,
        DIM, grp_off, 1.f);
    // 18. combine
    combine_kernel<<<3072, 256, 0, stream>>>(x1, ybuf, pos, w_sel, out);
}

// Round 3
// 241.484 us; speedup vs baseline: 3.7707x; 1.3218x over previous
//
#include <hip/hip_runtime.h>
#include <hip/hip_bf16.h>

// Problem constants
#define BATCH 2
#define SEQ 512
#define DIM 768
#define HEADS 12
#define NEXP 8
#define FFDIM 3072
#define HDIM 64
#define NTOK (BATCH*SEQ)          // 1024
#define NENT (2*NTOK)             // 2048 (token, slot) entries

typedef __hip_bfloat16 bf16;
typedef __attribute__((ext_vector_type(8))) short s8v;
typedef __attribute__((ext_vector_type(4))) float f4v;

// ---- async global->LDS (16B per lane, wave-uniform LDS base + lane*16) ----
typedef __attribute__((address_space(1))) const unsigned char gas_u8;
typedef __attribute__((address_space(3))) unsigned char las_u8;
__device__ __forceinline__ void gload16(const void* g, void* l) {
    __builtin_amdgcn_global_load_lds((gas_u8*)g, (las_u8*)l, 16, 0, 0);
}

// ---------------- LayerNorm: one block per token, 256 threads ----------------
__global__ __launch_bounds__(256) void ln_kernel(const float* __restrict__ x,
                                                 const float* __restrict__ g,
                                                 const float* __restrict__ b,
                                                 float* __restrict__ outf,
                                                 bf16* __restrict__ outb) {
    int t = blockIdx.x;
    const float* xr = x + (long)t * DIM;
    int tid = threadIdx.x;
    float v0 = xr[tid], v1 = xr[tid + 256], v2 = xr[tid + 512];
    float s = v0 + v1 + v2;
    __shared__ float red[4];
    #pragma unroll
    for (int o = 32; o; o >>= 1) s += __shfl_xor(s, o);
    if ((tid & 63) == 0) red[tid >> 6] = s;
    __syncthreads();
    s = red[0] + red[1] + red[2] + red[3];
    float mu = s * (1.f / DIM);
    float d0 = v0 - mu, d1 = v1 - mu, d2 = v2 - mu;
    float q = d0*d0 + d1*d1 + d2*d2;
    __shared__ float red2[4];
    #pragma unroll
    for (int o = 32; o; o >>= 1) q += __shfl_xor(q, o);
    if ((tid & 63) == 0) red2[tid >> 6] = q;
    __syncthreads();
    q = red2[0] + red2[1] + red2[2] + red2[3];
    float rstd = rsqrtf(q * (1.f / DIM) + 1e-5f);
    float o0 = d0 * rstd * g[tid]       + b[tid];
    float o1 = d1 * rstd * g[tid + 256] + b[tid + 256];
    float o2 = d2 * rstd * g[tid + 512] + b[tid + 512];
    if (outf) {
        float* of = outf + (long)t * DIM;
        of[tid] = o0; of[tid + 256] = o1; of[tid + 512] = o2;
    }
    if (outb) {
        bf16* ob = outb + (long)t * DIM;
        ob[tid] = __float2bfloat16(o0);
        ob[tid + 256] = __float2bfloat16(o1);
        ob[tid + 512] = __float2bfloat16(o2);
    }
}

// ---------------- MFMA GEMM, parameterized tile ----------------
// C[m,n] = alpha * sum_k A[m,k] * B[n,k]   (A,B bf16 row-major [.][K])
// Tile BM=32*WM x BN=32*WN, 4 waves in 2x2 grid, each wave WM x WN fragments.
// OUTMODE: 0 = f32 store (+bias,+resid,GELU opt), 1 = bf16 store, 2 = f32 atomicAdd (no bias).
// Batched via ze (zdiv split) or GROUPED via grp_off row ranges; split-K via ksplit.
template<int WM, int WN, bool GROUPED, bool GELU, int OUTMODE>
__global__ __launch_bounds__(256) void mfma_gemm(
    const bf16* __restrict__ A, const bf16* __restrict__ B,
    const float* __restrict__ bias, const float* __restrict__ resid,
    void* __restrict__ Cv,
    int M, int N, int K, int lda, int ldb, int ldc,
    int zdiv, int ksplit,
    long a_hi, long a_lo, long b_hi, long b_lo, long c_hi, long c_lo,
    long bias_stride, const int* __restrict__ grp_off, float alpha)
{
    constexpr int BM = 32 * WM, BN = 32 * WN;
    constexpr int AISS = (BM * 4) / 256;   // 16B-chunk issues for A tile
    constexpr int BISS = (BN * 4) / 256;

    int z = blockIdx.z;
    int ze = z / ksplit, ks = z % ksplit;
    int kper = K / ksplit;
    long aoff, boff, coff;
    int m_count = M;
    if (GROUPED) {
        int m0 = grp_off[ze], m1 = grp_off[ze + 1];
        m_count = m1 - m0;
        if ((int)blockIdx.y * BM >= m_count) return;
        aoff = (long)m0 * lda;
        coff = (long)m0 * ldc;
        boff = (long)ze * b_hi;
    } else {
        int zh = ze / zdiv, zl = ze % zdiv;
        aoff = zh * a_hi + zl * a_lo;
        boff = zh * b_hi + zl * b_lo;
        coff = zh * c_hi + zl * c_lo;
    }
    const short* Ag = (const short*)(A + aoff);
    const short* Bg = (const short*)(B + boff);
    const float* biasp = bias ? bias + (long)ze * bias_stride : nullptr;
    float* Cf = (float*)Cv + coff;
    bf16*  Cb = (bf16*)Cv + coff;

    __shared__ short As[BM * 32];   // [m][k] rows of 64B
    __shared__ short Bs[BN * 32];   // [n][k]

    int tid = threadIdx.x;
    int wv = tid >> 6, ln = tid & 63;
    int wr = wv >> 1, wc = wv & 1;          // 2x2 wave grid
    int fr = ln & 15, fq = ln >> 4;
    int bm = blockIdx.y * BM, bn = blockIdx.x * BN;

    f4v acc[WM][WN] = {};

    for (int k0 = ks * kper; k0 < (ks + 1) * kper; k0 += 32) {
        #pragma unroll
        for (int is = 0; is < AISS; ++is) {
            int c = is * 256 + wv * 64 + ln;
            int m = c >> 2, kq = c & 3;
            gload16(Ag + (long)(bm + m) * lda + k0 + kq * 8,
                    &As[(is * 256 + wv * 64) * 8]);
        }
        #pragma unroll
        for (int is = 0; is < BISS; ++is) {
            int c = is * 256 + wv * 64 + ln;
            int m = c >> 2, kq = c & 3;
            gload16(Bg + (long)(bn + m) * ldb + k0 + kq * 8,
                    &Bs[(is * 256 + wv * 64) * 8]);
        }
        __syncthreads();
        s8v av[WM], bv[WN];
        #pragma unroll
        for (int i = 0; i < WM; ++i)
            av[i] = *(const s8v*)&As[(wr * (WM * 16) + i * 16 + fr) * 32 + fq * 8];
        #pragma unroll
        for (int j = 0; j < WN; ++j)
            bv[j] = *(const s8v*)&Bs[(wc * (WN * 16) + j * 16 + fr) * 32 + fq * 8];
        #pragma unroll
        for (int i = 0; i < WM; ++i)
            #pragma unroll
            for (int j = 0; j < WN; ++j)
                acc[i][j] = __builtin_amdgcn_mfma_f32_16x16x32_bf16(av[i], bv[j], acc[i][j], 0, 0, 0);
        __syncthreads();
    }

    // epilogue: C/D layout col=lane&15, row=(lane>>4)*4+reg
    #pragma unroll
    for (int i = 0; i < WM; ++i) {
        #pragma unroll
        for (int r = 0; r < 4; ++r) {
            int row = bm + wr * (WM * 16) + i * 16 + fq * 4 + r;
            if (GROUPED && row >= m_count) continue;
            #pragma unroll
            for (int j = 0; j < WN; ++j) {
                int col = bn + wc * (WN * 16) + j * 16 + fr;
                if (col < N) {
                    float v = acc[i][j][r] * alpha;
                    if (OUTMODE == 2) {
                        atomicAdd(&Cf[(long)row * ldc + col], v);
                    } else {
                        if (biasp) v += biasp[col];
                        if (GELU) v = 0.5f * v * (1.f + erff(v * 0.70710678118654752f));
                        if (resid) v += resid[(long)row * ldc + col];
                        if (OUTMODE == 1) Cb[(long)row * ldc + col] = __float2bfloat16(v);
                        else              Cf[(long)row * ldc + col] = v;
                    }
                }
            }
        }
    }
}

// ---------------- row softmax over 512 (f32 in, bf16 out) ----------------
__global__ __launch_bounds__(256) void softmax512(const float* __restrict__ s,
                                                  bf16* __restrict__ attn) {
    long row = blockIdx.x;
    const float* p = s + row * 512;
    int tid = threadIdx.x;
    float a = p[tid], b = p[tid + 256];
    float m = fmaxf(a, b);
    __shared__ float red[4], red2[4];
    #pragma unroll
    for (int o = 32; o; o >>= 1) m = fmaxf(m, __shfl_xor(m, o));
    if ((tid & 63) == 0) red[tid >> 6] = m;
    __syncthreads();
    m = fmaxf(fmaxf(red[0], red[1]), fmaxf(red[2], red[3]));
    float e0 = expf(a - m), e1 = expf(b - m);
    float ssum = e0 + e1;
    #pragma unroll
    for (int o = 32; o; o >>= 1) ssum += __shfl_xor(ssum, o);
    if ((tid & 63) == 0) red2[tid >> 6] = ssum;
    __syncthreads();
    ssum = red2[0] + red2[1] + red2[2] + red2[3];
    float inv = 1.f / ssum;
    bf16* ar = attn + row * 512;
    ar[tid]       = __float2bfloat16(e0 * inv);
    ar[tid + 256] = __float2bfloat16(e1 * inv);
}

// ---------------- V transpose: qkv bf16 [tok][2304] -> vt [z][64][512] ------
__global__ __launch_bounds__(256) void vt_kernel(const bf16* __restrict__ qkvb,
                                                 bf16* __restrict__ vt) {
    int st = blockIdx.x;            // s tile (8)
    int z = blockIdx.y;             // 24
    int b = z / HEADS, h = z % HEADS;
    __shared__ short tile[64][65];
    int t = threadIdx.x;
    int d = t & 63, s0 = t >> 6;
    const short* q = (const short*)qkvb;
    #pragma unroll
    for (int i = 0; i < 16; ++i) {
        int s = st * 64 + s0 + i * 4;
        tile[s0 + i * 4][d] = q[(long)(b * SEQ + s) * 2304 + 2 * DIM + h * HDIM + d];
    }
    __syncthreads();
    short* o = (short*)vt;
    #pragma unroll
    for (int i = 0; i < 16; ++i) {
        int d2 = (t >> 6) + i * 4;
        o[(long)(z * 64 + d2) * 512 + st * 64 + (t & 63)] = tile[t & 63][d2];
    }
}

// ---------------- weight transpose-convert: f32 [z][R][C] -> bf16 [z][C][R] --
__global__ __launch_bounds__(256) void wtrans_kernel(const float* __restrict__ in,
                                                     bf16* __restrict__ out,
                                                     int R, int C) {
    int z = blockIdx.z;
    long ibase = (long)z * R * C;
    int rt = blockIdx.y * 64, ct = blockIdx.x * 64;
    __shared__ float tile[64][65];
    int t = threadIdx.x;
    int c = t & 63, r0 = t >> 6;
    #pragma unroll
    for (int i = 0; i < 16; ++i)
        tile[r0 + i * 4][c] = in[ibase + (long)(rt + r0 + i * 4) * C + ct + c];
    __syncthreads();
    #pragma unroll
    for (int i = 0; i < 16; ++i) {
        int cc = r0 + i * 4;
        out[ibase + (long)(ct + cc) * R + rt + c] = __float2bfloat16(tile[c][cc]);
    }
}

// ---------------- straight f32 -> bf16 convert ----------------
__global__ __launch_bounds__(256) void cvt_kernel(const float* __restrict__ in,
                                                  bf16* __restrict__ out, long n) {
    long i = ((long)blockIdx.x * 256 + threadIdx.x) * 4;
    if (i >= n) return;
    float4 v = *(const float4*)(in + i);
    out[i]     = __float2bfloat16(v.x);
    out[i + 1] = __float2bfloat16(v.y);
    out[i + 2] = __float2bfloat16(v.z);
    out[i + 3] = __float2bfloat16(v.w);
}

// ---------------- router: logits, softmax, top2, renorm ----------------
__global__ __launch_bounds__(64) void router_kernel(const float* __restrict__ t2,
                                                    const float* __restrict__ rw,
                                                    const float* __restrict__ rb,
                                                    int* __restrict__ e_sel,
                                                    float* __restrict__ w_sel) {
    int t = blockIdx.x;
    int lane = threadIdx.x;
    const float* tr = t2 + (long)t * DIM;
    float tv[12];
    #pragma unroll
    for (int i = 0; i < 12; ++i) tv[i] = tr[lane + 64 * i];
    float logits[NEXP];
    #pragma unroll
    for (int e = 0; e < NEXP; ++e) {
        const float* wr = rw + (long)e * DIM;
        float s = 0.f;
        #pragma unroll
        for (int i = 0; i < 12; ++i) s += tv[i] * wr[lane + 64 * i];
        #pragma unroll
        for (int o = 32; o; o >>= 1) s += __shfl_xor(s, o);
        logits[e] = s + rb[e];
    }
    if (lane == 0) {
        int e0 = -1, e1 = -1;
        float l0 = -1e30f, l1 = -1e30f;
        #pragma unroll
        for (int e = 0; e < NEXP; ++e) {
            float l = logits[e];
            if (l > l0) { l1 = l0; e1 = e0; l0 = l; e0 = e; }
            else if (l > l1) { l1 = l; e1 = e; }
        }
        float p1 = expf(l1 - l0);
        float inv = 1.f / (1.f + p1);
        e_sel[t * 2] = e0;  e_sel[t * 2 + 1] = e1;
        w_sel[t * 2] = inv; w_sel[t * 2 + 1] = p1 * inv;
    }
}

// ---------------- build per-expert entry lists (single block) ----------------
__global__ __launch_bounds__(1024) void build_lists(const int* __restrict__ e_sel,
                                                    int* __restrict__ entry_tok,
                                                    int* __restrict__ ent_exp,
                                                    int* __restrict__ pos,
                                                    int* __restrict__ grp_off) {
    __shared__ int cnt[NEXP];
    __shared__ int off[NEXP + 1];
    __shared__ int cur[NEXP];
    int tid = threadIdx.x;
    if (tid < NEXP) cnt[tid] = 0;
    __syncthreads();
    for (int i = tid; i < NENT; i += 1024) atomicAdd(&cnt[e_sel[i]], 1);
    __syncthreads();
    if (tid == 0) {
        off[0] = 0;
        for (int e = 0; e < NEXP; ++e) off[e + 1] = off[e] + cnt[e];
        for (int e = 0; e < NEXP; ++e) cur[e] = off[e];
    }
    __syncthreads();
    for (int i = tid; i < NENT; i += 1024) {
        int e = e_sel[i];
        int p = atomicAdd(&cur[e], 1);
        entry_tok[p] = i >> 1;
        ent_exp[p] = e;
        pos[i] = p;
    }
    if (tid < NEXP + 1) grp_off[tid] = off[tid];
}

// ---------------- gather rows (bf16, 8B units) ----------------
__global__ __launch_bounds__(256) void gather_kernel(const bf16* __restrict__ t2b,
                                                     const int* __restrict__ entry_tok,
                                                     bf16* __restrict__ t2g) {
    long i = (long)blockIdx.x * 256 + threadIdx.x;   // unit = 4 bf16 (8B); DIM/4=192
    if (i >= (long)NENT * 192) return;
    int p = (int)(i / 192), q = (int)(i % 192);
    ((uint2*)t2g)[(long)p * 192 + q] = ((const uint2*)t2b)[(long)entry_tok[p] * 192 + q];
}

// ---------------- prefill x1 = x + out_b (atomic GEMM accumulates into it) ---
__global__ __launch_bounds__(256) void prefill_x1(const float* __restrict__ x,
                                                  const float* __restrict__ out_b,
                                                  float* __restrict__ x1) {
    long i = ((long)blockIdx.x * 256 + threadIdx.x) * 4;   // NTOK*DIM/4 units
    if (i >= (long)NTOK * DIM) return;
    int d = (int)(i % DIM);
    float4 v = *(const float4*)(x + i);
    v.x += out_b[d]; v.y += out_b[d + 1]; v.z += out_b[d + 2]; v.w += out_b[d + 3];
    *(float4*)(x1 + i) = v;
}

// ---------------- prefill ybuf[p][.] = b2[exp(p)][.] ----------------
__global__ __launch_bounds__(256) void prefill_ybuf(const float* __restrict__ b2,
                                                    const int* __restrict__ ent_exp,
                                                    float* __restrict__ ybuf) {
    long i = ((long)blockIdx.x * 256 + threadIdx.x) * 4;
    if (i >= (long)NENT * DIM) return;
    int p = (int)(i / DIM), d = (int)(i % DIM);
    *(float4*)(ybuf + i) = *(const float4*)(b2 + (long)ent_exp[p] * DIM + d);
}

// ---------------- final combine: out = x1 + w0*y(pos0) + w1*y(pos1) ----------
__global__ __launch_bounds__(256) void combine_kernel(const float* __restrict__ x1,
                                                      const float* __restrict__ ybuf,
                                                      const int* __restrict__ pos,
                                                      const float* __restrict__ wsel,
                                                      float* __restrict__ out) {
    long i = (long)blockIdx.x * 256 + threadIdx.x;
    if (i >= (long)NTOK * DIM) return;
    int t = (int)(i / DIM), d = (int)(i % DIM);
    float v = x1[i];
    v += wsel[t * 2]     * ybuf[(long)pos[t * 2]     * DIM + d];
    v += wsel[t * 2 + 1] * ybuf[(long)pos[t * 2 + 1] * DIM + d];
    out[i] = v;
}

extern "C" void kernel_launch(void* const* d_in, const int* in_sizes, int n_in,
                              void* d_out, int out_size, void* d_ws, size_t ws_size,
                              hipStream_t stream) {
    const float* x        = (const float*)d_in[0];
    const float* ln1_g    = (const float*)d_in[1];
    const float* ln1_b    = (const float*)d_in[2];
    const float* ln2_g    = (const float*)d_in[3];
    const float* ln2_b    = (const float*)d_in[4];
    const float* in_w     = (const float*)d_in[5];
    const float* in_b     = (const float*)d_in[6];
    const float* out_w    = (const float*)d_in[7];
    const float* out_b    = (const float*)d_in[8];
    const float* router_w = (const float*)d_in[9];
    const float* router_b = (const float*)d_in[10];
    const float* w1       = (const float*)d_in[11];
    const float* b1       = (const float*)d_in[12];
    const float* w2       = (const float*)d_in[13];
    const float* b2       = (const float*)d_in[14];
    float* out = (float*)d_out;

    const long TD = (long)NTOK * DIM;          // 786432
    char* p = (char*)d_ws;
    size_t off = 0;
    auto alloc = [&](size_t bytes) -> void* {
        void* r = p + off; off += (bytes + 255) & ~(size_t)255; return r;
    };
    bf16*  h_b    = (bf16*)alloc(TD * 2);
    bf16*  in_wb  = (bf16*)alloc(2304L * 768 * 2);
    bf16*  qkv_b  = (bf16*)alloc(1024L * 2304 * 2);
    bf16*  out_wb = (bf16*)alloc(768L * 768 * 2);
    bf16*  vt_b   = (bf16*)alloc((24L * 64 + 64) * 512 * 2);   // +pad
    bf16*  oat_b  = (bf16*)alloc(TD * 2);
    float* x1     = (float*)alloc(TD * 4);
    float* t2     = (float*)alloc(TD * 4);
    bf16*  t2b    = (bf16*)alloc(TD * 2);
    bf16*  t2g    = (bf16*)alloc((2048L + 128) * 768 * 2);     // +pad (grouped A overread)
    bf16*  w1t    = (bf16*)alloc(8L * 3072 * 768 * 2);         // aliased: scores f32 + attn bf16
    bf16*  w2t    = (bf16*)alloc(8L * 768 * 3072 * 2);
    bf16*  hid    = (bf16*)alloc((2048L + 128) * 3072 * 2);    // +pad
    float* ybuf   = (float*)alloc(2048L * 768 * 4);
    int*   e_sel     = (int*)alloc(NENT * 4);
    float* w_sel     = (float*)alloc(NENT * 4);
    int*   entry_tok = (int*)alloc(NENT * 4);
    int*   ent_exp   = (int*)alloc(NENT * 4);
    int*   pos       = (int*)alloc(NENT * 4);
    int*   grp_off   = (int*)alloc(64);
    // scores/attn alias the not-yet-written w1t region; w1 transpose runs after PV.
    float* scores = (float*)w1t;                               // 24*512*512 f32
    bf16*  attn   = (bf16*)((char*)w1t + 24L * 512 * 512 * 4);

    // 1. LN1 -> h bf16
    ln_kernel<<<NTOK, 256, 0, stream>>>(x, ln1_g, ln1_b, nullptr, h_b);
    // 2-3. weight converts
    cvt_kernel<<<1728, 256, 0, stream>>>(in_w, in_wb, 2304L * 768);
    cvt_kernel<<<576, 256, 0, stream>>>(out_w, out_wb, 768L * 768);
    // 4. qkv = h @ in_w^T + in_b -> bf16 [1024,2304]   BM=64,BN=128: 288 blocks
    mfma_gemm<2, 4, false, false, 1><<<dim3(18, 16, 1), 256, 0, stream>>>(
        h_b, in_wb, in_b, nullptr, qkv_b,
        NTOK, 3 * DIM, DIM, DIM, DIM, 3 * DIM,
        1, 1, 0, 0, 0, 0, 0, 0, 0, nullptr, 1.f);
    // 5. scores = Q @ K^T / 8 -> f32 [24][512][512]   768 blocks
    mfma_gemm<2, 4, false, false, 0><<<dim3(4, 8, 24), 256, 0, stream>>>(
        qkv_b, qkv_b + DIM, nullptr, nullptr, scores,
        SEQ, SEQ, HDIM, 3 * DIM, 3 * DIM, SEQ,
        HEADS, 1, (long)SEQ * 3 * DIM, HDIM, (long)SEQ * 3 * DIM, HDIM,
        (long)HEADS * SEQ * SEQ, (long)SEQ * SEQ,
        0, nullptr, 0.125f);
    // 6. softmax -> attn bf16
    softmax512<<<24 * SEQ, 256, 0, stream>>>(scores, attn);
    // 7. V transpose -> vt [24][64][512]
    vt_kernel<<<dim3(8, 24), 256, 0, stream>>>(qkv_b, vt_b);
    // 8. o = attn @ V -> oat bf16 [1024,768]   BM=64,BN=64: 192 blocks
    mfma_gemm<2, 2, false, false, 1><<<dim3(1, 8, 24), 256, 0, stream>>>(
        attn, vt_b, nullptr, nullptr, oat_b,
        SEQ, HDIM, SEQ, SEQ, SEQ, DIM,
        HEADS, 1, (long)HEADS * SEQ * SEQ, (long)SEQ * SEQ,
        (long)HEADS * HDIM * SEQ, (long)HDIM * SEQ,
        (long)SEQ * DIM, HDIM,
        0, nullptr, 1.f);
    // 9a. prefill x1 = x + out_b
    prefill_x1<<<768, 256, 0, stream>>>(x, out_b, x1);
    // 9b. x1 += oat @ out_w^T   (split-K x2, atomic): 192 blocks
    mfma_gemm<2, 4, false, false, 2><<<dim3(6, 16, 2), 256, 0, stream>>>(
        oat_b, out_wb, nullptr, nullptr, x1,
        NTOK, DIM, DIM, DIM, DIM, DIM,
        1, 2, 0, 0, 0, 0, 0, 0, 0, nullptr, 1.f);
    // 10. LN2 -> t2 f32 + t2b bf16
    ln_kernel<<<NTOK, 256, 0, stream>>>(x1, ln2_g, ln2_b, t2, t2b);
    // 11. router
    router_kernel<<<NTOK, 64, 0, stream>>>(t2, router_w, router_b, e_sel, w_sel);
    // 12. build lists
    build_lists<<<1, 1024, 0, stream>>>(e_sel, entry_tok, ent_exp, pos, grp_off);
    // 13. gather bf16
    gather_kernel<<<1536, 256, 0, stream>>>(t2b, entry_tok, t2g);
    // 14. w1 transpose-convert (after PV: overwrites scores/attn region)
    wtrans_kernel<<<dim3(48, 12, 8), 256, 0, stream>>>(w1, w1t, DIM, FFDIM);
    // 15. FFN1 grouped: hid = gelu(t2g @ w1t^T + b1) -> bf16  BM=64: ~768 eff blocks
    mfma_gemm<2, 4, true, true, 1><<<dim3(24, 32, 8), 256, 0, stream>>>(
        t2g, w1t, b1, nullptr, hid,
        0, FFDIM, DIM, DIM, DIM, FFDIM,
        1, 1, 0, 0, (long)FFDIM * DIM, 0, 0, 0,
        FFDIM, grp_off, 1.f);
    // 16. w2 transpose-convert
    wtrans_kernel<<<dim3(12, 48, 8), 256, 0, stream>>>(w2, w2t, FFDIM, DIM);
    // 17a. prefill ybuf with b2 rows
    prefill_ybuf<<<1536, 256, 0, stream>>>(b2, ent_exp, ybuf);
    // 17b. FFN2 grouped split-K x4 (atomic): ybuf += hid @ w2t^T   ~768 eff blocks
    mfma_gemm<2, 4, true, false, 2><<<dim3(6, 32, 32), 256, 0, stream>>>(
        hid, w2t, nullptr, nullptr, ybuf,
        0, DIM, FFDIM, FFDIM, FFDIM, DIM,
        1, 4, 0, 0, (long)DIM * FFDIM, 0, 0, 0,
        DIM, grp_off, 1.f);
    // 18. combine
    combine_kernel<<<3072, 256, 0, stream>>>(x1, ybuf, pos, w_sel, out);
}

// Round 4
// 235.530 us; speedup vs baseline: 3.8660x; 1.0253x over previous
//
#include <hip/hip_runtime.h>
#include <hip/hip_bf16.h>

// Problem constants
#define BATCH 2
#define SEQ 512
#define DIM 768
#define HEADS 12
#define NEXP 8
#define FFDIM 3072
#define HDIM 64
#define NTOK (BATCH*SEQ)          // 1024
#define NENT (2*NTOK)             // 2048 (token, slot) entries

typedef __hip_bfloat16 bf16;
typedef __attribute__((ext_vector_type(8))) short s8v;
typedef __attribute__((ext_vector_type(4))) float f4v;

// ---- async global->LDS (16B per lane, wave-uniform LDS base + lane*16) ----
typedef __attribute__((address_space(1))) const unsigned char gas_u8;
typedef __attribute__((address_space(3))) unsigned char las_u8;
__device__ __forceinline__ void gload16(const void* g, void* l) {
    __builtin_amdgcn_global_load_lds((gas_u8*)g, (las_u8*)l, 16, 0, 0);
}

// ---------------- LayerNorm: one block per token, 256 threads ----------------
__global__ __launch_bounds__(256) void ln_kernel(const float* __restrict__ x,
                                                 const float* __restrict__ g,
                                                 const float* __restrict__ b,
                                                 float* __restrict__ outf,
                                                 bf16* __restrict__ outb) {
    int t = blockIdx.x;
    const float* xr = x + (long)t * DIM;
    int tid = threadIdx.x;
    float v0 = xr[tid], v1 = xr[tid + 256], v2 = xr[tid + 512];
    float s = v0 + v1 + v2;
    __shared__ float red[4];
    #pragma unroll
    for (int o = 32; o; o >>= 1) s += __shfl_xor(s, o);
    if ((tid & 63) == 0) red[tid >> 6] = s;
    __syncthreads();
    s = red[0] + red[1] + red[2] + red[3];
    float mu = s * (1.f / DIM);
    float d0 = v0 - mu, d1 = v1 - mu, d2 = v2 - mu;
    float q = d0*d0 + d1*d1 + d2*d2;
    __shared__ float red2[4];
    #pragma unroll
    for (int o = 32; o; o >>= 1) q += __shfl_xor(q, o);
    if ((tid & 63) == 0) red2[tid >> 6] = q;
    __syncthreads();
    q = red2[0] + red2[1] + red2[2] + red2[3];
    float rstd = rsqrtf(q * (1.f / DIM) + 1e-5f);
    float o0 = d0 * rstd * g[tid]       + b[tid];
    float o1 = d1 * rstd * g[tid + 256] + b[tid + 256];
    float o2 = d2 * rstd * g[tid + 512] + b[tid + 512];
    if (outf) {
        float* of = outf + (long)t * DIM;
        of[tid] = o0; of[tid + 256] = o1; of[tid + 512] = o2;
    }
    if (outb) {
        bf16* ob = outb + (long)t * DIM;
        ob[tid] = __float2bfloat16(o0);
        ob[tid + 256] = __float2bfloat16(o1);
        ob[tid + 512] = __float2bfloat16(o2);
    }
}

// ---------------- MFMA GEMM, parameterized tile (attention-side) ----------------
// C[m,n] = alpha * sum_k A[m,k] * B[n,k]   (A,B bf16 row-major [.][K])
// Tile BM=32*WM x BN=32*WN, 4 waves in 2x2 grid.
// OUTMODE: 0 = f32 store, 1 = bf16 store, 2 = f32 atomicAdd.
template<int WM, int WN, bool GROUPED, bool GELU, int OUTMODE>
__global__ __launch_bounds__(256) void mfma_gemm(
    const bf16* __restrict__ A, const bf16* __restrict__ B,
    const float* __restrict__ bias, const float* __restrict__ resid,
    void* __restrict__ Cv,
    int M, int N, int K, int lda, int ldb, int ldc,
    int zdiv, int ksplit,
    long a_hi, long a_lo, long b_hi, long b_lo, long c_hi, long c_lo,
    long bias_stride, const int* __restrict__ grp_off, float alpha)
{
    constexpr int BM = 32 * WM, BN = 32 * WN;
    constexpr int AISS = (BM * 4) / 256;
    constexpr int BISS = (BN * 4) / 256;

    int z = blockIdx.z;
    int ze = z / ksplit, ks = z % ksplit;
    int kper = K / ksplit;
    long aoff, boff, coff;
    int m_count = M;
    if (GROUPED) {
        int m0 = grp_off[ze], m1 = grp_off[ze + 1];
        m_count = m1 - m0;
        if ((int)blockIdx.y * BM >= m_count) return;
        aoff = (long)m0 * lda;
        coff = (long)m0 * ldc;
        boff = (long)ze * b_hi;
    } else {
        int zh = ze / zdiv, zl = ze % zdiv;
        aoff = zh * a_hi + zl * a_lo;
        boff = zh * b_hi + zl * b_lo;
        coff = zh * c_hi + zl * c_lo;
    }
    const short* Ag = (const short*)(A + aoff);
    const short* Bg = (const short*)(B + boff);
    const float* biasp = bias ? bias + (long)ze * bias_stride : nullptr;
    float* Cf = (float*)Cv + coff;
    bf16*  Cb = (bf16*)Cv + coff;

    __shared__ short As[BM * 32];
    __shared__ short Bs[BN * 32];

    int tid = threadIdx.x;
    int wv = tid >> 6, ln = tid & 63;
    int wr = wv >> 1, wc = wv & 1;
    int fr = ln & 15, fq = ln >> 4;
    int bm = blockIdx.y * BM, bn = blockIdx.x * BN;

    f4v acc[WM][WN] = {};

    for (int k0 = ks * kper; k0 < (ks + 1) * kper; k0 += 32) {
        #pragma unroll
        for (int is = 0; is < AISS; ++is) {
            int c = is * 256 + wv * 64 + ln;
            int m = c >> 2, kq = c & 3;
            gload16(Ag + (long)(bm + m) * lda + k0 + kq * 8,
                    &As[(is * 256 + wv * 64) * 8]);
        }
        #pragma unroll
        for (int is = 0; is < BISS; ++is) {
            int c = is * 256 + wv * 64 + ln;
            int m = c >> 2, kq = c & 3;
            gload16(Bg + (long)(bn + m) * ldb + k0 + kq * 8,
                    &Bs[(is * 256 + wv * 64) * 8]);
        }
        __syncthreads();
        s8v av[WM], bv[WN];
        #pragma unroll
        for (int i = 0; i < WM; ++i)
            av[i] = *(const s8v*)&As[(wr * (WM * 16) + i * 16 + fr) * 32 + fq * 8];
        #pragma unroll
        for (int j = 0; j < WN; ++j)
            bv[j] = *(const s8v*)&Bs[(wc * (WN * 16) + j * 16 + fr) * 32 + fq * 8];
        #pragma unroll
        for (int i = 0; i < WM; ++i)
            #pragma unroll
            for (int j = 0; j < WN; ++j)
                acc[i][j] = __builtin_amdgcn_mfma_f32_16x16x32_bf16(av[i], bv[j], acc[i][j], 0, 0, 0);
        __syncthreads();
    }

    #pragma unroll
    for (int i = 0; i < WM; ++i) {
        #pragma unroll
        for (int r = 0; r < 4; ++r) {
            int row = bm + wr * (WM * 16) + i * 16 + fq * 4 + r;
            if (GROUPED && row >= m_count) continue;
            #pragma unroll
            for (int j = 0; j < WN; ++j) {
                int col = bn + wc * (WN * 16) + j * 16 + fr;
                if (col < N) {
                    float v = acc[i][j][r] * alpha;
                    if (OUTMODE == 2) {
                        atomicAdd(&Cf[(long)row * ldc + col], v);
                    } else {
                        if (biasp) v += biasp[col];
                        if (GELU) v = 0.5f * v * (1.f + erff(v * 0.70710678118654752f));
                        if (resid) v += resid[(long)row * ldc + col];
                        if (OUTMODE == 1) Cb[(long)row * ldc + col] = __float2bfloat16(v);
                        else              Cf[(long)row * ldc + col] = v;
                    }
                }
            }
        }
    }
}

// ---------------- MoE grouped GEMM: BM=256, BN=64, expert->XCD pinned ----------
// 1-D grid, bid decode: e = bid&7 (XCD affinity), then xt, yt, ks.
// A bf16 [rows][lda] (rows grouped by grp_off), B bf16 [e][N][ldb] (row=n, K-major).
// OUTMODE: 1 = bf16 store (+bias,+GELU opt), 2 = f32 atomicAdd.
template<int XT, int YCAP, int KS, bool GELU, int OUTMODE>
__global__ __launch_bounds__(256) void moe_gemm(
    const bf16* __restrict__ A, const bf16* __restrict__ B,
    const float* __restrict__ bias, void* __restrict__ Cv,
    int lda, int ldb, int ldc, int Ktot, long b_hi, long bias_stride,
    const int* __restrict__ grp_off, int N)
{
    int bid = blockIdx.x;
    int e = bid & 7;
    int r = bid >> 3;
    int xt = r % XT; r /= XT;
    int yt = r % YCAP;
    int ks = r / YCAP;
    int m0 = grp_off[e], m1 = grp_off[e + 1];
    int m_count = m1 - m0;
    int bm = yt * 256;
    if (bm >= m_count) return;
    int bn = xt * 64;
    int kper = Ktot / KS;

    const short* Ag = (const short*)A + (long)m0 * lda;
    const short* Bg = (const short*)(B + (long)e * b_hi);
    const float* biasp = bias ? bias + (long)e * bias_stride : nullptr;
    float* Cf = (float*)Cv + (long)m0 * ldc;
    bf16*  Cb = (bf16*)Cv + (long)m0 * ldc;

    __shared__ short As[256 * 32];   // [m][k], rows of 64B
    __shared__ short Bs[64 * 32];    // [n][k]

    int tid = threadIdx.x;
    int wv = tid >> 6, ln = tid & 63;   // 4 waves stacked along M
    int fr = ln & 15, fq = ln >> 4;

    f4v acc[4][4] = {};

    for (int k0 = ks * kper; k0 < (ks + 1) * kper; k0 += 32) {
        #pragma unroll
        for (int is = 0; is < 4; ++is) {
            int c = is * 256 + wv * 64 + ln;       // A chunk 0..1023
            int m = c >> 2, kq = c & 3;
            gload16(Ag + (long)(bm + m) * lda + k0 + kq * 8,
                    &As[(is * 256 + wv * 64) * 8]);
        }
        {
            int c = wv * 64 + ln;                   // B chunk 0..255
            int n = c >> 2, kq = c & 3;
            gload16(Bg + (long)(bn + n) * ldb + k0 + kq * 8,
                    &Bs[(wv * 64) * 8]);
        }
        __syncthreads();
        s8v av[4], bv[4];
        #pragma unroll
        for (int i = 0; i < 4; ++i)
            av[i] = *(const s8v*)&As[(wv * 64 + i * 16 + fr) * 32 + fq * 8];
        #pragma unroll
        for (int j = 0; j < 4; ++j)
            bv[j] = *(const s8v*)&Bs[(j * 16 + fr) * 32 + fq * 8];
        #pragma unroll
        for (int i = 0; i < 4; ++i)
            #pragma unroll
            for (int j = 0; j < 4; ++j)
                acc[i][j] = __builtin_amdgcn_mfma_f32_16x16x32_bf16(av[i], bv[j], acc[i][j], 0, 0, 0);
        __syncthreads();
    }

    #pragma unroll
    for (int i = 0; i < 4; ++i) {
        #pragma unroll
        for (int rr = 0; rr < 4; ++rr) {
            int row = bm + wv * 64 + i * 16 + fq * 4 + rr;
            if (row >= m_count) continue;
            #pragma unroll
            for (int j = 0; j < 4; ++j) {
                int col = bn + j * 16 + fr;
                float v = acc[i][j][rr];
                if (OUTMODE == 2) {
                    atomicAdd(&Cf[(long)row * ldc + col], v);
                } else {
                    if (biasp) v += biasp[col];
                    if (GELU) v = 0.5f * v * (1.f + erff(v * 0.70710678118654752f));
                    Cb[(long)row * ldc + col] = __float2bfloat16(v);
                }
            }
        }
    }
}

// ---------------- row softmax over 512 (f32 in, bf16 out) ----------------
__global__ __launch_bounds__(256) void softmax512(const float* __restrict__ s,
                                                  bf16* __restrict__ attn) {
    long row = blockIdx.x;
    const float* p = s + row * 512;
    int tid = threadIdx.x;
    float a = p[tid], b = p[tid + 256];
    float m = fmaxf(a, b);
    __shared__ float red[4], red2[4];
    #pragma unroll
    for (int o = 32; o; o >>= 1) m = fmaxf(m, __shfl_xor(m, o));
    if ((tid & 63) == 0) red[tid >> 6] = m;
    __syncthreads();
    m = fmaxf(fmaxf(red[0], red[1]), fmaxf(red[2], red[3]));
    float e0 = expf(a - m), e1 = expf(b - m);
    float ssum = e0 + e1;
    #pragma unroll
    for (int o = 32; o; o >>= 1) ssum += __shfl_xor(ssum, o);
    if ((tid & 63) == 0) red2[tid >> 6] = ssum;
    __syncthreads();
    ssum = red2[0] + red2[1] + red2[2] + red2[3];
    float inv = 1.f / ssum;
    bf16* ar = attn + row * 512;
    ar[tid]       = __float2bfloat16(e0 * inv);
    ar[tid + 256] = __float2bfloat16(e1 * inv);
}

// ---------------- V transpose: qkv bf16 [tok][2304] -> vt [z][64][512] ------
__global__ __launch_bounds__(256) void vt_kernel(const bf16* __restrict__ qkvb,
                                                 bf16* __restrict__ vt) {
    int st = blockIdx.x;
    int z = blockIdx.y;
    int b = z / HEADS, h = z % HEADS;
    __shared__ short tile[64][65];
    int t = threadIdx.x;
    int d = t & 63, s0 = t >> 6;
    const short* q = (const short*)qkvb;
    #pragma unroll
    for (int i = 0; i < 16; ++i) {
        int s = st * 64 + s0 + i * 4;
        tile[s0 + i * 4][d] = q[(long)(b * SEQ + s) * 2304 + 2 * DIM + h * HDIM + d];
    }
    __syncthreads();
    short* o = (short*)vt;
    #pragma unroll
    for (int i = 0; i < 16; ++i) {
        int d2 = (t >> 6) + i * 4;
        o[(long)(z * 64 + d2) * 512 + st * 64 + (t & 63)] = tile[t & 63][d2];
    }
}

// ---------------- weight transpose-convert: f32 [z][R][C] -> bf16 [z][C][R] --
__global__ __launch_bounds__(256) void wtrans_kernel(const float* __restrict__ in,
                                                     bf16* __restrict__ out,
                                                     int R, int C) {
    int z = blockIdx.z;
    long ibase = (long)z * R * C;
    int rt = blockIdx.y * 64, ct = blockIdx.x * 64;
    __shared__ float tile[64][65];
    int t = threadIdx.x;
    int c = t & 63, r0 = t >> 6;
    #pragma unroll
    for (int i = 0; i < 16; ++i)
        tile[r0 + i * 4][c] = in[ibase + (long)(rt + r0 + i * 4) * C + ct + c];
    __syncthreads();
    #pragma unroll
    for (int i = 0; i < 16; ++i) {
        int cc = r0 + i * 4;
        out[ibase + (long)(ct + cc) * R + rt + c] = __float2bfloat16(tile[c][cc]);
    }
}

// ---------------- straight f32 -> bf16 convert ----------------
__global__ __launch_bounds__(256) void cvt_kernel(const float* __restrict__ in,
                                                  bf16* __restrict__ out, long n) {
    long i = ((long)blockIdx.x * 256 + threadIdx.x) * 4;
    if (i >= n) return;
    float4 v = *(const float4*)(in + i);
    out[i]     = __float2bfloat16(v.x);
    out[i + 1] = __float2bfloat16(v.y);
    out[i + 2] = __float2bfloat16(v.z);
    out[i + 3] = __float2bfloat16(v.w);
}

// ---------------- router: logits, softmax, top2, renorm ----------------
__global__ __launch_bounds__(64) void router_kernel(const float* __restrict__ t2,
                                                    const float* __restrict__ rw,
                                                    const float* __restrict__ rb,
                                                    int* __restrict__ e_sel,
                                                    float* __restrict__ w_sel) {
    int t = blockIdx.x;
    int lane = threadIdx.x;
    const float* tr = t2 + (long)t * DIM;
    float tv[12];
    #pragma unroll
    for (int i = 0; i < 12; ++i) tv[i] = tr[lane + 64 * i];
    float logits[NEXP];
    #pragma unroll
    for (int e = 0; e < NEXP; ++e) {
        const float* wr = rw + (long)e * DIM;
        float s = 0.f;
        #pragma unroll
        for (int i = 0; i < 12; ++i) s += tv[i] * wr[lane + 64 * i];
        #pragma unroll
        for (int o = 32; o; o >>= 1) s += __shfl_xor(s, o);
        logits[e] = s + rb[e];
    }
    if (lane == 0) {
        int e0 = -1, e1 = -1;
        float l0 = -1e30f, l1 = -1e30f;
        #pragma unroll
        for (int e = 0; e < NEXP; ++e) {
            float l = logits[e];
            if (l > l0) { l1 = l0; e1 = e0; l0 = l; e0 = e; }
            else if (l > l1) { l1 = l; e1 = e; }
        }
        float p1 = expf(l1 - l0);
        float inv = 1.f / (1.f + p1);
        e_sel[t * 2] = e0;  e_sel[t * 2 + 1] = e1;
        w_sel[t * 2] = inv; w_sel[t * 2 + 1] = p1 * inv;
    }
}

// ---------------- build per-expert entry lists (single block) ----------------
__global__ __launch_bounds__(1024) void build_lists(const int* __restrict__ e_sel,
                                                    int* __restrict__ entry_tok,
                                                    int* __restrict__ ent_exp,
                                                    int* __restrict__ pos,
                                                    int* __restrict__ grp_off) {
    __shared__ int cnt[NEXP];
    __shared__ int off[NEXP + 1];
    __shared__ int cur[NEXP];
    int tid = threadIdx.x;
    if (tid < NEXP) cnt[tid] = 0;
    __syncthreads();
    for (int i = tid; i < NENT; i += 1024) atomicAdd(&cnt[e_sel[i]], 1);
    __syncthreads();
    if (tid == 0) {
        off[0] = 0;
        for (int e = 0; e < NEXP; ++e) off[e + 1] = off[e] + cnt[e];
        for (int e = 0; e < NEXP; ++e) cur[e] = off[e];
    }
    __syncthreads();
    for (int i = tid; i < NENT; i += 1024) {
        int e = e_sel[i];
        int p = atomicAdd(&cur[e], 1);
        entry_tok[p] = i >> 1;
        ent_exp[p] = e;
        pos[i] = p;
    }
    if (tid < NEXP + 1) grp_off[tid] = off[tid];
}

// ---------------- gather rows (bf16, 8B units) ----------------
__global__ __launch_bounds__(256) void gather_kernel(const bf16* __restrict__ t2b,
                                                     const int* __restrict__ entry_tok,
                                                     bf16* __restrict__ t2g) {
    long i = (long)blockIdx.x * 256 + threadIdx.x;
    if (i >= (long)NENT * 192) return;
    int p = (int)(i / 192), q = (int)(i % 192);
    ((uint2*)t2g)[(long)p * 192 + q] = ((const uint2*)t2b)[(long)entry_tok[p] * 192 + q];
}

// ---------------- prefill x1 = x + out_b ----------------
__global__ __launch_bounds__(256) void prefill_x1(const float* __restrict__ x,
                                                  const float* __restrict__ out_b,
                                                  float* __restrict__ x1) {
    long i = ((long)blockIdx.x * 256 + threadIdx.x) * 4;
    if (i >= (long)NTOK * DIM) return;
    int d = (int)(i % DIM);
    float4 v = *(const float4*)(x + i);
    v.x += out_b[d]; v.y += out_b[d + 1]; v.z += out_b[d + 2]; v.w += out_b[d + 3];
    *(float4*)(x1 + i) = v;
}

// ---------------- prefill ybuf[p][.] = b2[exp(p)][.] ----------------
__global__ __launch_bounds__(256) void prefill_ybuf(const float* __restrict__ b2,
                                                    const int* __restrict__ ent_exp,
                                                    float* __restrict__ ybuf) {
    long i = ((long)blockIdx.x * 256 + threadIdx.x) * 4;
    if (i >= (long)NENT * DIM) return;
    int p = (int)(i / DIM), d = (int)(i % DIM);
    *(float4*)(ybuf + i) = *(const float4*)(b2 + (long)ent_exp[p] * DIM + d);
}

// ---------------- final combine: out = x1 + w0*y(pos0) + w1*y(pos1) ----------
__global__ __launch_bounds__(256) void combine_kernel(const float* __restrict__ x1,
                                                      const float* __restrict__ ybuf,
                                                      const int* __restrict__ pos,
                                                      const float* __restrict__ wsel,
                                                      float* __restrict__ out) {
    long i = (long)blockIdx.x * 256 + threadIdx.x;
    if (i >= (long)NTOK * DIM) return;
    int t = (int)(i / DIM), d = (int)(i % DIM);
    float v = x1[i];
    v += wsel[t * 2]     * ybuf[(long)pos[t * 2]     * DIM + d];
    v += wsel[t * 2 + 1] * ybuf[(long)pos[t * 2 + 1] * DIM + d];
    out[i] = v;
}

extern "C" void kernel_launch(void* const* d_in, const int* in_sizes, int n_in,
                              void* d_out, int out_size, void* d_ws, size_t ws_size,
                              hipStream_t stream) {
    const float* x        = (const float*)d_in[0];
    const float* ln1_g    = (const float*)d_in[1];
    const float* ln1_b    = (const float*)d_in[2];
    const float* ln2_g    = (const float*)d_in[3];
    const float* ln2_b    = (const float*)d_in[4];
    const float* in_w     = (const float*)d_in[5];
    const float* in_b     = (const float*)d_in[6];
    const float* out_w    = (const float*)d_in[7];
    const float* out_b    = (const float*)d_in[8];
    const float* router_w = (const float*)d_in[9];
    const float* router_b = (const float*)d_in[10];
    const float* w1       = (const float*)d_in[11];
    const float* b1       = (const float*)d_in[12];
    const float* w2       = (const float*)d_in[13];
    const float* b2       = (const float*)d_in[14];
    float* out = (float*)d_out;

    const long TD = (long)NTOK * DIM;
    char* p = (char*)d_ws;
    size_t off = 0;
    auto alloc = [&](size_t bytes) -> void* {
        void* r = p + off; off += (bytes + 255) & ~(size_t)255; return r;
    };
    bf16*  h_b    = (bf16*)alloc(TD * 2);
    bf16*  in_wb  = (bf16*)alloc(2304L * 768 * 2);
    bf16*  qkv_b  = (bf16*)alloc(1024L * 2304 * 2);
    bf16*  out_wb = (bf16*)alloc(768L * 768 * 2);
    bf16*  vt_b   = (bf16*)alloc((24L * 64 + 64) * 512 * 2);
    bf16*  oat_b  = (bf16*)alloc(TD * 2);
    float* x1     = (float*)alloc(TD * 4);
    float* t2     = (float*)alloc(TD * 4);
    bf16*  t2b    = (bf16*)alloc(TD * 2);
    bf16*  t2g    = (bf16*)alloc((2048L + 256) * 768 * 2);     // +256-row pad (BM=256 overread)
    bf16*  w1t    = (bf16*)alloc(8L * 3072 * 768 * 2);         // aliased: scores f32 + attn bf16
    bf16*  w2t    = (bf16*)alloc(8L * 768 * 3072 * 2);
    bf16*  hid    = (bf16*)alloc((2048L + 256) * 3072 * 2);    // +256-row pad
    float* ybuf   = (float*)alloc(2048L * 768 * 4);
    int*   e_sel     = (int*)alloc(NENT * 4);
    float* w_sel     = (float*)alloc(NENT * 4);
    int*   entry_tok = (int*)alloc(NENT * 4);
    int*   ent_exp   = (int*)alloc(NENT * 4);
    int*   pos       = (int*)alloc(NENT * 4);
    int*   grp_off   = (int*)alloc(64);
    float* scores = (float*)w1t;
    bf16*  attn   = (bf16*)((char*)w1t + 24L * 512 * 512 * 4);

    // 1. LN1 -> h bf16
    ln_kernel<<<NTOK, 256, 0, stream>>>(x, ln1_g, ln1_b, nullptr, h_b);
    // 2-3. weight converts
    cvt_kernel<<<1728, 256, 0, stream>>>(in_w, in_wb, 2304L * 768);
    cvt_kernel<<<576, 256, 0, stream>>>(out_w, out_wb, 768L * 768);
    // 4. qkv = h @ in_w^T + in_b -> bf16 [1024,2304]
    mfma_gemm<2, 4, false, false, 1><<<dim3(18, 16, 1), 256, 0, stream>>>(
        h_b, in_wb, in_b, nullptr, qkv_b,
        NTOK, 3 * DIM, DIM, DIM, DIM, 3 * DIM,
        1, 1, 0, 0, 0, 0, 0, 0, 0, nullptr, 1.f);
    // 5. scores = Q @ K^T / 8 -> f32 [24][512][512]
    mfma_gemm<2, 4, false, false, 0><<<dim3(4, 8, 24), 256, 0, stream>>>(
        qkv_b, qkv_b + DIM, nullptr, nullptr, scores,
        SEQ, SEQ, HDIM, 3 * DIM, 3 * DIM, SEQ,
        HEADS, 1, (long)SEQ * 3 * DIM, HDIM, (long)SEQ * 3 * DIM, HDIM,
        (long)HEADS * SEQ * SEQ, (long)SEQ * SEQ,
        0, nullptr, 0.125f);
    // 6. softmax -> attn bf16
    softmax512<<<24 * SEQ, 256, 0, stream>>>(scores, attn);
    // 7. V transpose
    vt_kernel<<<dim3(8, 24), 256, 0, stream>>>(qkv_b, vt_b);
    // 8. o = attn @ V -> oat bf16
    mfma_gemm<2, 2, false, false, 1><<<dim3(1, 8, 24), 256, 0, stream>>>(
        attn, vt_b, nullptr, nullptr, oat_b,
        SEQ, HDIM, SEQ, SEQ, SEQ, DIM,
        HEADS, 1, (long)HEADS * SEQ * SEQ, (long)SEQ * SEQ,
        (long)HEADS * HDIM * SEQ, (long)HDIM * SEQ,
        (long)SEQ * DIM, HDIM,
        0, nullptr, 1.f);
    // 9a. prefill x1 = x + out_b
    prefill_x1<<<768, 256, 0, stream>>>(x, out_b, x1);
    // 9b. x1 += oat @ out_w^T   (split-K x2, atomic)
    mfma_gemm<2, 4, false, false, 2><<<dim3(6, 16, 2), 256, 0, stream>>>(
        oat_b, out_wb, nullptr, nullptr, x1,
        NTOK, DIM, DIM, DIM, DIM, DIM,
        1, 2, 0, 0, 0, 0, 0, 0, 0, nullptr, 1.f);
    // 10. LN2 -> t2 f32 + t2b bf16
    ln_kernel<<<NTOK, 256, 0, stream>>>(x1, ln2_g, ln2_b, t2, t2b);
    // 11. router
    router_kernel<<<NTOK, 64, 0, stream>>>(t2, router_w, router_b, e_sel, w_sel);
    // 12. build lists
    build_lists<<<1, 1024, 0, stream>>>(e_sel, entry_tok, ent_exp, pos, grp_off);
    // 13. gather bf16
    gather_kernel<<<1536, 256, 0, stream>>>(t2b, entry_tok, t2g);
    // 14. w1 transpose-convert (after PV: overwrites scores/attn region)
    wtrans_kernel<<<dim3(48, 12, 8), 256, 0, stream>>>(w1, w1t, DIM, FFDIM);
    // 15. FFN1 grouped: hid = gelu(t2g @ w1t^T + b1) -> bf16
    //     BM=256 (B read once), BN=64 (XT=48), expert->XCD pinned, 384 active blocks
    moe_gemm<48, 8, 1, true, 1><<<8 * 48 * 8, 256, 0, stream>>>(
        t2g, w1t, b1, hid,
        DIM, DIM, FFDIM, DIM, (long)FFDIM * DIM, FFDIM, grp_off, FFDIM);
    // 16. w2 transpose-convert
    wtrans_kernel<<<dim3(12, 48, 8), 256, 0, stream>>>(w2, w2t, FFDIM, DIM);
    // 17a. prefill ybuf with b2 rows
    prefill_ybuf<<<1536, 256, 0, stream>>>(b2, ent_exp, ybuf);
    // 17b. FFN2 grouped split-K x4 (atomic): ybuf += hid @ w2t^T
    //      BM=256, BN=64 (XT=12), KS=4, 384 active blocks
    moe_gemm<12, 8, 4, false, 2><<<8 * 12 * 8 * 4, 256, 0, stream>>>(
        hid, w2t, nullptr, ybuf,
        FFDIM, FFDIM, DIM, FFDIM, (long)DIM * FFDIM, 0, grp_off, DIM);
    // 18. combine
    combine_kernel<<<3072, 256, 0, stream>>>(x1, ybuf, pos, w_sel, out);
}

// Round 5
// 213.944 us; speedup vs baseline: 4.2561x; 1.1009x over previous
//
#include <hip/hip_runtime.h>
#include <hip/hip_bf16.h>

// Problem constants
#define BATCH 2
#define SEQ 512
#define DIM 768
#define HEADS 12
#define NEXP 8
#define FFDIM 3072
#define HDIM 64
#define NTOK (BATCH*SEQ)          // 1024
#define NENT (2*NTOK)             // 2048 (token, slot) entries

typedef __hip_bfloat16 bf16;
typedef __attribute__((ext_vector_type(8))) short s8v;
typedef __attribute__((ext_vector_type(4))) float f4v;

// ---- async global->LDS (16B per lane, wave-uniform LDS base + lane*16) ----
typedef __attribute__((address_space(1))) const unsigned char gas_u8;
typedef __attribute__((address_space(3))) unsigned char las_u8;
__device__ __forceinline__ void gload16(const void* g, void* l) {
    __builtin_amdgcn_global_load_lds((gas_u8*)g, (las_u8*)l, 16, 0, 0);
}

// ---------------- LayerNorm: one block per token, 256 threads ----------------
__global__ __launch_bounds__(256) void ln_kernel(const float* __restrict__ x,
                                                 const float* __restrict__ g,
                                                 const float* __restrict__ b,
                                                 float* __restrict__ outf,
                                                 bf16* __restrict__ outb) {
    int t = blockIdx.x;
    const float* xr = x + (long)t * DIM;
    int tid = threadIdx.x;
    float v0 = xr[tid], v1 = xr[tid + 256], v2 = xr[tid + 512];
    float s = v0 + v1 + v2;
    __shared__ float red[4];
    #pragma unroll
    for (int o = 32; o; o >>= 1) s += __shfl_xor(s, o);
    if ((tid & 63) == 0) red[tid >> 6] = s;
    __syncthreads();
    s = red[0] + red[1] + red[2] + red[3];
    float mu = s * (1.f / DIM);
    float d0 = v0 - mu, d1 = v1 - mu, d2 = v2 - mu;
    float q = d0*d0 + d1*d1 + d2*d2;
    __shared__ float red2[4];
    #pragma unroll
    for (int o = 32; o; o >>= 1) q += __shfl_xor(q, o);
    if ((tid & 63) == 0) red2[tid >> 6] = q;
    __syncthreads();
    q = red2[0] + red2[1] + red2[2] + red2[3];
    float rstd = rsqrtf(q * (1.f / DIM) + 1e-5f);
    float o0 = d0 * rstd * g[tid]       + b[tid];
    float o1 = d1 * rstd * g[tid + 256] + b[tid + 256];
    float o2 = d2 * rstd * g[tid + 512] + b[tid + 512];
    if (outf) {
        float* of = outf + (long)t * DIM;
        of[tid] = o0; of[tid + 256] = o1; of[tid + 512] = o2;
    }
    if (outb) {
        bf16* ob = outb + (long)t * DIM;
        ob[tid] = __float2bfloat16(o0);
        ob[tid + 256] = __float2bfloat16(o1);
        ob[tid + 512] = __float2bfloat16(o2);
    }
}

// ---------------- MFMA GEMM, parameterized tile (attention-side) ----------------
// C[m,n] = alpha * sum_k A[m,k] * B[n,k]   (A,B bf16 row-major [.][K])
// Tile BM=32*WM x BN=32*WN, 4 waves in 2x2 grid.
// OUTMODE: 0 = f32 store, 1 = bf16 store, 2 = f32 atomicAdd.
template<int WM, int WN, bool GROUPED, bool GELU, int OUTMODE>
__global__ __launch_bounds__(256) void mfma_gemm(
    const bf16* __restrict__ A, const bf16* __restrict__ B,
    const float* __restrict__ bias, const float* __restrict__ resid,
    void* __restrict__ Cv,
    int M, int N, int K, int lda, int ldb, int ldc,
    int zdiv, int ksplit,
    long a_hi, long a_lo, long b_hi, long b_lo, long c_hi, long c_lo,
    long bias_stride, const int* __restrict__ grp_off, float alpha)
{
    constexpr int BM = 32 * WM, BN = 32 * WN;
    constexpr int ACH = BM * 4;     // 16B chunks in A tile
    constexpr int BCH = BN * 4;

    int z = blockIdx.z;
    int ze = z / ksplit, ks = z % ksplit;
    int kper = K / ksplit;
    long aoff, boff, coff;
    int m_count = M;
    if (GROUPED) {
        int m0 = grp_off[ze], m1 = grp_off[ze + 1];
        m_count = m1 - m0;
        if ((int)blockIdx.y * BM >= m_count) return;
        aoff = (long)m0 * lda;
        coff = (long)m0 * ldc;
        boff = (long)ze * b_hi;
    } else {
        int zh = ze / zdiv, zl = ze % zdiv;
        aoff = zh * a_hi + zl * a_lo;
        boff = zh * b_hi + zl * b_lo;
        coff = zh * c_hi + zl * c_lo;
    }
    const short* Ag = (const short*)(A + aoff);
    const short* Bg = (const short*)(B + boff);
    const float* biasp = bias ? bias + (long)ze * bias_stride : nullptr;
    float* Cf = (float*)Cv + coff;
    bf16*  Cb = (bf16*)Cv + coff;

    __shared__ short As[BM * 32];
    __shared__ short Bs[BN * 32];

    int tid = threadIdx.x;
    int wv = tid >> 6, ln = tid & 63;
    int wr = wv >> 1, wc = wv & 1;
    int fr = ln & 15, fq = ln >> 4;
    int bm = blockIdx.y * BM, bn = blockIdx.x * BN;

    f4v acc[WM][WN] = {};

    for (int k0 = ks * kper; k0 < (ks + 1) * kper; k0 += 32) {
        #pragma unroll
        for (int is = 0; is < ACH / 256; ++is) {
            int c = is * 256 + wv * 64 + ln;
            int m = c >> 2, kq = c & 3;
            gload16(Ag + (long)(bm + m) * lda + k0 + kq * 8,
                    &As[(is * 256 + wv * 64) * 8]);
        }
        if constexpr (ACH % 256) {
            if (tid < ACH % 256) {
                int c = (ACH / 256) * 256 + tid;
                int m = c >> 2, kq = c & 3;
                gload16(Ag + (long)(bm + m) * lda + k0 + kq * 8,
                        &As[((ACH / 256) * 256 + wv * 64) * 8]);
            }
        }
        #pragma unroll
        for (int is = 0; is < BCH / 256; ++is) {
            int c = is * 256 + wv * 64 + ln;
            int m = c >> 2, kq = c & 3;
            gload16(Bg + (long)(bn + m) * ldb + k0 + kq * 8,
                    &Bs[(is * 256 + wv * 64) * 8]);
        }
        if constexpr (BCH % 256) {
            if (tid < BCH % 256) {
                int c = (BCH / 256) * 256 + tid;
                int m = c >> 2, kq = c & 3;
                gload16(Bg + (long)(bn + m) * ldb + k0 + kq * 8,
                        &Bs[((BCH / 256) * 256 + wv * 64) * 8]);
            }
        }
        __syncthreads();
        s8v av[WM], bv[WN];
        #pragma unroll
        for (int i = 0; i < WM; ++i)
            av[i] = *(const s8v*)&As[(wr * (WM * 16) + i * 16 + fr) * 32 + fq * 8];
        #pragma unroll
        for (int j = 0; j < WN; ++j)
            bv[j] = *(const s8v*)&Bs[(wc * (WN * 16) + j * 16 + fr) * 32 + fq * 8];
        #pragma unroll
        for (int i = 0; i < WM; ++i)
            #pragma unroll
            for (int j = 0; j < WN; ++j)
                acc[i][j] = __builtin_amdgcn_mfma_f32_16x16x32_bf16(av[i], bv[j], acc[i][j], 0, 0, 0);
        __syncthreads();
    }

    #pragma unroll
    for (int i = 0; i < WM; ++i) {
        #pragma unroll
        for (int r = 0; r < 4; ++r) {
            int row = bm + wr * (WM * 16) + i * 16 + fq * 4 + r;
            if (GROUPED && row >= m_count) continue;
            #pragma unroll
            for (int j = 0; j < WN; ++j) {
                int col = bn + wc * (WN * 16) + j * 16 + fr;
                if (col < N) {
                    float v = acc[i][j][r] * alpha;
                    if (OUTMODE == 2) {
                        atomicAdd(&Cf[(long)row * ldc + col], v);
                    } else {
                        if (biasp) v += biasp[col];
                        if (GELU) v = 0.5f * v * (1.f + erff(v * 0.70710678118654752f));
                        if (resid) v += resid[(long)row * ldc + col];
                        if (OUTMODE == 1) Cb[(long)row * ldc + col] = __float2bfloat16(v);
                        else              Cf[(long)row * ldc + col] = v;
                    }
                }
            }
        }
    }
}

// ---------------- MoE grouped GEMM: BM=128, BN=64, expert->XCD pinned ----------
// 1-D grid, bid decode: e = bid&7 (XCD affinity), then xt, yt, ks.
// A bf16 [rows][lda] (rows grouped by grp_off), B bf16 [e][N][ldb] (row=n, K-major).
// 4 waves in 2(M)x2(N) grid; per-wave 64m x 32n (acc 4x2).
// OUTMODE: 1 = bf16 store (+bias,+GELU opt), 2 = f32 atomicAdd.
template<int XT, int YCAP, int KS, bool GELU, int OUTMODE>
__global__ __launch_bounds__(256) void moe_gemm(
    const bf16* __restrict__ A, const bf16* __restrict__ B,
    const float* __restrict__ bias, void* __restrict__ Cv,
    int lda, int ldb, int ldc, int Ktot, long b_hi, long bias_stride,
    const int* __restrict__ grp_off, int N)
{
    int bid = blockIdx.x;
    int e = bid & 7;
    int r = bid >> 3;
    int xt = r % XT; r /= XT;
    int yt = r % YCAP;
    int ks = r / YCAP;
    int m0 = grp_off[e], m1 = grp_off[e + 1];
    int m_count = m1 - m0;
    int bm = yt * 128;
    if (bm >= m_count) return;
    int bn = xt * 64;
    int kper = Ktot / KS;

    const short* Ag = (const short*)A + (long)m0 * lda;
    const short* Bg = (const short*)(B + (long)e * b_hi);
    const float* biasp = bias ? bias + (long)e * bias_stride : nullptr;
    float* Cf = (float*)Cv + (long)m0 * ldc;
    bf16*  Cb = (bf16*)Cv + (long)m0 * ldc;

    __shared__ short As[128 * 32];   // [m][k], rows of 64B
    __shared__ short Bs[64 * 32];    // [n][k]

    int tid = threadIdx.x;
    int wv = tid >> 6, ln = tid & 63;
    int wr = wv >> 1, wc = wv & 1;      // 2x2 wave grid: 64m x 32n per wave
    int fr = ln & 15, fq = ln >> 4;

    f4v acc[4][2] = {};

    for (int k0 = ks * kper; k0 < (ks + 1) * kper; k0 += 32) {
        #pragma unroll
        for (int is = 0; is < 2; ++is) {
            int c = is * 256 + wv * 64 + ln;       // A chunks 0..511
            int m = c >> 2, kq = c & 3;
            gload16(Ag + (long)(bm + m) * lda + k0 + kq * 8,
                    &As[(is * 256 + wv * 64) * 8]);
        }
        {
            int c = wv * 64 + ln;                   // B chunks 0..255
            int n = c >> 2, kq = c & 3;
            gload16(Bg + (long)(bn + n) * ldb + k0 + kq * 8,
                    &Bs[(wv * 64) * 8]);
        }
        __syncthreads();
        s8v av[4], bv[2];
        #pragma unroll
        for (int i = 0; i < 4; ++i)
            av[i] = *(const s8v*)&As[(wr * 64 + i * 16 + fr) * 32 + fq * 8];
        #pragma unroll
        for (int j = 0; j < 2; ++j)
            bv[j] = *(const s8v*)&Bs[(wc * 32 + j * 16 + fr) * 32 + fq * 8];
        #pragma unroll
        for (int i = 0; i < 4; ++i)
            #pragma unroll
            for (int j = 0; j < 2; ++j)
                acc[i][j] = __builtin_amdgcn_mfma_f32_16x16x32_bf16(av[i], bv[j], acc[i][j], 0, 0, 0);
        __syncthreads();
    }

    #pragma unroll
    for (int i = 0; i < 4; ++i) {
        #pragma unroll
        for (int rr = 0; rr < 4; ++rr) {
            int row = bm + wr * 64 + i * 16 + fq * 4 + rr;
            if (row >= m_count) continue;
            #pragma unroll
            for (int j = 0; j < 2; ++j) {
                int col = bn + wc * 32 + j * 16 + fr;
                float v = acc[i][j][rr];
                if (OUTMODE == 2) {
                    atomicAdd(&Cf[(long)row * ldc + col], v);
                } else {
                    if (biasp) v += biasp[col];
                    if (GELU) v = 0.5f * v * (1.f + erff(v * 0.70710678118654752f));
                    Cb[(long)row * ldc + col] = __float2bfloat16(v);
                }
            }
        }
    }
}

// ---------------- row softmax over 512 (f32 in, bf16 out) ----------------
__global__ __launch_bounds__(256) void softmax512(const float* __restrict__ s,
                                                  bf16* __restrict__ attn) {
    long row = blockIdx.x;
    const float* p = s + row * 512;
    int tid = threadIdx.x;
    float a = p[tid], b = p[tid + 256];
    float m = fmaxf(a, b);
    __shared__ float red[4], red2[4];
    #pragma unroll
    for (int o = 32; o; o >>= 1) m = fmaxf(m, __shfl_xor(m, o));
    if ((tid & 63) == 0) red[tid >> 6] = m;
    __syncthreads();
    m = fmaxf(fmaxf(red[0], red[1]), fmaxf(red[2], red[3]));
    float e0 = expf(a - m), e1 = expf(b - m);
    float ssum = e0 + e1;
    #pragma unroll
    for (int o = 32; o; o >>= 1) ssum += __shfl_xor(ssum, o);
    if ((tid & 63) == 0) red2[tid >> 6] = ssum;
    __syncthreads();
    ssum = red2[0] + red2[1] + red2[2] + red2[3];
    float inv = 1.f / ssum;
    bf16* ar = attn + row * 512;
    ar[tid]       = __float2bfloat16(e0 * inv);
    ar[tid + 256] = __float2bfloat16(e1 * inv);
}

// ---------------- V transpose: qkv bf16 [tok][2304] -> vt [z][64][512] ------
__global__ __launch_bounds__(256) void vt_kernel(const bf16* __restrict__ qkvb,
                                                 bf16* __restrict__ vt) {
    int st = blockIdx.x;
    int z = blockIdx.y;
    int b = z / HEADS, h = z % HEADS;
    __shared__ short tile[64][65];
    int t = threadIdx.x;
    int d = t & 63, s0 = t >> 6;
    const short* q = (const short*)qkvb;
    #pragma unroll
    for (int i = 0; i < 16; ++i) {
        int s = st * 64 + s0 + i * 4;
        tile[s0 + i * 4][d] = q[(long)(b * SEQ + s) * 2304 + 2 * DIM + h * HDIM + d];
    }
    __syncthreads();
    short* o = (short*)vt;
    #pragma unroll
    for (int i = 0; i < 16; ++i) {
        int d2 = (t >> 6) + i * 4;
        o[(long)(z * 64 + d2) * 512 + st * 64 + (t & 63)] = tile[t & 63][d2];
    }
}

// ---------------- weight transpose-convert: f32 [z][R][C] -> bf16 [z][C][R] --
__global__ __launch_bounds__(256) void wtrans_kernel(const float* __restrict__ in,
                                                     bf16* __restrict__ out,
                                                     int R, int C) {
    int z = blockIdx.z;
    long ibase = (long)z * R * C;
    int rt = blockIdx.y * 64, ct = blockIdx.x * 64;
    __shared__ float tile[64][65];
    int t = threadIdx.x;
    int c = t & 63, r0 = t >> 6;
    #pragma unroll
    for (int i = 0; i < 16; ++i)
        tile[r0 + i * 4][c] = in[ibase + (long)(rt + r0 + i * 4) * C + ct + c];
    __syncthreads();
    #pragma unroll
    for (int i = 0; i < 16; ++i) {
        int cc = r0 + i * 4;
        out[ibase + (long)(ct + cc) * R + rt + c] = __float2bfloat16(tile[c][cc]);
    }
}

// ---------------- straight f32 -> bf16 convert ----------------
__global__ __launch_bounds__(256) void cvt_kernel(const float* __restrict__ in,
                                                  bf16* __restrict__ out, long n) {
    long i = ((long)blockIdx.x * 256 + threadIdx.x) * 4;
    if (i >= n) return;
    float4 v = *(const float4*)(in + i);
    out[i]     = __float2bfloat16(v.x);
    out[i + 1] = __float2bfloat16(v.y);
    out[i + 2] = __float2bfloat16(v.z);
    out[i + 3] = __float2bfloat16(v.w);
}

// ---------------- router: logits, softmax, top2, renorm ----------------
__global__ __launch_bounds__(64) void router_kernel(const float* __restrict__ t2,
                                                    const float* __restrict__ rw,
                                                    const float* __restrict__ rb,
                                                    int* __restrict__ e_sel,
                                                    float* __restrict__ w_sel) {
    int t = blockIdx.x;
    int lane = threadIdx.x;
    const float* tr = t2 + (long)t * DIM;
    float tv[12];
    #pragma unroll
    for (int i = 0; i < 12; ++i) tv[i] = tr[lane + 64 * i];
    float logits[NEXP];
    #pragma unroll
    for (int e = 0; e < NEXP; ++e) {
        const float* wr = rw + (long)e * DIM;
        float s = 0.f;
        #pragma unroll
        for (int i = 0; i < 12; ++i) s += tv[i] * wr[lane + 64 * i];
        #pragma unroll
        for (int o = 32; o; o >>= 1) s += __shfl_xor(s, o);
        logits[e] = s + rb[e];
    }
    if (lane == 0) {
        int e0 = -1, e1 = -1;
        float l0 = -1e30f, l1 = -1e30f;
        #pragma unroll
        for (int e = 0; e < NEXP; ++e) {
            float l = logits[e];
            if (l > l0) { l1 = l0; e1 = e0; l0 = l; e0 = e; }
            else if (l > l1) { l1 = l; e1 = e; }
        }
        float p1 = expf(l1 - l0);
        float inv = 1.f / (1.f + p1);
        e_sel[t * 2] = e0;  e_sel[t * 2 + 1] = e1;
        w_sel[t * 2] = inv; w_sel[t * 2 + 1] = p1 * inv;
    }
}

// ---------------- build per-expert entry lists (single block) ----------------
__global__ __launch_bounds__(1024) void build_lists(const int* __restrict__ e_sel,
                                                    int* __restrict__ entry_tok,
                                                    int* __restrict__ ent_exp,
                                                    int* __restrict__ pos,
                                                    int* __restrict__ grp_off) {
    __shared__ int cnt[NEXP];
    __shared__ int off[NEXP + 1];
    __shared__ int cur[NEXP];
    int tid = threadIdx.x;
    if (tid < NEXP) cnt[tid] = 0;
    __syncthreads();
    for (int i = tid; i < NENT; i += 1024) atomicAdd(&cnt[e_sel[i]], 1);
    __syncthreads();
    if (tid == 0) {
        off[0] = 0;
        for (int e = 0; e < NEXP; ++e) off[e + 1] = off[e] + cnt[e];
        for (int e = 0; e < NEXP; ++e) cur[e] = off[e];
    }
    __syncthreads();
    for (int i = tid; i < NENT; i += 1024) {
        int e = e_sel[i];
        int p = atomicAdd(&cur[e], 1);
        entry_tok[p] = i >> 1;
        ent_exp[p] = e;
        pos[i] = p;
    }
    if (tid < NEXP + 1) grp_off[tid] = off[tid];
}

// ---------------- gather rows (bf16, 8B units) ----------------
__global__ __launch_bounds__(256) void gather_kernel(const bf16* __restrict__ t2b,
                                                     const int* __restrict__ entry_tok,
                                                     bf16* __restrict__ t2g) {
    long i = (long)blockIdx.x * 256 + threadIdx.x;
    if (i >= (long)NENT * 192) return;
    int p = (int)(i / 192), q = (int)(i % 192);
    ((uint2*)t2g)[(long)p * 192 + q] = ((const uint2*)t2b)[(long)entry_tok[p] * 192 + q];
}

// ---------------- prefill x1 = x + out_b ----------------
__global__ __launch_bounds__(256) void prefill_x1(const float* __restrict__ x,
                                                  const float* __restrict__ out_b,
                                                  float* __restrict__ x1) {
    long i = ((long)blockIdx.x * 256 + threadIdx.x) * 4;
    if (i >= (long)NTOK * DIM) return;
    int d = (int)(i % DIM);
    float4 v = *(const float4*)(x + i);
    v.x += out_b[d]; v.y += out_b[d + 1]; v.z += out_b[d + 2]; v.w += out_b[d + 3];
    *(float4*)(x1 + i) = v;
}

// ---------------- prefill ybuf[p][.] = b2[exp(p)][.] ----------------
__global__ __launch_bounds__(256) void prefill_ybuf(const float* __restrict__ b2,
                                                    const int* __restrict__ ent_exp,
                                                    float* __restrict__ ybuf) {
    long i = ((long)blockIdx.x * 256 + threadIdx.x) * 4;
    if (i >= (long)NENT * DIM) return;
    int p = (int)(i / DIM), d = (int)(i % DIM);
    *(float4*)(ybuf + i) = *(const float4*)(b2 + (long)ent_exp[p] * DIM + d);
}

// ---------------- final combine: out = x1 + w0*y(pos0) + w1*y(pos1) ----------
__global__ __launch_bounds__(256) void combine_kernel(const float* __restrict__ x1,
                                                      const float* __restrict__ ybuf,
                                                      const int* __restrict__ pos,
                                                      const float* __restrict__ wsel,
                                                      float* __restrict__ out) {
    long i = (long)blockIdx.x * 256 + threadIdx.x;
    if (i >= (long)NTOK * DIM) return;
    int t = (int)(i / DIM), d = (int)(i % DIM);
    float v = x1[i];
    v += wsel[t * 2]     * ybuf[(long)pos[t * 2]     * DIM + d];
    v += wsel[t * 2 + 1] * ybuf[(long)pos[t * 2 + 1] * DIM + d];
    out[i] = v;
}

extern "C" void kernel_launch(void* const* d_in, const int* in_sizes, int n_in,
                              void* d_out, int out_size, void* d_ws, size_t ws_size,
                              hipStream_t stream) {
    const float* x        = (const float*)d_in[0];
    const float* ln1_g    = (const float*)d_in[1];
    const float* ln1_b    = (const float*)d_in[2];
    const float* ln2_g    = (const float*)d_in[3];
    const float* ln2_b    = (const float*)d_in[4];
    const float* in_w     = (const float*)d_in[5];
    const float* in_b     = (const float*)d_in[6];
    const float* out_w    = (const float*)d_in[7];
    const float* out_b    = (const float*)d_in[8];
    const float* router_w = (const float*)d_in[9];
    const float* router_b = (const float*)d_in[10];
    const float* w1       = (const float*)d_in[11];
    const float* b1       = (const float*)d_in[12];
    const float* w2       = (const float*)d_in[13];
    const float* b2       = (const float*)d_in[14];
    float* out = (float*)d_out;

    const long TD = (long)NTOK * DIM;
    char* p = (char*)d_ws;
    size_t off = 0;
    auto alloc = [&](size_t bytes) -> void* {
        void* r = p + off; off += (bytes + 255) & ~(size_t)255; return r;
    };
    bf16*  h_b    = (bf16*)alloc(TD * 2);
    bf16*  in_wb  = (bf16*)alloc(2304L * 768 * 2);
    bf16*  qkv_b  = (bf16*)alloc(1024L * 2304 * 2);
    bf16*  out_wb = (bf16*)alloc(768L * 768 * 2);
    bf16*  vt_b   = (bf16*)alloc((24L * 64 + 64) * 512 * 2);
    bf16*  oat_b  = (bf16*)alloc(TD * 2);
    float* x1     = (float*)alloc(TD * 4);
    float* t2     = (float*)alloc(TD * 4);
    bf16*  t2b    = (bf16*)alloc(TD * 2);
    bf16*  t2g    = (bf16*)alloc((2048L + 256) * 768 * 2);     // +pad (BM overread)
    bf16*  w1t    = (bf16*)alloc(8L * 3072 * 768 * 2);         // aliased: scores f32 + attn bf16
    bf16*  w2t    = (bf16*)alloc(8L * 768 * 3072 * 2);
    bf16*  hid    = (bf16*)alloc((2048L + 256) * 3072 * 2);    // +pad
    float* ybuf   = (float*)alloc(2048L * 768 * 4);
    int*   e_sel     = (int*)alloc(NENT * 4);
    float* w_sel     = (float*)alloc(NENT * 4);
    int*   entry_tok = (int*)alloc(NENT * 4);
    int*   ent_exp   = (int*)alloc(NENT * 4);
    int*   pos       = (int*)alloc(NENT * 4);
    int*   grp_off   = (int*)alloc(64);
    float* scores = (float*)w1t;
    bf16*  attn   = (bf16*)((char*)w1t + 24L * 512 * 512 * 4);

    // 1. LN1 -> h bf16
    ln_kernel<<<NTOK, 256, 0, stream>>>(x, ln1_g, ln1_b, nullptr, h_b);
    // 2-3. weight converts
    cvt_kernel<<<1728, 256, 0, stream>>>(in_w, in_wb, 2304L * 768);
    cvt_kernel<<<576, 256, 0, stream>>>(out_w, out_wb, 768L * 768);
    // 4. qkv = h @ in_w^T + in_b -> bf16 [1024,2304]   BN=64: 576 blocks
    mfma_gemm<2, 2, false, false, 1><<<dim3(36, 16, 1), 256, 0, stream>>>(
        h_b, in_wb, in_b, nullptr, qkv_b,
        NTOK, 3 * DIM, DIM, DIM, DIM, 3 * DIM,
        1, 1, 0, 0, 0, 0, 0, 0, 0, nullptr, 1.f);
    // 5. scores = Q @ K^T / 8 -> f32 [24][512][512]   768 blocks
    mfma_gemm<2, 4, false, false, 0><<<dim3(4, 8, 24), 256, 0, stream>>>(
        qkv_b, qkv_b + DIM, nullptr, nullptr, scores,
        SEQ, SEQ, HDIM, 3 * DIM, 3 * DIM, SEQ,
        HEADS, 1, (long)SEQ * 3 * DIM, HDIM, (long)SEQ * 3 * DIM, HDIM,
        (long)HEADS * SEQ * SEQ, (long)SEQ * SEQ,
        0, nullptr, 0.125f);
    // 6. softmax -> attn bf16
    softmax512<<<24 * SEQ, 256, 0, stream>>>(scores, attn);
    // 7. V transpose
    vt_kernel<<<dim3(8, 24), 256, 0, stream>>>(qkv_b, vt_b);
    // 8. o = attn @ V -> oat bf16   BM=32: 384 blocks
    mfma_gemm<1, 2, false, false, 1><<<dim3(1, 16, 24), 256, 0, stream>>>(
        attn, vt_b, nullptr, nullptr, oat_b,
        SEQ, HDIM, SEQ, SEQ, SEQ, DIM,
        HEADS, 1, (long)HEADS * SEQ * SEQ, (long)SEQ * SEQ,
        (long)HEADS * HDIM * SEQ, (long)HDIM * SEQ,
        (long)SEQ * DIM, HDIM,
        0, nullptr, 1.f);
    // 9a. prefill x1 = x + out_b
    prefill_x1<<<768, 256, 0, stream>>>(x, out_b, x1);
    // 9b. x1 += oat @ out_w^T   (split-K x2, atomic)  BN=64: 384 blocks
    mfma_gemm<2, 2, false, false, 2><<<dim3(12, 16, 2), 256, 0, stream>>>(
        oat_b, out_wb, nullptr, nullptr, x1,
        NTOK, DIM, DIM, DIM, DIM, DIM,
        1, 2, 0, 0, 0, 0, 0, 0, 0, nullptr, 1.f);
    // 10. LN2 -> t2 f32 + t2b bf16
    ln_kernel<<<NTOK, 256, 0, stream>>>(x1, ln2_g, ln2_b, t2, t2b);
    // 11. router
    router_kernel<<<NTOK, 64, 0, stream>>>(t2, router_w, router_b, e_sel, w_sel);
    // 12. build lists
    build_lists<<<1, 1024, 0, stream>>>(e_sel, entry_tok, ent_exp, pos, grp_off);
    // 13. gather bf16
    gather_kernel<<<1536, 256, 0, stream>>>(t2b, entry_tok, t2g);
    // 14. w1 transpose-convert (after PV: overwrites scores/attn region)
    wtrans_kernel<<<dim3(48, 12, 8), 256, 0, stream>>>(w1, w1t, DIM, FFDIM);
    // 15. FFN1 grouped: hid = gelu(t2g @ w1t^T + b1) -> bf16
    //     BM=128, BN=64, XCD pinned; active ~768 blocks (3/CU)
    moe_gemm<48, 16, 1, true, 1><<<8 * 48 * 16, 256, 0, stream>>>(
        t2g, w1t, b1, hid,
        DIM, DIM, FFDIM, DIM, (long)FFDIM * DIM, FFDIM, grp_off, FFDIM);
    // 16. w2 transpose-convert
    wtrans_kernel<<<dim3(12, 48, 8), 256, 0, stream>>>(w2, w2t, FFDIM, DIM);
    // 17a. prefill ybuf with b2 rows
    prefill_ybuf<<<1536, 256, 0, stream>>>(b2, ent_exp, ybuf);
    // 17b. FFN2 grouped split-K x4 (atomic): ybuf += hid @ w2t^T
    //      BM=128, BN=64, KS=4; active ~768 blocks
    moe_gemm<12, 16, 4, false, 2><<<8 * 12 * 16 * 4, 256, 0, stream>>>(
        hid, w2t, nullptr, ybuf,
        FFDIM, FFDIM, DIM, FFDIM, (long)DIM * FFDIM, 0, grp_off, DIM);
    // 18. combine
    combine_kernel<<<3072, 256, 0, stream>>>(x1, ybuf, pos, w_sel, out);
}

// Round 6
// 210.454 us; speedup vs baseline: 4.3267x; 1.0166x over previous
//
#include <hip/hip_runtime.h>
#include <hip/hip_bf16.h>

// Problem constants
#define BATCH 2
#define SEQ 512
#define DIM 768
#define HEADS 12
#define NEXP 8
#define FFDIM 3072
#define HDIM 64
#define NTOK (BATCH*SEQ)          // 1024
#define NENT (2*NTOK)             // 2048 (token, slot) entries

typedef __hip_bfloat16 bf16;
typedef __attribute__((ext_vector_type(8))) short s8v;
typedef __attribute__((ext_vector_type(4))) float f4v;

// ---- async global->LDS (16B per lane, wave-uniform LDS base + lane*16) ----
typedef __attribute__((address_space(1))) const unsigned char gas_u8;
typedef __attribute__((address_space(3))) unsigned char las_u8;
__device__ __forceinline__ void gload16(const void* g, void* l) {
    __builtin_amdgcn_global_load_lds((gas_u8*)g, (las_u8*)l, 16, 0, 0);
}

// ---------------- LayerNorm: one block per token, 256 threads ----------------
__global__ __launch_bounds__(256) void ln_kernel(const float* __restrict__ x,
                                                 const float* __restrict__ g,
                                                 const float* __restrict__ b,
                                                 float* __restrict__ outf,
                                                 bf16* __restrict__ outb) {
    int t = blockIdx.x;
    const float* xr = x + (long)t * DIM;
    int tid = threadIdx.x;
    float v0 = xr[tid], v1 = xr[tid + 256], v2 = xr[tid + 512];
    float s = v0 + v1 + v2;
    __shared__ float red[4];
    #pragma unroll
    for (int o = 32; o; o >>= 1) s += __shfl_xor(s, o);
    if ((tid & 63) == 0) red[tid >> 6] = s;
    __syncthreads();
    s = red[0] + red[1] + red[2] + red[3];
    float mu = s * (1.f / DIM);
    float d0 = v0 - mu, d1 = v1 - mu, d2 = v2 - mu;
    float q = d0*d0 + d1*d1 + d2*d2;
    __shared__ float red2[4];
    #pragma unroll
    for (int o = 32; o; o >>= 1) q += __shfl_xor(q, o);
    if ((tid & 63) == 0) red2[tid >> 6] = q;
    __syncthreads();
    q = red2[0] + red2[1] + red2[2] + red2[3];
    float rstd = rsqrtf(q * (1.f / DIM) + 1e-5f);
    float o0 = d0 * rstd * g[tid]       + b[tid];
    float o1 = d1 * rstd * g[tid + 256] + b[tid + 256];
    float o2 = d2 * rstd * g[tid + 512] + b[tid + 512];
    if (outf) {
        float* of = outf + (long)t * DIM;
        of[tid] = o0; of[tid + 256] = o1; of[tid + 512] = o2;
    }
    if (outb) {
        bf16* ob = outb + (long)t * DIM;
        ob[tid] = __float2bfloat16(o0);
        ob[tid + 256] = __float2bfloat16(o1);
        ob[tid + 512] = __float2bfloat16(o2);
    }
}

// ---------------- MFMA GEMM, parameterized tile (attention-side) ----------------
// C[m,n] = alpha * sum_k A[m,k] * B[n,k]   (A,B bf16 row-major [.][K])
// Tile BM=32*WM x BN=32*WN, 4 waves in 2x2 grid.
// OUTMODE: 0 = f32 store, 1 = bf16 store, 2 = f32 atomicAdd.
template<int WM, int WN, bool GROUPED, bool GELU, int OUTMODE>
__global__ __launch_bounds__(256) void mfma_gemm(
    const bf16* __restrict__ A, const bf16* __restrict__ B,
    const float* __restrict__ bias, const float* __restrict__ resid,
    void* __restrict__ Cv,
    int M, int N, int K, int lda, int ldb, int ldc,
    int zdiv, int ksplit,
    long a_hi, long a_lo, long b_hi, long b_lo, long c_hi, long c_lo,
    long bias_stride, const int* __restrict__ grp_off, float alpha)
{
    constexpr int BM = 32 * WM, BN = 32 * WN;
    constexpr int ACH = BM * 4;     // 16B chunks in A tile
    constexpr int BCH = BN * 4;

    int z = blockIdx.z;
    int ze = z / ksplit, ks = z % ksplit;
    int kper = K / ksplit;
    long aoff, boff, coff;
    int m_count = M;
    if (GROUPED) {
        int m0 = grp_off[ze], m1 = grp_off[ze + 1];
        m_count = m1 - m0;
        if ((int)blockIdx.y * BM >= m_count) return;
        aoff = (long)m0 * lda;
        coff = (long)m0 * ldc;
        boff = (long)ze * b_hi;
    } else {
        int zh = ze / zdiv, zl = ze % zdiv;
        aoff = zh * a_hi + zl * a_lo;
        boff = zh * b_hi + zl * b_lo;
        coff = zh * c_hi + zl * c_lo;
    }
    const short* Ag = (const short*)(A + aoff);
    const short* Bg = (const short*)(B + boff);
    const float* biasp = bias ? bias + (long)ze * bias_stride : nullptr;
    float* Cf = (float*)Cv + coff;
    bf16*  Cb = (bf16*)Cv + coff;

    __shared__ short As[BM * 32];
    __shared__ short Bs[BN * 32];

    int tid = threadIdx.x;
    int wv = tid >> 6, ln = tid & 63;
    int wr = wv >> 1, wc = wv & 1;
    int fr = ln & 15, fq = ln >> 4;
    int bm = blockIdx.y * BM, bn = blockIdx.x * BN;

    f4v acc[WM][WN] = {};

    for (int k0 = ks * kper; k0 < (ks + 1) * kper; k0 += 32) {
        #pragma unroll
        for (int is = 0; is < ACH / 256; ++is) {
            int c = is * 256 + wv * 64 + ln;
            int m = c >> 2, kq = c & 3;
            gload16(Ag + (long)(bm + m) * lda + k0 + kq * 8,
                    &As[(is * 256 + wv * 64) * 8]);
        }
        if constexpr (ACH % 256) {
            if (tid < ACH % 256) {
                int c = (ACH / 256) * 256 + tid;
                int m = c >> 2, kq = c & 3;
                gload16(Ag + (long)(bm + m) * lda + k0 + kq * 8,
                        &As[((ACH / 256) * 256 + wv * 64) * 8]);
            }
        }
        #pragma unroll
        for (int is = 0; is < BCH / 256; ++is) {
            int c = is * 256 + wv * 64 + ln;
            int m = c >> 2, kq = c & 3;
            gload16(Bg + (long)(bn + m) * ldb + k0 + kq * 8,
                    &Bs[(is * 256 + wv * 64) * 8]);
        }
        if constexpr (BCH % 256) {
            if (tid < BCH % 256) {
                int c = (BCH / 256) * 256 + tid;
                int m = c >> 2, kq = c & 3;
                gload16(Bg + (long)(bn + m) * ldb + k0 + kq * 8,
                        &Bs[((BCH / 256) * 256 + wv * 64) * 8]);
            }
        }
        __syncthreads();
        s8v av[WM], bv[WN];
        #pragma unroll
        for (int i = 0; i < WM; ++i)
            av[i] = *(const s8v*)&As[(wr * (WM * 16) + i * 16 + fr) * 32 + fq * 8];
        #pragma unroll
        for (int j = 0; j < WN; ++j)
            bv[j] = *(const s8v*)&Bs[(wc * (WN * 16) + j * 16 + fr) * 32 + fq * 8];
        #pragma unroll
        for (int i = 0; i < WM; ++i)
            #pragma unroll
            for (int j = 0; j < WN; ++j)
                acc[i][j] = __builtin_amdgcn_mfma_f32_16x16x32_bf16(av[i], bv[j], acc[i][j], 0, 0, 0);
        __syncthreads();
    }

    #pragma unroll
    for (int i = 0; i < WM; ++i) {
        #pragma unroll
        for (int r = 0; r < 4; ++r) {
            int row = bm + wr * (WM * 16) + i * 16 + fq * 4 + r;
            if (GROUPED && row >= m_count) continue;
            #pragma unroll
            for (int j = 0; j < WN; ++j) {
                int col = bn + wc * (WN * 16) + j * 16 + fr;
                if (col < N) {
                    float v = acc[i][j][r] * alpha;
                    if (OUTMODE == 2) {
                        atomicAdd(&Cf[(long)row * ldc + col], v);
                    } else {
                        if (biasp) v += biasp[col];
                        if (GELU) v = 0.5f * v * (1.f + erff(v * 0.70710678118654752f));
                        if (resid) v += resid[(long)row * ldc + col];
                        if (OUTMODE == 1) Cb[(long)row * ldc + col] = __float2bfloat16(v);
                        else              Cf[(long)row * ldc + col] = v;
                    }
                }
            }
        }
    }
}

// ---------------- MoE grouped GEMM v2: BM=128, BN=64, BK=64, double-buffered --
// 2-phase K-loop (stage next || compute cur), global-source XOR swizzle so the
// linear global_load_lds destination yields conflict-free ds_read_b128.
// 1-D grid, bid decode: e = bid&7 (XCD affinity), then xt, yt, ks.
// OUTMODE: 1 = bf16 store (+bias,+GELU opt), 2 = f32 atomicAdd.
template<int XT, int YCAP, int KS, bool GELU, int OUTMODE>
__global__ __launch_bounds__(256) void moe_gemm(
    const bf16* __restrict__ A, const bf16* __restrict__ B,
    const float* __restrict__ bias, void* __restrict__ Cv,
    int lda, int ldb, int ldc, int Ktot, long b_hi, long bias_stride,
    const int* __restrict__ grp_off, int N)
{
    int bid = blockIdx.x;
    int e = bid & 7;
    int r = bid >> 3;
    int xt = r % XT; r /= XT;
    int yt = r % YCAP;
    int ks = r / YCAP;
    int m0 = grp_off[e], m1 = grp_off[e + 1];
    int m_count = m1 - m0;
    int bm = yt * 128;
    if (bm >= m_count) return;
    int bn = xt * 64;
    int kper = Ktot / KS;           // multiple of 64

    const short* Ag = (const short*)A + (long)m0 * lda;
    const short* Bg = (const short*)(B + (long)e * b_hi);
    const float* biasp = bias ? bias + (long)e * bias_stride : nullptr;
    float* Cf = (float*)Cv + (long)m0 * ldc;
    bf16*  Cb = (bf16*)Cv + (long)m0 * ldc;

    __shared__ short As[2][128 * 64];   // [m][k] rows of 128B, 16KB per buf
    __shared__ short Bs[2][64 * 64];    // [n][k], 8KB per buf

    int tid = threadIdx.x;
    int wv = tid >> 6, ln = tid & 63;
    int wr = wv >> 1, wc = wv & 1;      // 2x2 wave grid: 64m x 32n per wave
    int fr = ln & 15, fq = ln >> 4;

    f4v acc[4][2] = {};

    // Stage one BK=64 tile. LDS chunk (row, q) receives global k-chunk q^(row&7)
    // (swizzle applied on the GLOBAL address; LDS dest stays linear per m104/m173).
    auto stage = [&](int buf, int k0) {
        #pragma unroll
        for (int is = 0; is < 4; ++is) {
            int c = is * 256 + wv * 64 + ln;        // A chunks 0..1023
            int m = c >> 3, q = c & 7;
            int qg = q ^ (m & 7);
            gload16(Ag + (long)(bm + m) * lda + k0 + qg * 8,
                    &As[buf][(is * 256 + wv * 64) * 8]);
        }
        #pragma unroll
        for (int is = 0; is < 2; ++is) {
            int c = is * 256 + wv * 64 + ln;        // B chunks 0..511
            int n = c >> 3, q = c & 7;
            int qg = q ^ (n & 7);
            gload16(Bg + (long)(bn + n) * ldb + k0 + qg * 8,
                    &Bs[buf][(is * 256 + wv * 64) * 8]);
        }
    };

    int kbeg = ks * kper;
    int nit = kper / 64;
    stage(0, kbeg);
    __syncthreads();
    int cur = 0;
    for (int it = 0; it < nit; ++it) {
        if (it + 1 < nit) stage(cur ^ 1, kbeg + (it + 1) * 64);
        #pragma unroll
        for (int ksub = 0; ksub < 2; ++ksub) {
            s8v av[4], bv[2];
            int qg = ksub * 4 + fq;                 // global 16B k-chunk 0..7
            #pragma unroll
            for (int i = 0; i < 4; ++i) {
                int row = wr * 64 + i * 16 + fr;
                av[i] = *(const s8v*)&As[cur][row * 64 + (qg ^ (row & 7)) * 8];
            }
            #pragma unroll
            for (int j = 0; j < 2; ++j) {
                int row = wc * 32 + j * 16 + fr;
                bv[j] = *(const s8v*)&Bs[cur][row * 64 + (qg ^ (row & 7)) * 8];
            }
            #pragma unroll
            for (int i = 0; i < 4; ++i)
                #pragma unroll
                for (int j = 0; j < 2; ++j)
                    acc[i][j] = __builtin_amdgcn_mfma_f32_16x16x32_bf16(av[i], bv[j], acc[i][j], 0, 0, 0);
        }
        __syncthreads();                            // drains vmcnt (next buf ready)
        cur ^= 1;
    }

    #pragma unroll
    for (int i = 0; i < 4; ++i) {
        #pragma unroll
        for (int rr = 0; rr < 4; ++rr) {
            int row = bm + wr * 64 + i * 16 + fq * 4 + rr;
            if (row >= m_count) continue;
            #pragma unroll
            for (int j = 0; j < 2; ++j) {
                int col = bn + wc * 32 + j * 16 + fr;
                float v = acc[i][j][rr];
                if (OUTMODE == 2) {
                    atomicAdd(&Cf[(long)row * ldc + col], v);
                } else {
                    if (biasp) v += biasp[col];
                    if (GELU) v = 0.5f * v * (1.f + erff(v * 0.70710678118654752f));
                    Cb[(long)row * ldc + col] = __float2bfloat16(v);
                }
            }
        }
    }
}

// ---------------- row softmax over 512 (f32 in, bf16 out) ----------------
__global__ __launch_bounds__(256) void softmax512(const float* __restrict__ s,
                                                  bf16* __restrict__ attn) {
    long row = blockIdx.x;
    const float* p = s + row * 512;
    int tid = threadIdx.x;
    float a = p[tid], b = p[tid + 256];
    float m = fmaxf(a, b);
    __shared__ float red[4], red2[4];
    #pragma unroll
    for (int o = 32; o; o >>= 1) m = fmaxf(m, __shfl_xor(m, o));
    if ((tid & 63) == 0) red[tid >> 6] = m;
    __syncthreads();
    m = fmaxf(fmaxf(red[0], red[1]), fmaxf(red[2], red[3]));
    float e0 = expf(a - m), e1 = expf(b - m);
    float ssum = e0 + e1;
    #pragma unroll
    for (int o = 32; o; o >>= 1) ssum += __shfl_xor(ssum, o);
    if ((tid & 63) == 0) red2[tid >> 6] = ssum;
    __syncthreads();
    ssum = red2[0] + red2[1] + red2[2] + red2[3];
    float inv = 1.f / ssum;
    bf16* ar = attn + row * 512;
    ar[tid]       = __float2bfloat16(e0 * inv);
    ar[tid + 256] = __float2bfloat16(e1 * inv);
}

// ---------------- V transpose: qkv bf16 [tok][2304] -> vt [z][64][512] ------
__global__ __launch_bounds__(256) void vt_kernel(const bf16* __restrict__ qkvb,
                                                 bf16* __restrict__ vt) {
    int st = blockIdx.x;
    int z = blockIdx.y;
    int b = z / HEADS, h = z % HEADS;
    __shared__ short tile[64][65];
    int t = threadIdx.x;
    int d = t & 63, s0 = t >> 6;
    const short* q = (const short*)qkvb;
    #pragma unroll
    for (int i = 0; i < 16; ++i) {
        int s = st * 64 + s0 + i * 4;
        tile[s0 + i * 4][d] = q[(long)(b * SEQ + s) * 2304 + 2 * DIM + h * HDIM + d];
    }
    __syncthreads();
    short* o = (short*)vt;
    #pragma unroll
    for (int i = 0; i < 16; ++i) {
        int d2 = (t >> 6) + i * 4;
        o[(long)(z * 64 + d2) * 512 + st * 64 + (t & 63)] = tile[t & 63][d2];
    }
}

// ---------------- weight transpose-convert: f32 [z][R][C] -> bf16 [z][C][R] --
__global__ __launch_bounds__(256) void wtrans_kernel(const float* __restrict__ in,
                                                     bf16* __restrict__ out,
                                                     int R, int C) {
    int z = blockIdx.z;
    long ibase = (long)z * R * C;
    int rt = blockIdx.y * 64, ct = blockIdx.x * 64;
    __shared__ float tile[64][65];
    int t = threadIdx.x;
    int c = t & 63, r0 = t >> 6;
    #pragma unroll
    for (int i = 0; i < 16; ++i)
        tile[r0 + i * 4][c] = in[ibase + (long)(rt + r0 + i * 4) * C + ct + c];
    __syncthreads();
    #pragma unroll
    for (int i = 0; i < 16; ++i) {
        int cc = r0 + i * 4;
        out[ibase + (long)(ct + cc) * R + rt + c] = __float2bfloat16(tile[c][cc]);
    }
}

// ---------------- straight f32 -> bf16 convert ----------------
__global__ __launch_bounds__(256) void cvt_kernel(const float* __restrict__ in,
                                                  bf16* __restrict__ out, long n) {
    long i = ((long)blockIdx.x * 256 + threadIdx.x) * 4;
    if (i >= n) return;
    float4 v = *(const float4*)(in + i);
    out[i]     = __float2bfloat16(v.x);
    out[i + 1] = __float2bfloat16(v.y);
    out[i + 2] = __float2bfloat16(v.z);
    out[i + 3] = __float2bfloat16(v.w);
}

// ---------------- router: logits, softmax, top2, renorm ----------------
__global__ __launch_bounds__(64) void router_kernel(const float* __restrict__ t2,
                                                    const float* __restrict__ rw,
                                                    const float* __restrict__ rb,
                                                    int* __restrict__ e_sel,
                                                    float* __restrict__ w_sel) {
    int t = blockIdx.x;
    int lane = threadIdx.x;
    const float* tr = t2 + (long)t * DIM;
    float tv[12];
    #pragma unroll
    for (int i = 0; i < 12; ++i) tv[i] = tr[lane + 64 * i];
    float logits[NEXP];
    #pragma unroll
    for (int e = 0; e < NEXP; ++e) {
        const float* wr = rw + (long)e * DIM;
        float s = 0.f;
        #pragma unroll
        for (int i = 0; i < 12; ++i) s += tv[i] * wr[lane + 64 * i];
        #pragma unroll
        for (int o = 32; o; o >>= 1) s += __shfl_xor(s, o);
        logits[e] = s + rb[e];
    }
    if (lane == 0) {
        int e0 = -1, e1 = -1;
        float l0 = -1e30f, l1 = -1e30f;
        #pragma unroll
        for (int e = 0; e < NEXP; ++e) {
            float l = logits[e];
            if (l > l0) { l1 = l0; e1 = e0; l0 = l; e0 = e; }
            else if (l > l1) { l1 = l; e1 = e; }
        }
        float p1 = expf(l1 - l0);
        float inv = 1.f / (1.f + p1);
        e_sel[t * 2] = e0;  e_sel[t * 2 + 1] = e1;
        w_sel[t * 2] = inv; w_sel[t * 2 + 1] = p1 * inv;
    }
}

// ---------------- build per-expert entry lists (single block) ----------------
__global__ __launch_bounds__(1024) void build_lists(const int* __restrict__ e_sel,
                                                    int* __restrict__ entry_tok,
                                                    int* __restrict__ ent_exp,
                                                    int* __restrict__ pos,
                                                    int* __restrict__ grp_off) {
    __shared__ int cnt[NEXP];
    __shared__ int off[NEXP + 1];
    __shared__ int cur[NEXP];
    int tid = threadIdx.x;
    if (tid < NEXP) cnt[tid] = 0;
    __syncthreads();
    for (int i = tid; i < NENT; i += 1024) atomicAdd(&cnt[e_sel[i]], 1);
    __syncthreads();
    if (tid == 0) {
        off[0] = 0;
        for (int e = 0; e < NEXP; ++e) off[e + 1] = off[e] + cnt[e];
        for (int e = 0; e < NEXP; ++e) cur[e] = off[e];
    }
    __syncthreads();
    for (int i = tid; i < NENT; i += 1024) {
        int e = e_sel[i];
        int p = atomicAdd(&cur[e], 1);
        entry_tok[p] = i >> 1;
        ent_exp[p] = e;
        pos[i] = p;
    }
    if (tid < NEXP + 1) grp_off[tid] = off[tid];
}

// ---------------- gather rows (bf16, 8B units) ----------------
__global__ __launch_bounds__(256) void gather_kernel(const bf16* __restrict__ t2b,
                                                     const int* __restrict__ entry_tok,
                                                     bf16* __restrict__ t2g) {
    long i = (long)blockIdx.x * 256 + threadIdx.x;
    if (i >= (long)NENT * 192) return;
    int p = (int)(i / 192), q = (int)(i % 192);
    ((uint2*)t2g)[(long)p * 192 + q] = ((const uint2*)t2b)[(long)entry_tok[p] * 192 + q];
}

// ---------------- prefill x1 = x + out_b ----------------
__global__ __launch_bounds__(256) void prefill_x1(const float* __restrict__ x,
                                                  const float* __restrict__ out_b,
                                                  float* __restrict__ x1) {
    long i = ((long)blockIdx.x * 256 + threadIdx.x) * 4;
    if (i >= (long)NTOK * DIM) return;
    int d = (int)(i % DIM);
    float4 v = *(const float4*)(x + i);
    v.x += out_b[d]; v.y += out_b[d + 1]; v.z += out_b[d + 2]; v.w += out_b[d + 3];
    *(float4*)(x1 + i) = v;
}

// ---------------- prefill ybuf[p][.] = b2[exp(p)][.] ----------------
__global__ __launch_bounds__(256) void prefill_ybuf(const float* __restrict__ b2,
                                                    const int* __restrict__ ent_exp,
                                                    float* __restrict__ ybuf) {
    long i = ((long)blockIdx.x * 256 + threadIdx.x) * 4;
    if (i >= (long)NENT * DIM) return;
    int p = (int)(i / DIM), d = (int)(i % DIM);
    *(float4*)(ybuf + i) = *(const float4*)(b2 + (long)ent_exp[p] * DIM + d);
}

// ---------------- final combine: out = x1 + w0*y(pos0) + w1*y(pos1) ----------
__global__ __launch_bounds__(256) void combine_kernel(const float* __restrict__ x1,
                                                      const float* __restrict__ ybuf,
                                                      const int* __restrict__ pos,
                                                      const float* __restrict__ wsel,
                                                      float* __restrict__ out) {
    long i = (long)blockIdx.x * 256 + threadIdx.x;
    if (i >= (long)NTOK * DIM) return;
    int t = (int)(i / DIM), d = (int)(i % DIM);
    float v = x1[i];
    v += wsel[t * 2]     * ybuf[(long)pos[t * 2]     * DIM + d];
    v += wsel[t * 2 + 1] * ybuf[(long)pos[t * 2 + 1] * DIM + d];
    out[i] = v;
}

extern "C" void kernel_launch(void* const* d_in, const int* in_sizes, int n_in,
                              void* d_out, int out_size, void* d_ws, size_t ws_size,
                              hipStream_t stream) {
    const float* x        = (const float*)d_in[0];
    const float* ln1_g    = (const float*)d_in[1];
    const float* ln1_b    = (const float*)d_in[2];
    const float* ln2_g    = (const float*)d_in[3];
    const float* ln2_b    = (const float*)d_in[4];
    const float* in_w     = (const float*)d_in[5];
    const float* in_b     = (const float*)d_in[6];
    const float* out_w    = (const float*)d_in[7];
    const float* out_b    = (const float*)d_in[8];
    const float* router_w = (const float*)d_in[9];
    const float* router_b = (const float*)d_in[10];
    const float* w1       = (const float*)d_in[11];
    const float* b1       = (const float*)d_in[12];
    const float* w2       = (const float*)d_in[13];
    const float* b2       = (const float*)d_in[14];
    float* out = (float*)d_out;

    const long TD = (long)NTOK * DIM;
    char* p = (char*)d_ws;
    size_t off = 0;
    auto alloc = [&](size_t bytes) -> void* {
        void* r = p + off; off += (bytes + 255) & ~(size_t)255; return r;
    };
    bf16*  h_b    = (bf16*)alloc(TD * 2);
    bf16*  in_wb  = (bf16*)alloc(2304L * 768 * 2);
    bf16*  qkv_b  = (bf16*)alloc(1024L * 2304 * 2);
    bf16*  out_wb = (bf16*)alloc(768L * 768 * 2);
    bf16*  vt_b   = (bf16*)alloc((24L * 64 + 64) * 512 * 2);
    bf16*  oat_b  = (bf16*)alloc(TD * 2);
    float* x1     = (float*)alloc(TD * 4);
    float* t2     = (float*)alloc(TD * 4);
    bf16*  t2b    = (bf16*)alloc(TD * 2);
    bf16*  t2g    = (bf16*)alloc((2048L + 256) * 768 * 2);     // +pad (BM overread)
    bf16*  w1t    = (bf16*)alloc(8L * 3072 * 768 * 2);         // aliased: scores f32 + attn bf16
    bf16*  w2t    = (bf16*)alloc(8L * 768 * 3072 * 2);
    bf16*  hid    = (bf16*)alloc((2048L + 256) * 3072 * 2);    // +pad
    float* ybuf   = (float*)alloc(2048L * 768 * 4);
    int*   e_sel     = (int*)alloc(NENT * 4);
    float* w_sel     = (float*)alloc(NENT * 4);
    int*   entry_tok = (int*)alloc(NENT * 4);
    int*   ent_exp   = (int*)alloc(NENT * 4);
    int*   pos       = (int*)alloc(NENT * 4);
    int*   grp_off   = (int*)alloc(64);
    float* scores = (float*)w1t;
    bf16*  attn   = (bf16*)((char*)w1t + 24L * 512 * 512 * 4);

    // 1. LN1 -> h bf16
    ln_kernel<<<NTOK, 256, 0, stream>>>(x, ln1_g, ln1_b, nullptr, h_b);
    // 2-3. weight converts
    cvt_kernel<<<1728, 256, 0, stream>>>(in_w, in_wb, 2304L * 768);
    cvt_kernel<<<576, 256, 0, stream>>>(out_w, out_wb, 768L * 768);
    // 4. qkv = h @ in_w^T + in_b -> bf16 [1024,2304]   BN=64: 576 blocks
    mfma_gemm<2, 2, false, false, 1><<<dim3(36, 16, 1), 256, 0, stream>>>(
        h_b, in_wb, in_b, nullptr, qkv_b,
        NTOK, 3 * DIM, DIM, DIM, DIM, 3 * DIM,
        1, 1, 0, 0, 0, 0, 0, 0, 0, nullptr, 1.f);
    // 5. scores = Q @ K^T / 8 -> f32 [24][512][512]   768 blocks
    mfma_gemm<2, 4, false, false, 0><<<dim3(4, 8, 24), 256, 0, stream>>>(
        qkv_b, qkv_b + DIM, nullptr, nullptr, scores,
        SEQ, SEQ, HDIM, 3 * DIM, 3 * DIM, SEQ,
        HEADS, 1, (long)SEQ * 3 * DIM, HDIM, (long)SEQ * 3 * DIM, HDIM,
        (long)HEADS * SEQ * SEQ, (long)SEQ * SEQ,
        0, nullptr, 0.125f);
    // 6. softmax -> attn bf16
    softmax512<<<24 * SEQ, 256, 0, stream>>>(scores, attn);
    // 7. V transpose
    vt_kernel<<<dim3(8, 24), 256, 0, stream>>>(qkv_b, vt_b);
    // 8. o = attn @ V -> oat bf16   BM=32: 384 blocks
    mfma_gemm<1, 2, false, false, 1><<<dim3(1, 16, 24), 256, 0, stream>>>(
        attn, vt_b, nullptr, nullptr, oat_b,
        SEQ, HDIM, SEQ, SEQ, SEQ, DIM,
        HEADS, 1, (long)HEADS * SEQ * SEQ, (long)SEQ * SEQ,
        (long)HEADS * HDIM * SEQ, (long)HDIM * SEQ,
        (long)SEQ * DIM, HDIM,
        0, nullptr, 1.f);
    // 9a. prefill x1 = x + out_b
    prefill_x1<<<768, 256, 0, stream>>>(x, out_b, x1);
    // 9b. x1 += oat @ out_w^T   (split-K x2, atomic)  BN=64: 384 blocks
    mfma_gemm<2, 2, false, false, 2><<<dim3(12, 16, 2), 256, 0, stream>>>(
        oat_b, out_wb, nullptr, nullptr, x1,
        NTOK, DIM, DIM, DIM, DIM, DIM,
        1, 2, 0, 0, 0, 0, 0, 0, 0, nullptr, 1.f);
    // 10. LN2 -> t2 f32 + t2b bf16
    ln_kernel<<<NTOK, 256, 0, stream>>>(x1, ln2_g, ln2_b, t2, t2b);
    // 11. router
    router_kernel<<<NTOK, 64, 0, stream>>>(t2, router_w, router_b, e_sel, w_sel);
    // 12. build lists
    build_lists<<<1, 1024, 0, stream>>>(e_sel, entry_tok, ent_exp, pos, grp_off);
    // 13. gather bf16
    gather_kernel<<<1536, 256, 0, stream>>>(t2b, entry_tok, t2g);
    // 14. w1 transpose-convert (after PV: overwrites scores/attn region)
    wtrans_kernel<<<dim3(48, 12, 8), 256, 0, stream>>>(w1, w1t, DIM, FFDIM);
    // 15. FFN1 grouped: hid = gelu(t2g @ w1t^T + b1) -> bf16
    //     BM=128, BN=64, BK=64 dbuf, XCD pinned; active ~768 blocks (3/CU)
    moe_gemm<48, 16, 1, true, 1><<<8 * 48 * 16, 256, 0, stream>>>(
        t2g, w1t, b1, hid,
        DIM, DIM, FFDIM, DIM, (long)FFDIM * DIM, FFDIM, grp_off, FFDIM);
    // 16. w2 transpose-convert
    wtrans_kernel<<<dim3(12, 48, 8), 256, 0, stream>>>(w2, w2t, FFDIM, DIM);
    // 17a. prefill ybuf with b2 rows
    prefill_ybuf<<<1536, 256, 0, stream>>>(b2, ent_exp, ybuf);
    // 17b. FFN2 grouped split-K x4 (atomic): ybuf += hid @ w2t^T
    //      BM=128, BN=64, BK=64 dbuf, KS=4; active ~768 blocks
    moe_gemm<12, 16, 4, false, 2><<<8 * 12 * 16 * 4, 256, 0, stream>>>(
        hid, w2t, nullptr, ybuf,
        FFDIM, FFDIM, DIM, FFDIM, (long)DIM * FFDIM, 0, grp_off, DIM);
    // 18. combine
    combine_kernel<<<3072, 256, 0, stream>>>(x1, ybuf, pos, w_sel, out);
}

// Round 7
// 204.247 us; speedup vs baseline: 4.4582x; 1.0304x over previous
//
#include <hip/hip_runtime.h>
#include <hip/hip_bf16.h>

// Problem constants
#define BATCH 2
#define SEQ 512
#define DIM 768
#define HEADS 12
#define NEXP 8
#define FFDIM 3072
#define HDIM 64
#define NTOK (BATCH*SEQ)          // 1024
#define NENT (2*NTOK)             // 2048 (token, slot) entries

typedef __hip_bfloat16 bf16;
typedef __attribute__((ext_vector_type(8))) short s8v;
typedef __attribute__((ext_vector_type(4))) float f4v;

// ---- async global->LDS (16B per lane, wave-uniform LDS base + lane*16) ----
typedef __attribute__((address_space(1))) const unsigned char gas_u8;
typedef __attribute__((address_space(3))) unsigned char las_u8;
__device__ __forceinline__ void gload16(const void* g, void* l) {
    __builtin_amdgcn_global_load_lds((gas_u8*)g, (las_u8*)l, 16, 0, 0);
}

__device__ __forceinline__ unsigned short bf16bits(float f) {
    __hip_bfloat16 h = __float2bfloat16(f);
    return *reinterpret_cast<unsigned short*>(&h);
}

// ---------------- LayerNorm: one block per token, 256 threads ----------------
__global__ __launch_bounds__(256) void ln_kernel(const float* __restrict__ x,
                                                 const float* __restrict__ g,
                                                 const float* __restrict__ b,
                                                 float* __restrict__ outf,
                                                 bf16* __restrict__ outb) {
    int t = blockIdx.x;
    const float* xr = x + (long)t * DIM;
    int tid = threadIdx.x;
    float v0 = xr[tid], v1 = xr[tid + 256], v2 = xr[tid + 512];
    float s = v0 + v1 + v2;
    __shared__ float red[4];
    #pragma unroll
    for (int o = 32; o; o >>= 1) s += __shfl_xor(s, o);
    if ((tid & 63) == 0) red[tid >> 6] = s;
    __syncthreads();
    s = red[0] + red[1] + red[2] + red[3];
    float mu = s * (1.f / DIM);
    float d0 = v0 - mu, d1 = v1 - mu, d2 = v2 - mu;
    float q = d0*d0 + d1*d1 + d2*d2;
    __shared__ float red2[4];
    #pragma unroll
    for (int o = 32; o; o >>= 1) q += __shfl_xor(q, o);
    if ((tid & 63) == 0) red2[tid >> 6] = q;
    __syncthreads();
    q = red2[0] + red2[1] + red2[2] + red2[3];
    float rstd = rsqrtf(q * (1.f / DIM) + 1e-5f);
    float o0 = d0 * rstd * g[tid]       + b[tid];
    float o1 = d1 * rstd * g[tid + 256] + b[tid + 256];
    float o2 = d2 * rstd * g[tid + 512] + b[tid + 512];
    if (outf) {
        float* of = outf + (long)t * DIM;
        of[tid] = o0; of[tid + 256] = o1; of[tid + 512] = o2;
    }
    if (outb) {
        bf16* ob = outb + (long)t * DIM;
        ob[tid] = __float2bfloat16(o0);
        ob[tid + 256] = __float2bfloat16(o1);
        ob[tid + 512] = __float2bfloat16(o2);
    }
}

// ---------------- MFMA GEMM, parameterized tile (attention-side) ----------------
// C[m,n] = alpha * sum_k A[m,k] * B[n,k]   (A,B bf16 row-major [.][K])
// Tile BM=32*WM x BN=32*WN, 4 waves in 2x2 grid.
// OUTMODE: 0 = f32 store, 1 = bf16 store, 2 = f32 atomicAdd.
template<int WM, int WN, bool GROUPED, bool GELU, int OUTMODE>
__global__ __launch_bounds__(256) void mfma_gemm(
    const bf16* __restrict__ A, const bf16* __restrict__ B,
    const float* __restrict__ bias, const float* __restrict__ resid,
    void* __restrict__ Cv,
    int M, int N, int K, int lda, int ldb, int ldc,
    int zdiv, int ksplit,
    long a_hi, long a_lo, long b_hi, long b_lo, long c_hi, long c_lo,
    long bias_stride, const int* __restrict__ grp_off, float alpha)
{
    constexpr int BM = 32 * WM, BN = 32 * WN;
    constexpr int ACH = BM * 4;     // 16B chunks in A tile
    constexpr int BCH = BN * 4;

    int z = blockIdx.z;
    int ze = z / ksplit, ks = z % ksplit;
    int kper = K / ksplit;
    long aoff, boff, coff;
    int m_count = M;
    if (GROUPED) {
        int m0 = grp_off[ze], m1 = grp_off[ze + 1];
        m_count = m1 - m0;
        if ((int)blockIdx.y * BM >= m_count) return;
        aoff = (long)m0 * lda;
        coff = (long)m0 * ldc;
        boff = (long)ze * b_hi;
    } else {
        int zh = ze / zdiv, zl = ze % zdiv;
        aoff = zh * a_hi + zl * a_lo;
        boff = zh * b_hi + zl * b_lo;
        coff = zh * c_hi + zl * c_lo;
    }
    const short* Ag = (const short*)(A + aoff);
    const short* Bg = (const short*)(B + boff);
    const float* biasp = bias ? bias + (long)ze * bias_stride : nullptr;
    float* Cf = (float*)Cv + coff;
    bf16*  Cb = (bf16*)Cv + coff;

    __shared__ short As[BM * 32];
    __shared__ short Bs[BN * 32];

    int tid = threadIdx.x;
    int wv = tid >> 6, ln = tid & 63;
    int wr = wv >> 1, wc = wv & 1;
    int fr = ln & 15, fq = ln >> 4;
    int bm = blockIdx.y * BM, bn = blockIdx.x * BN;

    f4v acc[WM][WN] = {};

    for (int k0 = ks * kper; k0 < (ks + 1) * kper; k0 += 32) {
        #pragma unroll
        for (int is = 0; is < ACH / 256; ++is) {
            int c = is * 256 + wv * 64 + ln;
            int m = c >> 2, kq = c & 3;
            gload16(Ag + (long)(bm + m) * lda + k0 + kq * 8,
                    &As[(is * 256 + wv * 64) * 8]);
        }
        if constexpr (ACH % 256) {
            if (tid < ACH % 256) {
                int c = (ACH / 256) * 256 + tid;
                int m = c >> 2, kq = c & 3;
                gload16(Ag + (long)(bm + m) * lda + k0 + kq * 8,
                        &As[((ACH / 256) * 256 + wv * 64) * 8]);
            }
        }
        #pragma unroll
        for (int is = 0; is < BCH / 256; ++is) {
            int c = is * 256 + wv * 64 + ln;
            int m = c >> 2, kq = c & 3;
            gload16(Bg + (long)(bn + m) * ldb + k0 + kq * 8,
                    &Bs[(is * 256 + wv * 64) * 8]);
        }
        if constexpr (BCH % 256) {
            if (tid < BCH % 256) {
                int c = (BCH / 256) * 256 + tid;
                int m = c >> 2, kq = c & 3;
                gload16(Bg + (long)(bn + m) * ldb + k0 + kq * 8,
                        &Bs[((BCH / 256) * 256 + wv * 64) * 8]);
            }
        }
        __syncthreads();
        s8v av[WM], bv[WN];
        #pragma unroll
        for (int i = 0; i < WM; ++i)
            av[i] = *(const s8v*)&As[(wr * (WM * 16) + i * 16 + fr) * 32 + fq * 8];
        #pragma unroll
        for (int j = 0; j < WN; ++j)
            bv[j] = *(const s8v*)&Bs[(wc * (WN * 16) + j * 16 + fr) * 32 + fq * 8];
        #pragma unroll
        for (int i = 0; i < WM; ++i)
            #pragma unroll
            for (int j = 0; j < WN; ++j)
                acc[i][j] = __builtin_amdgcn_mfma_f32_16x16x32_bf16(av[i], bv[j], acc[i][j], 0, 0, 0);
        __syncthreads();
    }

    #pragma unroll
    for (int i = 0; i < WM; ++i) {
        #pragma unroll
        for (int r = 0; r < 4; ++r) {
            int row = bm + wr * (WM * 16) + i * 16 + fq * 4 + r;
            if (GROUPED && row >= m_count) continue;
            #pragma unroll
            for (int j = 0; j < WN; ++j) {
                int col = bn + wc * (WN * 16) + j * 16 + fr;
                if (col < N) {
                    float v = acc[i][j][r] * alpha;
                    if (OUTMODE == 2) {
                        atomicAdd(&Cf[(long)row * ldc + col], v);
                    } else {
                        if (biasp) v += biasp[col];
                        if (GELU) v = 0.5f * v * (1.f + erff(v * 0.70710678118654752f));
                        if (resid) v += resid[(long)row * ldc + col];
                        if (OUTMODE == 1) Cb[(long)row * ldc + col] = __float2bfloat16(v);
                        else              Cf[(long)row * ldc + col] = v;
                    }
                }
            }
        }
    }
}

// ---------------- MoE grouped GEMM v3: f32 weights consumed directly ----------
// A: bf16 [rows][lda] (grouped by grp_off), staged via global_load_lds with
//    global-side XOR swizzle (unchanged from v2).
// B: f32 [Ktot][N] per expert (w1/w2 native layout!). Reg-staged: f32 loads ->
//    cvt to bf16 pairs -> transposing ds_write_b32 into Bs[n][k], XOR-swizzled.
//    Write banks: lane kp=tid&31 -> bank kp^((n&7)<<2), n wave-uniform => 2-way (free).
//    Read banks: 16 lanes rows r..r+15 -> 8 bank groups => 2-way (free).
// BM=128, BN=64, BK=64, double-buffered; 1-D grid, e = bid&7 (XCD pinning).
// OUTMODE: 1 = bf16 store (+bias,+GELU opt), 2 = f32 atomicAdd.
template<int XT, int YCAP, int KS, bool GELU, int OUTMODE>
__global__ __launch_bounds__(256) void moe_gemm(
    const bf16* __restrict__ A, const float* __restrict__ B,
    const float* __restrict__ bias, void* __restrict__ Cv,
    int lda, int N, int ldc, int Ktot, long b_hi, long bias_stride,
    const int* __restrict__ grp_off)
{
    int bid = blockIdx.x;
    int e = bid & 7;
    int r = bid >> 3;
    int xt = r % XT; r /= XT;
    int yt = r % YCAP;
    int ks = r / YCAP;
    int m0 = grp_off[e], m1 = grp_off[e + 1];
    int m_count = m1 - m0;
    int bm = yt * 128;
    if (bm >= m_count) return;
    int bn = xt * 64;
    int kper = Ktot / KS;           // multiple of 64

    const short* Ag = (const short*)A + (long)m0 * lda;
    const float* Bg = B + (long)e * b_hi;
    const float* biasp = bias ? bias + (long)e * bias_stride : nullptr;
    float* Cf = (float*)Cv + (long)m0 * ldc;
    bf16*  Cb = (bf16*)Cv + (long)m0 * ldc;

    __shared__ short As[2][128 * 64];   // [m][k] rows of 128B (16KB/buf)
    __shared__ short Bs[2][64 * 64];    // [n][k] rows of 128B (8KB/buf), swizzled

    int tid = threadIdx.x;
    int wv = tid >> 6, ln = tid & 63;
    int wr = wv >> 1, wc = wv & 1;      // 2x2 wave grid: 64m x 32n per wave
    int fr = ln & 15, fq = ln >> 4;
    int kp = tid & 31;                  // B staging: k-pair (k=2kp,2kp+1)
    int nb = tid >> 5;                  // B staging: n-octet (n = nb*8 + i)

    f4v acc[4][2] = {};

    // A tile: LDS chunk (m, q) receives global k-chunk q^(m&7) (swizzle on
    // the GLOBAL address; LDS dest stays linear per the gload_lds rule).
    auto stageA = [&](int buf, int k0) {
        #pragma unroll
        for (int is = 0; is < 4; ++is) {
            int c = is * 256 + wv * 64 + ln;        // chunks 0..1023
            int m = c >> 3, q = c & 7;
            int qg = q ^ (m & 7);
            gload16(Ag + (long)(bm + m) * lda + k0 + qg * 8,
                    &As[buf][(is * 256 + wv * 64) * 8]);
        }
    };
    // B tile: 16 f32 per thread (rows 2kp,2kp+1 x cols bn+nb*8..+7)
    auto loadB = [&](int k0, float4* br) {
        const float* p0 = Bg + (long)(k0 + 2 * kp) * N + bn + nb * 8;
        br[0] = *(const float4*)p0;
        br[1] = *(const float4*)(p0 + 4);
        br[2] = *(const float4*)(p0 + N);
        br[3] = *(const float4*)(p0 + N + 4);
    };
    auto writeB = [&](int buf, const float4* br) {
        const float* f = (const float*)br;
        #pragma unroll
        for (int i = 0; i < 8; ++i) {
            unsigned u = ((unsigned)bf16bits(f[i + 8]) << 16) | bf16bits(f[i]);
            int n = nb * 8 + i;
            int byte = n * 128 + ((kp * 4) ^ ((n & 7) << 4));
            *(unsigned*)((char*)&Bs[buf][0] + byte) = u;
        }
    };

    int kbeg = ks * kper;
    int nit = kper / 64;
    float4 br[4];
    loadB(kbeg, br);
    stageA(0, kbeg);
    writeB(0, br);
    __syncthreads();
    int cur = 0;
    for (int it = 0; it < nit; ++it) {
        float4 br2[4];
        bool more = (it + 1 < nit);
        if (more) {
            loadB(kbeg + (it + 1) * 64, br2);       // reg loads first (vmcnt)
            stageA(cur ^ 1, kbeg + (it + 1) * 64);  // then async A loads
        }
        #pragma unroll
        for (int ksub = 0; ksub < 2; ++ksub) {
            s8v av[4], bv[2];
            int qg = ksub * 4 + fq;                 // global 16B k-chunk 0..7
            #pragma unroll
            for (int i = 0; i < 4; ++i) {
                int row = wr * 64 + i * 16 + fr;
                av[i] = *(const s8v*)&As[cur][row * 64 + (qg ^ (row & 7)) * 8];
            }
            #pragma unroll
            for (int j = 0; j < 2; ++j) {
                int row = wc * 32 + j * 16 + fr;
                bv[j] = *(const s8v*)((const char*)&Bs[cur][0] +
                                      row * 128 + ((qg * 16) ^ ((row & 7) << 4)));
            }
            #pragma unroll
            for (int i = 0; i < 4; ++i)
                #pragma unroll
                for (int j = 0; j < 2; ++j)
                    acc[i][j] = __builtin_amdgcn_mfma_f32_16x16x32_bf16(av[i], bv[j], acc[i][j], 0, 0, 0);
        }
        if (more) writeB(cur ^ 1, br2);
        __syncthreads();                            // drains vmcnt+lgkmcnt
        cur ^= 1;
    }

    #pragma unroll
    for (int i = 0; i < 4; ++i) {
        #pragma unroll
        for (int rr = 0; rr < 4; ++rr) {
            int row = bm + wr * 64 + i * 16 + fq * 4 + rr;
            if (row >= m_count) continue;
            #pragma unroll
            for (int j = 0; j < 2; ++j) {
                int col = bn + wc * 32 + j * 16 + fr;
                float v = acc[i][j][rr];
                if (OUTMODE == 2) {
                    atomicAdd(&Cf[(long)row * ldc + col], v);
                } else {
                    if (biasp) v += biasp[col];
                    if (GELU) v = 0.5f * v * (1.f + erff(v * 0.70710678118654752f));
                    Cb[(long)row * ldc + col] = __float2bfloat16(v);
                }
            }
        }
    }
}

// ---------------- row softmax over 512 (f32 in, bf16 out) ----------------
__global__ __launch_bounds__(256) void softmax512(const float* __restrict__ s,
                                                  bf16* __restrict__ attn) {
    long row = blockIdx.x;
    const float* p = s + row * 512;
    int tid = threadIdx.x;
    float a = p[tid], b = p[tid + 256];
    float m = fmaxf(a, b);
    __shared__ float red[4], red2[4];
    #pragma unroll
    for (int o = 32; o; o >>= 1) m = fmaxf(m, __shfl_xor(m, o));
    if ((tid & 63) == 0) red[tid >> 6] = m;
    __syncthreads();
    m = fmaxf(fmaxf(red[0], red[1]), fmaxf(red[2], red[3]));
    float e0 = expf(a - m), e1 = expf(b - m);
    float ssum = e0 + e1;
    #pragma unroll
    for (int o = 32; o; o >>= 1) ssum += __shfl_xor(ssum, o);
    if ((tid & 63) == 0) red2[tid >> 6] = ssum;
    __syncthreads();
    ssum = red2[0] + red2[1] + red2[2] + red2[3];
    float inv = 1.f / ssum;
    bf16* ar = attn + row * 512;
    ar[tid]       = __float2bfloat16(e0 * inv);
    ar[tid + 256] = __float2bfloat16(e1 * inv);
}

// ---------------- V transpose: qkv bf16 [tok][2304] -> vt [z][64][512] ------
__global__ __launch_bounds__(256) void vt_kernel(const bf16* __restrict__ qkvb,
                                                 bf16* __restrict__ vt) {
    int st = blockIdx.x;
    int z = blockIdx.y;
    int b = z / HEADS, h = z % HEADS;
    __shared__ short tile[64][65];
    int t = threadIdx.x;
    int d = t & 63, s0 = t >> 6;
    const short* q = (const short*)qkvb;
    #pragma unroll
    for (int i = 0; i < 16; ++i) {
        int s = st * 64 + s0 + i * 4;
        tile[s0 + i * 4][d] = q[(long)(b * SEQ + s) * 2304 + 2 * DIM + h * HDIM + d];
    }
    __syncthreads();
    short* o = (short*)vt;
    #pragma unroll
    for (int i = 0; i < 16; ++i) {
        int d2 = (t >> 6) + i * 4;
        o[(long)(z * 64 + d2) * 512 + st * 64 + (t & 63)] = tile[t & 63][d2];
    }
}

// ---------------- straight f32 -> bf16 convert ----------------
__global__ __launch_bounds__(256) void cvt_kernel(const float* __restrict__ in,
                                                  bf16* __restrict__ out, long n) {
    long i = ((long)blockIdx.x * 256 + threadIdx.x) * 4;
    if (i >= n) return;
    float4 v = *(const float4*)(in + i);
    out[i]     = __float2bfloat16(v.x);
    out[i + 1] = __float2bfloat16(v.y);
    out[i + 2] = __float2bfloat16(v.z);
    out[i + 3] = __float2bfloat16(v.w);
}

// ---------------- router: logits, softmax, top2, renorm ----------------
__global__ __launch_bounds__(64) void router_kernel(const float* __restrict__ t2,
                                                    const float* __restrict__ rw,
                                                    const float* __restrict__ rb,
                                                    int* __restrict__ e_sel,
                                                    float* __restrict__ w_sel) {
    int t = blockIdx.x;
    int lane = threadIdx.x;
    const float* tr = t2 + (long)t * DIM;
    float tv[12];
    #pragma unroll
    for (int i = 0; i < 12; ++i) tv[i] = tr[lane + 64 * i];
    float logits[NEXP];
    #pragma unroll
    for (int e = 0; e < NEXP; ++e) {
        const float* wr = rw + (long)e * DIM;
        float s = 0.f;
        #pragma unroll
        for (int i = 0; i < 12; ++i) s += tv[i] * wr[lane + 64 * i];
        #pragma unroll
        for (int o = 32; o; o >>= 1) s += __shfl_xor(s, o);
        logits[e] = s + rb[e];
    }
    if (lane == 0) {
        int e0 = -1, e1 = -1;
        float l0 = -1e30f, l1 = -1e30f;
        #pragma unroll
        for (int e = 0; e < NEXP; ++e) {
            float l = logits[e];
            if (l > l0) { l1 = l0; e1 = e0; l0 = l; e0 = e; }
            else if (l > l1) { l1 = l; e1 = e; }
        }
        float p1 = expf(l1 - l0);
        float inv = 1.f / (1.f + p1);
        e_sel[t * 2] = e0;  e_sel[t * 2 + 1] = e1;
        w_sel[t * 2] = inv; w_sel[t * 2 + 1] = p1 * inv;
    }
}

// ---------------- build per-expert entry lists (single block) ----------------
__global__ __launch_bounds__(1024) void build_lists(const int* __restrict__ e_sel,
                                                    int* __restrict__ entry_tok,
                                                    int* __restrict__ ent_exp,
                                                    int* __restrict__ pos,
                                                    int* __restrict__ grp_off) {
    __shared__ int cnt[NEXP];
    __shared__ int off[NEXP + 1];
    __shared__ int cur[NEXP];
    int tid = threadIdx.x;
    if (tid < NEXP) cnt[tid] = 0;
    __syncthreads();
    for (int i = tid; i < NENT; i += 1024) atomicAdd(&cnt[e_sel[i]], 1);
    __syncthreads();
    if (tid == 0) {
        off[0] = 0;
        for (int e = 0; e < NEXP; ++e) off[e + 1] = off[e] + cnt[e];
        for (int e = 0; e < NEXP; ++e) cur[e] = off[e];
    }
    __syncthreads();
    for (int i = tid; i < NENT; i += 1024) {
        int e = e_sel[i];
        int p = atomicAdd(&cur[e], 1);
        entry_tok[p] = i >> 1;
        ent_exp[p] = e;
        pos[i] = p;
    }
    if (tid < NEXP + 1) grp_off[tid] = off[tid];
}

// ---------------- gather rows (bf16, 8B units) ----------------
__global__ __launch_bounds__(256) void gather_kernel(const bf16* __restrict__ t2b,
                                                     const int* __restrict__ entry_tok,
                                                     bf16* __restrict__ t2g) {
    long i = (long)blockIdx.x * 256 + threadIdx.x;
    if (i >= (long)NENT * 192) return;
    int p = (int)(i / 192), q = (int)(i % 192);
    ((uint2*)t2g)[(long)p * 192 + q] = ((const uint2*)t2b)[(long)entry_tok[p] * 192 + q];
}

// ---------------- prefill x1 = x + out_b ----------------
__global__ __launch_bounds__(256) void prefill_x1(const float* __restrict__ x,
                                                  const float* __restrict__ out_b,
                                                  float* __restrict__ x1) {
    long i = ((long)blockIdx.x * 256 + threadIdx.x) * 4;
    if (i >= (long)NTOK * DIM) return;
    int d = (int)(i % DIM);
    float4 v = *(const float4*)(x + i);
    v.x += out_b[d]; v.y += out_b[d + 1]; v.z += out_b[d + 2]; v.w += out_b[d + 3];
    *(float4*)(x1 + i) = v;
}

// ---------------- prefill ybuf[p][.] = b2[exp(p)][.] ----------------
__global__ __launch_bounds__(256) void prefill_ybuf(const float* __restrict__ b2,
                                                    const int* __restrict__ ent_exp,
                                                    float* __restrict__ ybuf) {
    long i = ((long)blockIdx.x * 256 + threadIdx.x) * 4;
    if (i >= (long)NENT * DIM) return;
    int p = (int)(i / DIM), d = (int)(i % DIM);
    *(float4*)(ybuf + i) = *(const float4*)(b2 + (long)ent_exp[p] * DIM + d);
}

// ---------------- final combine: out = x1 + w0*y(pos0) + w1*y(pos1) ----------
__global__ __launch_bounds__(256) void combine_kernel(const float* __restrict__ x1,
                                                      const float* __restrict__ ybuf,
                                                      const int* __restrict__ pos,
                                                      const float* __restrict__ wsel,
                                                      float* __restrict__ out) {
    long i = (long)blockIdx.x * 256 + threadIdx.x;
    if (i >= (long)NTOK * DIM) return;
    int t = (int)(i / DIM), d = (int)(i % DIM);
    float v = x1[i];
    v += wsel[t * 2]     * ybuf[(long)pos[t * 2]     * DIM + d];
    v += wsel[t * 2 + 1] * ybuf[(long)pos[t * 2 + 1] * DIM + d];
    out[i] = v;
}

extern "C" void kernel_launch(void* const* d_in, const int* in_sizes, int n_in,
                              void* d_out, int out_size, void* d_ws, size_t ws_size,
                              hipStream_t stream) {
    const float* x        = (const float*)d_in[0];
    const float* ln1_g    = (const float*)d_in[1];
    const float* ln1_b    = (const float*)d_in[2];
    const float* ln2_g    = (const float*)d_in[3];
    const float* ln2_b    = (const float*)d_in[4];
    const float* in_w     = (const float*)d_in[5];
    const float* in_b     = (const float*)d_in[6];
    const float* out_w    = (const float*)d_in[7];
    const float* out_b    = (const float*)d_in[8];
    const float* router_w = (const float*)d_in[9];
    const float* router_b = (const float*)d_in[10];
    const float* w1       = (const float*)d_in[11];
    const float* b1       = (const float*)d_in[12];
    const float* w2       = (const float*)d_in[13];
    const float* b2       = (const float*)d_in[14];
    float* out = (float*)d_out;

    const long TD = (long)NTOK * DIM;
    char* p = (char*)d_ws;
    size_t off = 0;
    auto alloc = [&](size_t bytes) -> void* {
        void* r = p + off; off += (bytes + 255) & ~(size_t)255; return r;
    };
    bf16*  h_b    = (bf16*)alloc(TD * 2);
    bf16*  in_wb  = (bf16*)alloc(2304L * 768 * 2);
    bf16*  qkv_b  = (bf16*)alloc(1024L * 2304 * 2);
    bf16*  out_wb = (bf16*)alloc(768L * 768 * 2);
    bf16*  vt_b   = (bf16*)alloc((24L * 64 + 64) * 512 * 2);
    bf16*  oat_b  = (bf16*)alloc(TD * 2);
    float* x1     = (float*)alloc(TD * 4);
    float* t2     = (float*)alloc(TD * 4);
    bf16*  t2b    = (bf16*)alloc(TD * 2);
    bf16*  t2g    = (bf16*)alloc((2048L + 256) * 768 * 2);     // +pad (BM overread)
    float* scores = (float*)alloc(24L * 512 * 512 * 4);
    bf16*  attn   = (bf16*)alloc(24L * 512 * 512 * 2);
    bf16*  hid    = (bf16*)alloc((2048L + 256) * 3072 * 2);    // +pad
    float* ybuf   = (float*)alloc(2048L * 768 * 4);
    int*   e_sel     = (int*)alloc(NENT * 4);
    float* w_sel     = (float*)alloc(NENT * 4);
    int*   entry_tok = (int*)alloc(NENT * 4);
    int*   ent_exp   = (int*)alloc(NENT * 4);
    int*   pos       = (int*)alloc(NENT * 4);
    int*   grp_off   = (int*)alloc(64);

    // 1. LN1 -> h bf16
    ln_kernel<<<NTOK, 256, 0, stream>>>(x, ln1_g, ln1_b, nullptr, h_b);
    // 2-3. attention weight converts (already [N][K]; no transpose needed)
    cvt_kernel<<<1728, 256, 0, stream>>>(in_w, in_wb, 2304L * 768);
    cvt_kernel<<<576, 256, 0, stream>>>(out_w, out_wb, 768L * 768);
    // 4. qkv = h @ in_w^T + in_b -> bf16 [1024,2304]   BN=64: 576 blocks
    mfma_gemm<2, 2, false, false, 1><<<dim3(36, 16, 1), 256, 0, stream>>>(
        h_b, in_wb, in_b, nullptr, qkv_b,
        NTOK, 3 * DIM, DIM, DIM, DIM, 3 * DIM,
        1, 1, 0, 0, 0, 0, 0, 0, 0, nullptr, 1.f);
    // 5. scores = Q @ K^T / 8 -> f32 [24][512][512]   768 blocks
    mfma_gemm<2, 4, false, false, 0><<<dim3(4, 8, 24), 256, 0, stream>>>(
        qkv_b, qkv_b + DIM, nullptr, nullptr, scores,
        SEQ, SEQ, HDIM, 3 * DIM, 3 * DIM, SEQ,
        HEADS, 1, (long)SEQ * 3 * DIM, HDIM, (long)SEQ * 3 * DIM, HDIM,
        (long)HEADS * SEQ * SEQ, (long)SEQ * SEQ,
        0, nullptr, 0.125f);
    // 6. softmax -> attn bf16
    softmax512<<<24 * SEQ, 256, 0, stream>>>(scores, attn);
    // 7. V transpose
    vt_kernel<<<dim3(8, 24), 256, 0, stream>>>(qkv_b, vt_b);
    // 8. o = attn @ V -> oat bf16   BM=32: 384 blocks
    mfma_gemm<1, 2, false, false, 1><<<dim3(1, 16, 24), 256, 0, stream>>>(
        attn, vt_b, nullptr, nullptr, oat_b,
        SEQ, HDIM, SEQ, SEQ, SEQ, DIM,
        HEADS, 1, (long)HEADS * SEQ * SEQ, (long)SEQ * SEQ,
        (long)HEADS * HDIM * SEQ, (long)HDIM * SEQ,
        (long)SEQ * DIM, HDIM,
        0, nullptr, 1.f);
    // 9a. prefill x1 = x + out_b
    prefill_x1<<<768, 256, 0, stream>>>(x, out_b, x1);
    // 9b. x1 += oat @ out_w^T   (split-K x2, atomic)  BN=64: 384 blocks
    mfma_gemm<2, 2, false, false, 2><<<dim3(12, 16, 2), 256, 0, stream>>>(
        oat_b, out_wb, nullptr, nullptr, x1,
        NTOK, DIM, DIM, DIM, DIM, DIM,
        1, 2, 0, 0, 0, 0, 0, 0, 0, nullptr, 1.f);
    // 10. LN2 -> t2 f32 + t2b bf16
    ln_kernel<<<NTOK, 256, 0, stream>>>(x1, ln2_g, ln2_b, t2, t2b);
    // 11. router
    router_kernel<<<NTOK, 64, 0, stream>>>(t2, router_w, router_b, e_sel, w_sel);
    // 12. build lists
    build_lists<<<1, 1024, 0, stream>>>(e_sel, entry_tok, ent_exp, pos, grp_off);
    // 13. gather bf16
    gather_kernel<<<1536, 256, 0, stream>>>(t2b, entry_tok, t2g);
    // 14. FFN1 grouped: hid = gelu(t2g @ w1[e] + b1) -> bf16
    //     w1 consumed directly as f32 [768][3072]; XCD pinned; ~768 active blocks
    moe_gemm<48, 16, 1, true, 1><<<8 * 48 * 16, 256, 0, stream>>>(
        t2g, w1, b1, hid,
        DIM, FFDIM, FFDIM, DIM, (long)DIM * FFDIM, FFDIM, grp_off);
    // 15a. prefill ybuf with b2 rows
    prefill_ybuf<<<1536, 256, 0, stream>>>(b2, ent_exp, ybuf);
    // 15b. FFN2 grouped split-K x4 (atomic): ybuf += hid @ w2[e]
    //      w2 consumed directly as f32 [3072][768]; ~768 active blocks
    moe_gemm<12, 16, 4, false, 2><<<8 * 12 * 16 * 4, 256, 0, stream>>>(
        hid, w2, nullptr, ybuf,
        FFDIM, DIM, DIM, FFDIM, (long)FFDIM * DIM, 0, grp_off);
    // 16. combine
    combine_kernel<<<3072, 256, 0, stream>>>(x1, ybuf, pos, w_sel, out);
}

// Round 8
// 198.167 us; speedup vs baseline: 4.5949x; 1.0307x over previous
//
#include <hip/hip_runtime.h>
#include <hip/hip_bf16.h>

// Problem constants
#define BATCH 2
#define SEQ 512
#define DIM 768
#define HEADS 12
#define NEXP 8
#define FFDIM 3072
#define HDIM 64
#define NTOK (BATCH*SEQ)          // 1024
#define NENT (2*NTOK)             // 2048 (token, slot) entries

typedef __hip_bfloat16 bf16;
typedef __attribute__((ext_vector_type(8))) short s8v;
typedef __attribute__((ext_vector_type(4))) float f4v;

// ---- async global->LDS (16B per lane, wave-uniform LDS base + lane*16) ----
typedef __attribute__((address_space(1))) const unsigned char gas_u8;
typedef __attribute__((address_space(3))) unsigned char las_u8;
__device__ __forceinline__ void gload16(const void* g, void* l) {
    __builtin_amdgcn_global_load_lds((gas_u8*)g, (las_u8*)l, 16, 0, 0);
}

__device__ __forceinline__ unsigned short bf16bits(float f) {
    __hip_bfloat16 h = __float2bfloat16(f);
    return *reinterpret_cast<unsigned short*>(&h);
}

// ---------------- LayerNorm: one block per token, 256 threads ----------------
__global__ __launch_bounds__(256) void ln_kernel(const float* __restrict__ x,
                                                 const float* __restrict__ g,
                                                 const float* __restrict__ b,
                                                 float* __restrict__ outf,
                                                 bf16* __restrict__ outb) {
    int t = blockIdx.x;
    const float* xr = x + (long)t * DIM;
    int tid = threadIdx.x;
    float v0 = xr[tid], v1 = xr[tid + 256], v2 = xr[tid + 512];
    float s = v0 + v1 + v2;
    __shared__ float red[4];
    #pragma unroll
    for (int o = 32; o; o >>= 1) s += __shfl_xor(s, o);
    if ((tid & 63) == 0) red[tid >> 6] = s;
    __syncthreads();
    s = red[0] + red[1] + red[2] + red[3];
    float mu = s * (1.f / DIM);
    float d0 = v0 - mu, d1 = v1 - mu, d2 = v2 - mu;
    float q = d0*d0 + d1*d1 + d2*d2;
    __shared__ float red2[4];
    #pragma unroll
    for (int o = 32; o; o >>= 1) q += __shfl_xor(q, o);
    if ((tid & 63) == 0) red2[tid >> 6] = q;
    __syncthreads();
    q = red2[0] + red2[1] + red2[2] + red2[3];
    float rstd = rsqrtf(q * (1.f / DIM) + 1e-5f);
    float o0 = d0 * rstd * g[tid]       + b[tid];
    float o1 = d1 * rstd * g[tid + 256] + b[tid + 256];
    float o2 = d2 * rstd * g[tid + 512] + b[tid + 512];
    if (outf) {
        float* of = outf + (long)t * DIM;
        of[tid] = o0; of[tid + 256] = o1; of[tid + 512] = o2;
    }
    if (outb) {
        bf16* ob = outb + (long)t * DIM;
        ob[tid] = __float2bfloat16(o0);
        ob[tid + 256] = __float2bfloat16(o1);
        ob[tid + 512] = __float2bfloat16(o2);
    }
}

// ---------------- MFMA GEMM, parameterized tile (attention-side) ----------------
// C[m,n] = alpha * sum_k A[m,k] * B[n,k]   (A,B bf16 row-major [.][K])
// Tile BM=32*WM x BN=32*WN, 4 waves in 2x2 grid.
// OUTMODE: 0 = f32 store, 1 = bf16 store, 2 = f32 atomicAdd.
template<int WM, int WN, bool GROUPED, bool GELU, int OUTMODE>
__global__ __launch_bounds__(256) void mfma_gemm(
    const bf16* __restrict__ A, const bf16* __restrict__ B,
    const float* __restrict__ bias, const float* __restrict__ resid,
    void* __restrict__ Cv,
    int M, int N, int K, int lda, int ldb, int ldc,
    int zdiv, int ksplit,
    long a_hi, long a_lo, long b_hi, long b_lo, long c_hi, long c_lo,
    long bias_stride, const int* __restrict__ grp_off, float alpha)
{
    constexpr int BM = 32 * WM, BN = 32 * WN;
    constexpr int ACH = BM * 4;     // 16B chunks in A tile
    constexpr int BCH = BN * 4;

    int z = blockIdx.z;
    int ze = z / ksplit, ks = z % ksplit;
    int kper = K / ksplit;
    long aoff, boff, coff;
    int m_count = M;
    if (GROUPED) {
        int m0 = grp_off[ze], m1 = grp_off[ze + 1];
        m_count = m1 - m0;
        if ((int)blockIdx.y * BM >= m_count) return;
        aoff = (long)m0 * lda;
        coff = (long)m0 * ldc;
        boff = (long)ze * b_hi;
    } else {
        int zh = ze / zdiv, zl = ze % zdiv;
        aoff = zh * a_hi + zl * a_lo;
        boff = zh * b_hi + zl * b_lo;
        coff = zh * c_hi + zl * c_lo;
    }
    const short* Ag = (const short*)(A + aoff);
    const short* Bg = (const short*)(B + boff);
    const float* biasp = bias ? bias + (long)ze * bias_stride : nullptr;
    float* Cf = (float*)Cv + coff;
    bf16*  Cb = (bf16*)Cv + coff;

    __shared__ short As[BM * 32];
    __shared__ short Bs[BN * 32];

    int tid = threadIdx.x;
    int wv = tid >> 6, ln = tid & 63;
    int wr = wv >> 1, wc = wv & 1;
    int fr = ln & 15, fq = ln >> 4;
    int bm = blockIdx.y * BM, bn = blockIdx.x * BN;

    f4v acc[WM][WN] = {};

    for (int k0 = ks * kper; k0 < (ks + 1) * kper; k0 += 32) {
        #pragma unroll
        for (int is = 0; is < ACH / 256; ++is) {
            int c = is * 256 + wv * 64 + ln;
            int m = c >> 2, kq = c & 3;
            gload16(Ag + (long)(bm + m) * lda + k0 + kq * 8,
                    &As[(is * 256 + wv * 64) * 8]);
        }
        if constexpr (ACH % 256) {
            if (tid < ACH % 256) {
                int c = (ACH / 256) * 256 + tid;
                int m = c >> 2, kq = c & 3;
                gload16(Ag + (long)(bm + m) * lda + k0 + kq * 8,
                        &As[((ACH / 256) * 256 + wv * 64) * 8]);
            }
        }
        #pragma unroll
        for (int is = 0; is < BCH / 256; ++is) {
            int c = is * 256 + wv * 64 + ln;
            int m = c >> 2, kq = c & 3;
            gload16(Bg + (long)(bn + m) * ldb + k0 + kq * 8,
                    &Bs[(is * 256 + wv * 64) * 8]);
        }
        if constexpr (BCH % 256) {
            if (tid < BCH % 256) {
                int c = (BCH / 256) * 256 + tid;
                int m = c >> 2, kq = c & 3;
                gload16(Bg + (long)(bn + m) * ldb + k0 + kq * 8,
                        &Bs[((BCH / 256) * 256 + wv * 64) * 8]);
            }
        }
        __syncthreads();
        s8v av[WM], bv[WN];
        #pragma unroll
        for (int i = 0; i < WM; ++i)
            av[i] = *(const s8v*)&As[(wr * (WM * 16) + i * 16 + fr) * 32 + fq * 8];
        #pragma unroll
        for (int j = 0; j < WN; ++j)
            bv[j] = *(const s8v*)&Bs[(wc * (WN * 16) + j * 16 + fr) * 32 + fq * 8];
        #pragma unroll
        for (int i = 0; i < WM; ++i)
            #pragma unroll
            for (int j = 0; j < WN; ++j)
                acc[i][j] = __builtin_amdgcn_mfma_f32_16x16x32_bf16(av[i], bv[j], acc[i][j], 0, 0, 0);
        __syncthreads();
    }

    #pragma unroll
    for (int i = 0; i < WM; ++i) {
        #pragma unroll
        for (int r = 0; r < 4; ++r) {
            int row = bm + wr * (WM * 16) + i * 16 + fq * 4 + r;
            if (GROUPED && row >= m_count) continue;
            #pragma unroll
            for (int j = 0; j < WN; ++j) {
                int col = bn + wc * (WN * 16) + j * 16 + fr;
                if (col < N) {
                    float v = acc[i][j][r] * alpha;
                    if (OUTMODE == 2) {
                        atomicAdd(&Cf[(long)row * ldc + col], v);
                    } else {
                        if (biasp) v += biasp[col];
                        if (GELU) v = 0.5f * v * (1.f + erff(v * 0.70710678118654752f));
                        if (resid) v += resid[(long)row * ldc + col];
                        if (OUTMODE == 1) Cb[(long)row * ldc + col] = __float2bfloat16(v);
                        else              Cf[(long)row * ldc + col] = v;
                    }
                }
            }
        }
    }
}

// ---------------- MoE grouped GEMM v4: f32 weights, COALESCED B staging -------
// A: bf16 [rows][lda], gload_lds with global-side XOR swizzle (unchanged).
// B: f32 [Ktot][N] per expert. Coalesced reg-staging:
//    thread t: cols c=4*(t&15)..+3, rows 4a..4a+3 (a=t>>4) -> 4x float4 where
//    16 consecutive lanes read 256 contiguous bytes (ideal coalescing).
//    Write: per col n, pack k-quad (4 bf16) -> 1x ds_write_b64 at
//    byte n*128 + (8a ^ ((n&7)<<4)). Swizzle has no bit-3 => the 16B read
//    chunk at (16*qg ^ swz) holds k=8qg..8qg+7 contiguously (matches read).
// BM=128, BN=64, BK=64, double-buffered; 1-D grid, e = bid&7 (XCD pinning).
// OUTMODE: 1 = bf16 store (+bias,+GELU opt), 2 = f32 atomicAdd.
template<int XT, int YCAP, int KS, bool GELU, int OUTMODE>
__global__ __launch_bounds__(256) void moe_gemm(
    const bf16* __restrict__ A, const float* __restrict__ B,
    const float* __restrict__ bias, void* __restrict__ Cv,
    int lda, int N, int ldc, int Ktot, long b_hi, long bias_stride,
    const int* __restrict__ grp_off)
{
    int bid = blockIdx.x;
    int e = bid & 7;
    int r = bid >> 3;
    int xt = r % XT; r /= XT;
    int yt = r % YCAP;
    int ks = r / YCAP;
    int m0 = grp_off[e], m1 = grp_off[e + 1];
    int m_count = m1 - m0;
    int bm = yt * 128;
    if (bm >= m_count) return;
    int bn = xt * 64;
    int kper = Ktot / KS;           // multiple of 64

    const short* Ag = (const short*)A + (long)m0 * lda;
    const float* Bg = B + (long)e * b_hi;
    const float* biasp = bias ? bias + (long)e * bias_stride : nullptr;
    float* Cf = (float*)Cv + (long)m0 * ldc;
    bf16*  Cb = (bf16*)Cv + (long)m0 * ldc;

    __shared__ short As[2][128 * 64];   // [m][k] rows of 128B (16KB/buf)
    __shared__ short Bs[2][64 * 64];    // [n][k] rows of 128B (8KB/buf), swizzled

    int tid = threadIdx.x;
    int wv = tid >> 6, ln = tid & 63;
    int wr = wv >> 1, wc = wv & 1;      // 2x2 wave grid: 64m x 32n per wave
    int fr = ln & 15, fq = ln >> 4;
    int cq = tid & 15;                  // B staging: col quad (cols 4cq..4cq+3)
    int aa = tid >> 4;                  // B staging: row quad (rows 4aa..4aa+3)

    f4v acc[4][2] = {};

    // A tile: LDS chunk (m, q) receives global k-chunk q^(m&7) (swizzle on
    // the GLOBAL address; LDS dest stays linear per the gload_lds rule).
    auto stageA = [&](int buf, int k0) {
        #pragma unroll
        for (int is = 0; is < 4; ++is) {
            int c = is * 256 + wv * 64 + ln;        // chunks 0..1023
            int m = c >> 3, q = c & 7;
            int qg = q ^ (m & 7);
            gload16(Ag + (long)(bm + m) * lda + k0 + qg * 8,
                    &As[buf][(is * 256 + wv * 64) * 8]);
        }
    };
    // B tile: coalesced — 4 float4 from rows k0+4aa..+3, cols bn+4cq..+3
    auto loadB = [&](int k0, float4* br) {
        const float* p0 = Bg + (long)(k0 + 4 * aa) * N + bn + 4 * cq;
        br[0] = *(const float4*)p0;
        br[1] = *(const float4*)(p0 + N);
        br[2] = *(const float4*)(p0 + 2 * N);
        br[3] = *(const float4*)(p0 + 3 * N);
    };
    auto writeB = [&](int buf, const float4* br) {
        #pragma unroll
        for (int i = 0; i < 4; ++i) {
            int n = 4 * cq + i;
            unsigned lo = ((unsigned)bf16bits(br[1][i]) << 16) | bf16bits(br[0][i]);
            unsigned hi = ((unsigned)bf16bits(br[3][i]) << 16) | bf16bits(br[2][i]);
            int byte = n * 128 + ((8 * aa) ^ ((n & 7) << 4));
            uint2 v; v.x = lo; v.y = hi;
            *(uint2*)((char*)&Bs[buf][0] + byte) = v;
        }
    };

    int kbeg = ks * kper;
    int nit = kper / 64;
    float4 br[4];
    loadB(kbeg, br);
    stageA(0, kbeg);
    writeB(0, br);
    __syncthreads();
    int cur = 0;
    for (int it = 0; it < nit; ++it) {
        float4 br2[4];
        bool more = (it + 1 < nit);
        if (more) {
            loadB(kbeg + (it + 1) * 64, br2);       // reg loads first (vmcnt)
            stageA(cur ^ 1, kbeg + (it + 1) * 64);  // then async A loads
        }
        #pragma unroll
        for (int ksub = 0; ksub < 2; ++ksub) {
            s8v av[4], bv[2];
            int qg = ksub * 4 + fq;                 // global 16B k-chunk 0..7
            #pragma unroll
            for (int i = 0; i < 4; ++i) {
                int row = wr * 64 + i * 16 + fr;
                av[i] = *(const s8v*)&As[cur][row * 64 + (qg ^ (row & 7)) * 8];
            }
            #pragma unroll
            for (int j = 0; j < 2; ++j) {
                int row = wc * 32 + j * 16 + fr;
                bv[j] = *(const s8v*)((const char*)&Bs[cur][0] +
                                      row * 128 + ((qg * 16) ^ ((row & 7) << 4)));
            }
            #pragma unroll
            for (int i = 0; i < 4; ++i)
                #pragma unroll
                for (int j = 0; j < 2; ++j)
                    acc[i][j] = __builtin_amdgcn_mfma_f32_16x16x32_bf16(av[i], bv[j], acc[i][j], 0, 0, 0);
        }
        if (more) writeB(cur ^ 1, br2);
        __syncthreads();                            // drains vmcnt+lgkmcnt
        cur ^= 1;
    }

    #pragma unroll
    for (int i = 0; i < 4; ++i) {
        #pragma unroll
        for (int rr = 0; rr < 4; ++rr) {
            int row = bm + wr * 64 + i * 16 + fq * 4 + rr;
            if (row >= m_count) continue;
            #pragma unroll
            for (int j = 0; j < 2; ++j) {
                int col = bn + wc * 32 + j * 16 + fr;
                float v = acc[i][j][rr];
                if (OUTMODE == 2) {
                    atomicAdd(&Cf[(long)row * ldc + col], v);
                } else {
                    if (biasp) v += biasp[col];
                    if (GELU) v = 0.5f * v * (1.f + erff(v * 0.70710678118654752f));
                    Cb[(long)row * ldc + col] = __float2bfloat16(v);
                }
            }
        }
    }
}

// ---------------- row softmax over 512 (f32 in, bf16 out) ----------------
__global__ __launch_bounds__(256) void softmax512(const float* __restrict__ s,
                                                  bf16* __restrict__ attn) {
    long row = blockIdx.x;
    const float* p = s + row * 512;
    int tid = threadIdx.x;
    float a = p[tid], b = p[tid + 256];
    float m = fmaxf(a, b);
    __shared__ float red[4], red2[4];
    #pragma unroll
    for (int o = 32; o; o >>= 1) m = fmaxf(m, __shfl_xor(m, o));
    if ((tid & 63) == 0) red[tid >> 6] = m;
    __syncthreads();
    m = fmaxf(fmaxf(red[0], red[1]), fmaxf(red[2], red[3]));
    float e0 = expf(a - m), e1 = expf(b - m);
    float ssum = e0 + e1;
    #pragma unroll
    for (int o = 32; o; o >>= 1) ssum += __shfl_xor(ssum, o);
    if ((tid & 63) == 0) red2[tid >> 6] = ssum;
    __syncthreads();
    ssum = red2[0] + red2[1] + red2[2] + red2[3];
    float inv = 1.f / ssum;
    bf16* ar = attn + row * 512;
    ar[tid]       = __float2bfloat16(e0 * inv);
    ar[tid + 256] = __float2bfloat16(e1 * inv);
}

// ---------------- V transpose: qkv bf16 [tok][2304] -> vt [z][64][512] ------
__global__ __launch_bounds__(256) void vt_kernel(const bf16* __restrict__ qkvb,
                                                 bf16* __restrict__ vt) {
    int st = blockIdx.x;
    int z = blockIdx.y;
    int b = z / HEADS, h = z % HEADS;
    __shared__ short tile[64][65];
    int t = threadIdx.x;
    int d = t & 63, s0 = t >> 6;
    const short* q = (const short*)qkvb;
    #pragma unroll
    for (int i = 0; i < 16; ++i) {
        int s = st * 64 + s0 + i * 4;
        tile[s0 + i * 4][d] = q[(long)(b * SEQ + s) * 2304 + 2 * DIM + h * HDIM + d];
    }
    __syncthreads();
    short* o = (short*)vt;
    #pragma unroll
    for (int i = 0; i < 16; ++i) {
        int d2 = (t >> 6) + i * 4;
        o[(long)(z * 64 + d2) * 512 + st * 64 + (t & 63)] = tile[t & 63][d2];
    }
}

// ---------------- straight f32 -> bf16 convert ----------------
__global__ __launch_bounds__(256) void cvt_kernel(const float* __restrict__ in,
                                                  bf16* __restrict__ out, long n) {
    long i = ((long)blockIdx.x * 256 + threadIdx.x) * 4;
    if (i >= n) return;
    float4 v = *(const float4*)(in + i);
    out[i]     = __float2bfloat16(v.x);
    out[i + 1] = __float2bfloat16(v.y);
    out[i + 2] = __float2bfloat16(v.z);
    out[i + 3] = __float2bfloat16(v.w);
}

// ---------------- router: logits, softmax, top2, renorm ----------------
__global__ __launch_bounds__(64) void router_kernel(const float* __restrict__ t2,
                                                    const float* __restrict__ rw,
                                                    const float* __restrict__ rb,
                                                    int* __restrict__ e_sel,
                                                    float* __restrict__ w_sel) {
    int t = blockIdx.x;
    int lane = threadIdx.x;
    const float* tr = t2 + (long)t * DIM;
    float tv[12];
    #pragma unroll
    for (int i = 0; i < 12; ++i) tv[i] = tr[lane + 64 * i];
    float logits[NEXP];
    #pragma unroll
    for (int e = 0; e < NEXP; ++e) {
        const float* wr = rw + (long)e * DIM;
        float s = 0.f;
        #pragma unroll
        for (int i = 0; i < 12; ++i) s += tv[i] * wr[lane + 64 * i];
        #pragma unroll
        for (int o = 32; o; o >>= 1) s += __shfl_xor(s, o);
        logits[e] = s + rb[e];
    }
    if (lane == 0) {
        int e0 = -1, e1 = -1;
        float l0 = -1e30f, l1 = -1e30f;
        #pragma unroll
        for (int e = 0; e < NEXP; ++e) {
            float l = logits[e];
            if (l > l0) { l1 = l0; e1 = e0; l0 = l; e0 = e; }
            else if (l > l1) { l1 = l; e1 = e; }
        }
        float p1 = expf(l1 - l0);
        float inv = 1.f / (1.f + p1);
        e_sel[t * 2] = e0;  e_sel[t * 2 + 1] = e1;
        w_sel[t * 2] = inv; w_sel[t * 2 + 1] = p1 * inv;
    }
}

// ---------------- build per-expert entry lists (single block) ----------------
__global__ __launch_bounds__(1024) void build_lists(const int* __restrict__ e_sel,
                                                    int* __restrict__ entry_tok,
                                                    int* __restrict__ ent_exp,
                                                    int* __restrict__ pos,
                                                    int* __restrict__ grp_off) {
    __shared__ int cnt[NEXP];
    __shared__ int off[NEXP + 1];
    __shared__ int cur[NEXP];
    int tid = threadIdx.x;
    if (tid < NEXP) cnt[tid] = 0;
    __syncthreads();
    for (int i = tid; i < NENT; i += 1024) atomicAdd(&cnt[e_sel[i]], 1);
    __syncthreads();
    if (tid == 0) {
        off[0] = 0;
        for (int e = 0; e < NEXP; ++e) off[e + 1] = off[e] + cnt[e];
        for (int e = 0; e < NEXP; ++e) cur[e] = off[e];
    }
    __syncthreads();
    for (int i = tid; i < NENT; i += 1024) {
        int e = e_sel[i];
        int p = atomicAdd(&cur[e], 1);
        entry_tok[p] = i >> 1;
        ent_exp[p] = e;
        pos[i] = p;
    }
    if (tid < NEXP + 1) grp_off[tid] = off[tid];
}

// ---------------- gather rows (bf16, 8B units) ----------------
__global__ __launch_bounds__(256) void gather_kernel(const bf16* __restrict__ t2b,
                                                     const int* __restrict__ entry_tok,
                                                     bf16* __restrict__ t2g) {
    long i = (long)blockIdx.x * 256 + threadIdx.x;
    if (i >= (long)NENT * 192) return;
    int p = (int)(i / 192), q = (int)(i % 192);
    ((uint2*)t2g)[(long)p * 192 + q] = ((const uint2*)t2b)[(long)entry_tok[p] * 192 + q];
}

// ---------------- prefill x1 = x + out_b ----------------
__global__ __launch_bounds__(256) void prefill_x1(const float* __restrict__ x,
                                                  const float* __restrict__ out_b,
                                                  float* __restrict__ x1) {
    long i = ((long)blockIdx.x * 256 + threadIdx.x) * 4;
    if (i >= (long)NTOK * DIM) return;
    int d = (int)(i % DIM);
    float4 v = *(const float4*)(x + i);
    v.x += out_b[d]; v.y += out_b[d + 1]; v.z += out_b[d + 2]; v.w += out_b[d + 3];
    *(float4*)(x1 + i) = v;
}

// ---------------- prefill ybuf[p][.] = b2[exp(p)][.] ----------------
__global__ __launch_bounds__(256) void prefill_ybuf(const float* __restrict__ b2,
                                                    const int* __restrict__ ent_exp,
                                                    float* __restrict__ ybuf) {
    long i = ((long)blockIdx.x * 256 + threadIdx.x) * 4;
    if (i >= (long)NENT * DIM) return;
    int p = (int)(i / DIM), d = (int)(i % DIM);
    *(float4*)(ybuf + i) = *(const float4*)(b2 + (long)ent_exp[p] * DIM + d);
}

// ---------------- final combine: out = x1 + w0*y(pos0) + w1*y(pos1) ----------
__global__ __launch_bounds__(256) void combine_kernel(const float* __restrict__ x1,
                                                      const float* __restrict__ ybuf,
                                                      const int* __restrict__ pos,
                                                      const float* __restrict__ wsel,
                                                      float* __restrict__ out) {
    long i = (long)blockIdx.x * 256 + threadIdx.x;
    if (i >= (long)NTOK * DIM) return;
    int t = (int)(i / DIM), d = (int)(i % DIM);
    float v = x1[i];
    v += wsel[t * 2]     * ybuf[(long)pos[t * 2]     * DIM + d];
    v += wsel[t * 2 + 1] * ybuf[(long)pos[t * 2 + 1] * DIM + d];
    out[i] = v;
}

extern "C" void kernel_launch(void* const* d_in, const int* in_sizes, int n_in,
                              void* d_out, int out_size, void* d_ws, size_t ws_size,
                              hipStream_t stream) {
    const float* x        = (const float*)d_in[0];
    const float* ln1_g    = (const float*)d_in[1];
    const float* ln1_b    = (const float*)d_in[2];
    const float* ln2_g    = (const float*)d_in[3];
    const float* ln2_b    = (const float*)d_in[4];
    const float* in_w     = (const float*)d_in[5];
    const float* in_b     = (const float*)d_in[6];
    const float* out_w    = (const float*)d_in[7];
    const float* out_b    = (const float*)d_in[8];
    const float* router_w = (const float*)d_in[9];
    const float* router_b = (const float*)d_in[10];
    const float* w1       = (const float*)d_in[11];
    const float* b1       = (const float*)d_in[12];
    const float* w2       = (const float*)d_in[13];
    const float* b2       = (const float*)d_in[14];
    float* out = (float*)d_out;

    const long TD = (long)NTOK * DIM;
    char* p = (char*)d_ws;
    size_t off = 0;
    auto alloc = [&](size_t bytes) -> void* {
        void* r = p + off; off += (bytes + 255) & ~(size_t)255; return r;
    };
    bf16*  h_b    = (bf16*)alloc(TD * 2);
    bf16*  in_wb  = (bf16*)alloc(2304L * 768 * 2);
    bf16*  qkv_b  = (bf16*)alloc(1024L * 2304 * 2);
    bf16*  out_wb = (bf16*)alloc(768L * 768 * 2);
    bf16*  vt_b   = (bf16*)alloc((24L * 64 + 64) * 512 * 2);
    bf16*  oat_b  = (bf16*)alloc(TD * 2);
    float* x1     = (float*)alloc(TD * 4);
    float* t2     = (float*)alloc(TD * 4);
    bf16*  t2b    = (bf16*)alloc(TD * 2);
    bf16*  t2g    = (bf16*)alloc((2048L + 256) * 768 * 2);     // +pad (BM overread)
    float* scores = (float*)alloc(24L * 512 * 512 * 4);
    bf16*  attn   = (bf16*)alloc(24L * 512 * 512 * 2);
    bf16*  hid    = (bf16*)alloc((2048L + 256) * 3072 * 2);    // +pad
    float* ybuf   = (float*)alloc(2048L * 768 * 4);
    int*   e_sel     = (int*)alloc(NENT * 4);
    float* w_sel     = (float*)alloc(NENT * 4);
    int*   entry_tok = (int*)alloc(NENT * 4);
    int*   ent_exp   = (int*)alloc(NENT * 4);
    int*   pos       = (int*)alloc(NENT * 4);
    int*   grp_off   = (int*)alloc(64);

    // 1. LN1 -> h bf16
    ln_kernel<<<NTOK, 256, 0, stream>>>(x, ln1_g, ln1_b, nullptr, h_b);
    // 2-3. attention weight converts (already [N][K]; no transpose needed)
    cvt_kernel<<<1728, 256, 0, stream>>>(in_w, in_wb, 2304L * 768);
    cvt_kernel<<<576, 256, 0, stream>>>(out_w, out_wb, 768L * 768);
    // 4. qkv = h @ in_w^T + in_b -> bf16 [1024,2304]   BN=64: 576 blocks
    mfma_gemm<2, 2, false, false, 1><<<dim3(36, 16, 1), 256, 0, stream>>>(
        h_b, in_wb, in_b, nullptr, qkv_b,
        NTOK, 3 * DIM, DIM, DIM, DIM, 3 * DIM,
        1, 1, 0, 0, 0, 0, 0, 0, 0, nullptr, 1.f);
    // 5. scores = Q @ K^T / 8 -> f32 [24][512][512]   768 blocks
    mfma_gemm<2, 4, false, false, 0><<<dim3(4, 8, 24), 256, 0, stream>>>(
        qkv_b, qkv_b + DIM, nullptr, nullptr, scores,
        SEQ, SEQ, HDIM, 3 * DIM, 3 * DIM, SEQ,
        HEADS, 1, (long)SEQ * 3 * DIM, HDIM, (long)SEQ * 3 * DIM, HDIM,
        (long)HEADS * SEQ * SEQ, (long)SEQ * SEQ,
        0, nullptr, 0.125f);
    // 6. softmax -> attn bf16
    softmax512<<<24 * SEQ, 256, 0, stream>>>(scores, attn);
    // 7. V transpose
    vt_kernel<<<dim3(8, 24), 256, 0, stream>>>(qkv_b, vt_b);
    // 8. o = attn @ V -> oat bf16   BM=32: 384 blocks
    mfma_gemm<1, 2, false, false, 1><<<dim3(1, 16, 24), 256, 0, stream>>>(
        attn, vt_b, nullptr, nullptr, oat_b,
        SEQ, HDIM, SEQ, SEQ, SEQ, DIM,
        HEADS, 1, (long)HEADS * SEQ * SEQ, (long)SEQ * SEQ,
        (long)HEADS * HDIM * SEQ, (long)HDIM * SEQ,
        (long)SEQ * DIM, HDIM,
        0, nullptr, 1.f);
    // 9a. prefill x1 = x + out_b
    prefill_x1<<<768, 256, 0, stream>>>(x, out_b, x1);
    // 9b. x1 += oat @ out_w^T   (split-K x2, atomic)  BN=64: 384 blocks
    mfma_gemm<2, 2, false, false, 2><<<dim3(12, 16, 2), 256, 0, stream>>>(
        oat_b, out_wb, nullptr, nullptr, x1,
        NTOK, DIM, DIM, DIM, DIM, DIM,
        1, 2, 0, 0, 0, 0, 0, 0, 0, nullptr, 1.f);
    // 10. LN2 -> t2 f32 + t2b bf16
    ln_kernel<<<NTOK, 256, 0, stream>>>(x1, ln2_g, ln2_b, t2, t2b);
    // 11. router
    router_kernel<<<NTOK, 64, 0, stream>>>(t2, router_w, router_b, e_sel, w_sel);
    // 12. build lists
    build_lists<<<1, 1024, 0, stream>>>(e_sel, entry_tok, ent_exp, pos, grp_off);
    // 13. gather bf16
    gather_kernel<<<1536, 256, 0, stream>>>(t2b, entry_tok, t2g);
    // 14. FFN1 grouped: hid = gelu(t2g @ w1[e] + b1) -> bf16
    //     w1 consumed directly as f32 [768][3072], coalesced staging
    moe_gemm<48, 16, 1, true, 1><<<8 * 48 * 16, 256, 0, stream>>>(
        t2g, w1, b1, hid,
        DIM, FFDIM, FFDIM, DIM, (long)DIM * FFDIM, FFDIM, grp_off);
    // 15a. prefill ybuf with b2 rows
    prefill_ybuf<<<1536, 256, 0, stream>>>(b2, ent_exp, ybuf);
    // 15b. FFN2 grouped split-K x4 (atomic): ybuf += hid @ w2[e]
    //      w2 consumed directly as f32 [3072][768], coalesced staging
    moe_gemm<12, 16, 4, false, 2><<<8 * 12 * 16 * 4, 256, 0, stream>>>(
        hid, w2, nullptr, ybuf,
        FFDIM, DIM, DIM, FFDIM, (long)FFDIM * DIM, 0, grp_off);
    // 16. combine
    combine_kernel<<<3072, 256, 0, stream>>>(x1, ybuf, pos, w_sel, out);
}